// Round 1
// baseline (637.561 us; speedup 1.0000x reference)
//
#include <hip/hip_runtime.h>
#include <math.h>

#define D_MODEL 64
#define D_STATE 16
#define D_INNER 128
#define DT_RANK 4
#define BB 8
#define LL 4096
#define NTOK (BB*LL)      // 32768
#define EPSV 1e-6f
#define NCHUNK 32
#define LC (LL/NCHUNK)    // 128
#define TT 32             // tokens per conv block

__device__ __forceinline__ float sig_(float v) { return 1.f / (1.f + __expf(-v)); }
__device__ __forceinline__ float softplus_(float v) {
    return (v > 20.f) ? v : __logf(1.f + __expf(v));
}

// K1: RMSNorm + in_proj (256 outputs) + silu(z). Wave per token, 8 tokens/wave.
__global__ __launch_bounds__(256) void k1_norm_inproj(
    const float* __restrict__ x, const float* __restrict__ w_norm,
    const float* __restrict__ W_in, const float* __restrict__ b_in,
    float* __restrict__ u_raw, float* __restrict__ z_silu)
{
    __shared__ float WT[64 * 256];   // W_in transposed: WT[k][o]
    int tid = threadIdx.x;
    for (int i = tid; i < 64 * 256; i += 256) {
        int o = i >> 6, k = i & 63;
        WT[k * 256 + o] = W_in[i];
    }
    __syncthreads();
    int lane = tid & 63, wid = tid >> 6;
    int base = blockIdx.x * 32;
    float wn = w_norm[lane];
    float b0 = b_in[lane], b1 = b_in[64 + lane], b2 = b_in[128 + lane], b3 = b_in[192 + lane];
    for (int it = 0; it < 8; ++it) {
        int g = base + wid * 8 + it;
        float xv = x[g * 64 + lane];
        float ss = xv * xv;
        #pragma unroll
        for (int off = 32; off; off >>= 1) ss += __shfl_xor(ss, off, 64);
        float r = rsqrtf(ss * (1.f / 64.f) + EPSV);
        float xn = xv * r * wn;
        float a0 = 0.f, a1 = 0.f, a2 = 0.f, a3 = 0.f;
        for (int k = 0; k < 64; ++k) {
            float xk = __shfl(xn, k, 64);
            const float* w = &WT[k * 256 + lane];
            a0 += xk * w[0]; a1 += xk * w[64]; a2 += xk * w[128]; a3 += xk * w[192];
        }
        u_raw[g * 128 + lane]      = a0 + b0;
        u_raw[g * 128 + 64 + lane] = a1 + b1;
        float z0 = a2 + b2, z1 = a3 + b3;
        z_silu[g * 128 + lane]      = z0 * sig_(z0);
        z_silu[g * 128 + 64 + lane] = z1 * sig_(z1);
    }
}

// K2: full channel-mixing conv1d (O=I=128, K=4, causal window t-3..t) + silu.
// Block handles one batch x 32 tokens; thread = (output o, token-half).
__global__ __launch_bounds__(256) void k2_conv(
    const float* __restrict__ u_raw, const float* __restrict__ W_conv,
    const float* __restrict__ b_conv, float* __restrict__ u_conv)
{
    __shared__ float ulds[(TT + 3) * 128];   // rows: t = tb-3 .. tb+31
    int b  = blockIdx.x >> 7;                // L/TT = 128 blocks per batch
    int tb = (blockIdx.x & 127) * TT;
    int tid = threadIdx.x;
    for (int i = tid; i < (TT + 3) * 128; i += 256) {
        int row = i >> 7, c = i & 127;
        int t = tb - 3 + row;
        ulds[i] = (t >= 0) ? u_raw[(b * LL + t) * 128 + c] : 0.f;
    }
    __syncthreads();
    int o  = tid & 127;
    int tg = tid >> 7;           // token group 0/1 (16 tokens each)
    int trow0 = tg * 16;
    float acc[16];
    #pragma unroll
    for (int i = 0; i < 16; ++i) acc[i] = 0.f;
    const float* Wo = W_conv + o * 512;      // W_conv[o][c][k], k contiguous
    for (int c = 0; c < 128; c += 4) {
        float4 w0 = *(const float4*)&Wo[(c + 0) * 4];
        float4 w1 = *(const float4*)&Wo[(c + 1) * 4];
        float4 w2 = *(const float4*)&Wo[(c + 2) * 4];
        float4 w3 = *(const float4*)&Wo[(c + 3) * 4];
        #pragma unroll
        for (int h = 0; h < 2; ++h) {
            float4 uv[11];
            #pragma unroll
            for (int m = 0; m < 11; ++m)
                uv[m] = *(const float4*)&ulds[(trow0 + h * 8 + m) * 128 + c];
            #pragma unroll
            for (int t = 0; t < 8; ++t) {
                float s = acc[h * 8 + t];
                s += w0.x * uv[t].x + w0.y * uv[t + 1].x + w0.z * uv[t + 2].x + w0.w * uv[t + 3].x;
                s += w1.x * uv[t].y + w1.y * uv[t + 1].y + w1.z * uv[t + 2].y + w1.w * uv[t + 3].y;
                s += w2.x * uv[t].z + w2.y * uv[t + 1].z + w2.z * uv[t + 2].z + w2.w * uv[t + 3].z;
                s += w3.x * uv[t].w + w3.y * uv[t + 1].w + w3.z * uv[t + 2].w + w3.w * uv[t + 3].w;
                acc[h * 8 + t] = s;
            }
        }
    }
    float bc = b_conv[o];
    #pragma unroll
    for (int t = 0; t < 16; ++t) {
        float v = acc[t] + bc;
        u_conv[(b * LL + tb + trow0 + t) * 128 + o] = v * sig_(v);
    }
}

// K3: xp = u @ W_xp^T + b_xp -> (dt, Bm, Cm); delta = softplus(dt @ W_dt^T + b_dt)
__global__ __launch_bounds__(256) void k3_xproj(
    const float* __restrict__ u_conv,
    const float* __restrict__ W_xp, const float* __restrict__ b_xp,
    const float* __restrict__ W_dt, const float* __restrict__ b_dt,
    float* __restrict__ delta, float* __restrict__ Bm, float* __restrict__ Cm)
{
    int tid = threadIdx.x, lane = tid & 63, wid = tid >> 6;
    int base = blockIdx.x * 32;
    int ro = lane < 36 ? lane : 35;
    const float* wr = &W_xp[ro * 128];
    float bx = b_xp[ro];
    float bd0 = b_dt[lane], bd1 = b_dt[lane + 64];
    float wd00 = W_dt[lane * 4 + 0], wd01 = W_dt[lane * 4 + 1],
          wd02 = W_dt[lane * 4 + 2], wd03 = W_dt[lane * 4 + 3];
    float wd10 = W_dt[(lane + 64) * 4 + 0], wd11 = W_dt[(lane + 64) * 4 + 1],
          wd12 = W_dt[(lane + 64) * 4 + 2], wd13 = W_dt[(lane + 64) * 4 + 3];
    for (int it = 0; it < 8; ++it) {
        int g = base + wid * 8 + it;
        float u0 = u_conv[g * 128 + lane];
        float u1 = u_conv[g * 128 + 64 + lane];
        float acc = bx;
        for (int c = 0; c < 64; ++c) { float uc = __shfl(u0, c, 64); acc += uc * wr[c]; }
        for (int c = 0; c < 64; ++c) { float uc = __shfl(u1, c, 64); acc += uc * wr[64 + c]; }
        float dt0 = __shfl(acc, 0, 64), dt1 = __shfl(acc, 1, 64),
              dt2 = __shfl(acc, 2, 64), dt3 = __shfl(acc, 3, 64);
        float v0 = bd0 + dt0 * wd00 + dt1 * wd01 + dt2 * wd02 + dt3 * wd03;
        float v1 = bd1 + dt0 * wd10 + dt1 * wd11 + dt2 * wd12 + dt3 * wd13;
        delta[g * 128 + lane]      = softplus_(v0);
        delta[g * 128 + 64 + lane] = softplus_(v1);
        if (lane >= 4 && lane < 20)       Bm[g * 16 + lane - 4]  = acc;
        else if (lane >= 20 && lane < 36) Cm[g * 16 + lane - 20] = acc;
    }
}

// K4a: per-chunk (P = prod a, Q = local scan end from 0). thread = (b,chunk,d,n)
__global__ __launch_bounds__(256) void k4a_chunk(
    const float* __restrict__ delta, const float* __restrict__ u_conv,
    const float* __restrict__ Bm, const float* __restrict__ A_log,
    float* __restrict__ P, float* __restrict__ Q)
{
    int bid = blockIdx.x;
    int b = bid >> 8, c = (bid >> 3) & 31, dblk = bid & 7;
    int tid = threadIdx.x;
    int d = dblk * 16 + (tid >> 4), n = tid & 15;
    float Aval = -__expf(A_log[d * 16 + n]);
    float Pp = 1.f, Qq = 0.f;
    int g0 = b * LL + c * LC;
    for (int t = 0; t < LC; ++t) {
        int g = g0 + t;
        float dl = delta[g * 128 + d];
        float uu = u_conv[g * 128 + d];
        float bm = Bm[g * 16 + n];
        float a = __expf(dl * Aval);
        Pp *= a;
        Qq = a * Qq + dl * uu * bm;
    }
    int idx = ((b * NCHUNK + c) * 128 + d) * 16 + n;
    P[idx] = Pp; Q[idx] = Qq;
}

// K4b: carry scan across chunks. thread = (b,d,n), loop c.
__global__ __launch_bounds__(256) void k4b_carry(
    const float* __restrict__ P, const float* __restrict__ Q, float* __restrict__ Hinit)
{
    int tid = blockIdx.x * 256 + threadIdx.x;  // 0..16383
    int b = tid >> 11, dn = tid & 2047;
    float carry = 0.f;
    for (int c = 0; c < NCHUNK; ++c) {
        int idx = (b * NCHUNK + c) * 2048 + dn;
        Hinit[idx] = carry;
        carry = P[idx] * carry + Q[idx];
    }
}

// K4c: replay chunk from Hinit, y[t,d] = sum_n h*C + D*u, y *= silu(z)
__global__ __launch_bounds__(256) void k4c_scan(
    const float* __restrict__ delta, const float* __restrict__ u_conv,
    const float* __restrict__ Bm, const float* __restrict__ Cm,
    const float* __restrict__ z_silu, const float* __restrict__ A_log,
    const float* __restrict__ D_param, const float* __restrict__ Hinit,
    float* __restrict__ y_pre)
{
    int bid = blockIdx.x;
    int b = bid >> 8, c = (bid >> 3) & 31, dblk = bid & 7;
    int tid = threadIdx.x;
    int d = dblk * 16 + (tid >> 4), n = tid & 15;
    float Aval = -__expf(A_log[d * 16 + n]);
    float h = Hinit[((b * NCHUNK + c) * 128 + d) * 16 + n];
    float Dp = D_param[d];
    int g0 = b * LL + c * LC;
    for (int t = 0; t < LC; ++t) {
        int g = g0 + t;
        float dl = delta[g * 128 + d];
        float uu = u_conv[g * 128 + d];
        float bm = Bm[g * 16 + n];
        float cm = Cm[g * 16 + n];
        float a = __expf(dl * Aval);
        h = a * h + dl * uu * bm;
        float yv = h * cm;
        yv += __shfl_xor(yv, 1, 64);
        yv += __shfl_xor(yv, 2, 64);
        yv += __shfl_xor(yv, 4, 64);
        yv += __shfl_xor(yv, 8, 64);
        if (n == 0) {
            float y = yv + Dp * uu;
            y *= z_silu[g * 128 + d];
            y_pre[g * 128 + d] = y;
        }
    }
}

// K5: out = x + y_pre @ W_out^T + b_out. Wave per token, lane = output m.
__global__ __launch_bounds__(256) void k5_outproj(
    const float* __restrict__ y_pre, const float* __restrict__ W_out,
    const float* __restrict__ b_out, const float* __restrict__ x,
    float* __restrict__ out)
{
    int tid = threadIdx.x, lane = tid & 63, wid = tid >> 6;
    int base = blockIdx.x * 32;
    const float* wrow = &W_out[lane * 128];
    float bo = b_out[lane];
    for (int it = 0; it < 8; ++it) {
        int g = base + wid * 8 + it;
        float y0 = y_pre[g * 128 + lane], y1 = y_pre[g * 128 + 64 + lane];
        float acc = 0.f;
        for (int d2 = 0; d2 < 64; ++d2) acc += __shfl(y0, d2, 64) * wrow[d2];
        for (int d2 = 0; d2 < 64; ++d2) acc += __shfl(y1, d2, 64) * wrow[64 + d2];
        out[g * 64 + lane] = x[g * 64 + lane] + bo + acc;
    }
}

extern "C" void kernel_launch(void* const* d_in, const int* in_sizes, int n_in,
                              void* d_out, int out_size, void* d_ws, size_t ws_size,
                              hipStream_t stream)
{
    const float* x       = (const float*)d_in[0];
    const float* w_norm  = (const float*)d_in[1];
    const float* W_in    = (const float*)d_in[2];
    const float* b_in    = (const float*)d_in[3];
    const float* W_conv  = (const float*)d_in[4];
    const float* b_conv  = (const float*)d_in[5];
    const float* W_xp    = (const float*)d_in[6];
    const float* b_xp    = (const float*)d_in[7];
    const float* W_dt    = (const float*)d_in[8];
    const float* b_dt    = (const float*)d_in[9];
    const float* W_out   = (const float*)d_in[10];
    const float* b_out   = (const float*)d_in[11];
    const float* A_log   = (const float*)d_in[12];
    const float* D_param = (const float*)d_in[13];
    float* ws = (float*)d_ws;

    float* u_raw  = ws;                    // 4M floats (B,L,128)
    float* z_silu = ws + 4194304;          // 4M
    float* u_conv = ws + 8388608;          // 4M
    float* delta  = ws + 12582912;         // 4M
    float* Bm     = ws + 16777216;         // 512K (B,L,16)
    float* Cm     = Bm + 524288;           // 512K
    float* P      = Cm + 524288;           // 512K (B,C,128,16)
    float* Q      = P + 524288;            // 512K
    float* Hinit  = Q + 524288;            // 512K
    float* y_pre  = u_raw;                 // reuse: u_raw dead after k2
    float* out    = (float*)d_out;

    k1_norm_inproj<<<1024, 256, 0, stream>>>(x, w_norm, W_in, b_in, u_raw, z_silu);
    k2_conv<<<1024, 256, 0, stream>>>(u_raw, W_conv, b_conv, u_conv);
    k3_xproj<<<1024, 256, 0, stream>>>(u_conv, W_xp, b_xp, W_dt, b_dt, delta, Bm, Cm);
    k4a_chunk<<<2048, 256, 0, stream>>>(delta, u_conv, Bm, A_log, P, Q);
    k4b_carry<<<64, 256, 0, stream>>>(P, Q, Hinit);
    k4c_scan<<<2048, 256, 0, stream>>>(delta, u_conv, Bm, Cm, z_silu, A_log, D_param, Hinit, y_pre);
    k5_outproj<<<1024, 256, 0, stream>>>(y_pre, W_out, b_out, x, out);
}

// Round 2
// 545.311 us; speedup vs baseline: 1.1692x; 1.1692x over previous
//
#include <hip/hip_runtime.h>
#include <math.h>

#define D_MODEL 64
#define D_STATE 16
#define D_INNER 128
#define DT_RANK 4
#define BB 8
#define LL 4096
#define NTOK (BB*LL)      // 32768
#define EPSV 1e-6f
#define NCHUNK 32
#define LC (LL/NCHUNK)    // 128
#define TT 32             // tokens per conv block

__device__ __forceinline__ float sig_(float v) { return 1.f / (1.f + __expf(-v)); }
__device__ __forceinline__ float softplus_(float v) {
    return (v > 20.f) ? v : __logf(1.f + __expf(v));
}

// K1: RMSNorm + in_proj + silu(z).
// Block = 128 threads (2 waves). thread = channel o: computes u (W_in row o) and
// z (W_in row o+128) for a 32-token tile staged in LDS. Weights live in VGPRs
// (w_norm folded in); activation reads are uniform ds_read_b128 broadcasts.
__global__ __launch_bounds__(128) void k1_norm_inproj(
    const float* __restrict__ x, const float* __restrict__ w_norm,
    const float* __restrict__ W_in, const float* __restrict__ b_in,
    float* __restrict__ u_raw, float* __restrict__ z_silu)
{
    __shared__ float xs[32 * 68];   // row stride 68 floats (17 quads) - conflict-free
    __shared__ float rs[32];
    int tid = threadIdx.x;          // output channel o in [0,128)
    int tb = blockIdx.x * 32;
    float wu[64], wz[64];
    #pragma unroll
    for (int q = 0; q < 16; ++q) {
        float4 a  = *(const float4*)&W_in[tid * 64 + q * 4];
        float4 b  = *(const float4*)&W_in[(tid + 128) * 64 + q * 4];
        float4 wn = *(const float4*)&w_norm[q * 4];
        wu[4*q+0] = a.x * wn.x; wu[4*q+1] = a.y * wn.y;
        wu[4*q+2] = a.z * wn.z; wu[4*q+3] = a.w * wn.w;
        wz[4*q+0] = b.x * wn.x; wz[4*q+1] = b.y * wn.y;
        wz[4*q+2] = b.z * wn.z; wz[4*q+3] = b.w * wn.w;
    }
    // stage x tile: 32 tokens x 64 floats = 512 float4, coalesced
    for (int i = tid; i < 512; i += 128) {
        int t = i >> 4, q = i & 15;
        *(float4*)&xs[t * 68 + q * 4] = *(const float4*)&x[(tb + t) * 64 + q * 4];
    }
    __syncthreads();
    if (tid < 32) {
        float ss = 0.f;
        #pragma unroll
        for (int q = 0; q < 16; ++q) {
            float4 v = *(const float4*)&xs[tid * 68 + q * 4];
            ss += v.x*v.x + v.y*v.y + v.z*v.z + v.w*v.w;
        }
        rs[tid] = rsqrtf(ss * (1.f / 64.f) + EPSV);
    }
    __syncthreads();
    float bu = b_in[tid], bz = b_in[tid + 128];
    for (int t = 0; t < 32; ++t) {
        float au0=0.f,au1=0.f,au2=0.f,au3=0.f;
        float az0=0.f,az1=0.f,az2=0.f,az3=0.f;
        #pragma unroll
        for (int q = 0; q < 16; ++q) {
            float4 v = *(const float4*)&xs[t * 68 + q * 4];   // uniform broadcast
            au0 += v.x * wu[4*q+0]; au1 += v.y * wu[4*q+1];
            au2 += v.z * wu[4*q+2]; au3 += v.w * wu[4*q+3];
            az0 += v.x * wz[4*q+0]; az1 += v.y * wz[4*q+1];
            az2 += v.z * wz[4*q+2]; az3 += v.w * wz[4*q+3];
        }
        float r = rs[t];
        float uv = ((au0+au1)+(au2+au3)) * r + bu;
        float zv = ((az0+az1)+(az2+az3)) * r + bz;
        int g = tb + t;
        u_raw[g * 128 + tid]  = uv;
        z_silu[g * 128 + tid] = zv * sig_(zv);
    }
}

// K2: full channel-mixing conv1d (O=I=128, K=4, causal window t-3..t) + silu.
__global__ __launch_bounds__(256) void k2_conv(
    const float* __restrict__ u_raw, const float* __restrict__ W_conv,
    const float* __restrict__ b_conv, float* __restrict__ u_conv)
{
    __shared__ float ulds[(TT + 3) * 128];
    int b  = blockIdx.x >> 7;
    int tb = (blockIdx.x & 127) * TT;
    int tid = threadIdx.x;
    for (int i = tid; i < (TT + 3) * 128; i += 256) {
        int row = i >> 7, c = i & 127;
        int t = tb - 3 + row;
        ulds[i] = (t >= 0) ? u_raw[(b * LL + t) * 128 + c] : 0.f;
    }
    __syncthreads();
    int o  = tid & 127;
    int tg = tid >> 7;
    int trow0 = tg * 16;
    float acc[16];
    #pragma unroll
    for (int i = 0; i < 16; ++i) acc[i] = 0.f;
    const float* Wo = W_conv + o * 512;
    for (int c = 0; c < 128; c += 4) {
        float4 w0 = *(const float4*)&Wo[(c + 0) * 4];
        float4 w1 = *(const float4*)&Wo[(c + 1) * 4];
        float4 w2 = *(const float4*)&Wo[(c + 2) * 4];
        float4 w3 = *(const float4*)&Wo[(c + 3) * 4];
        #pragma unroll
        for (int h = 0; h < 2; ++h) {
            float4 uv[11];
            #pragma unroll
            for (int m = 0; m < 11; ++m)
                uv[m] = *(const float4*)&ulds[(trow0 + h * 8 + m) * 128 + c];
            #pragma unroll
            for (int t = 0; t < 8; ++t) {
                float s = acc[h * 8 + t];
                s += w0.x * uv[t].x + w0.y * uv[t + 1].x + w0.z * uv[t + 2].x + w0.w * uv[t + 3].x;
                s += w1.x * uv[t].y + w1.y * uv[t + 1].y + w1.z * uv[t + 2].y + w1.w * uv[t + 3].y;
                s += w2.x * uv[t].z + w2.y * uv[t + 1].z + w2.z * uv[t + 2].z + w2.w * uv[t + 3].z;
                s += w3.x * uv[t].w + w3.y * uv[t + 1].w + w3.z * uv[t + 2].w + w3.w * uv[t + 3].w;
                acc[h * 8 + t] = s;
            }
        }
    }
    float bc = b_conv[o];
    #pragma unroll
    for (int t = 0; t < 16; ++t) {
        float v = acc[t] + bc;
        u_conv[(b * LL + tb + trow0 + t) * 128 + o] = v * sig_(v);
    }
}

// K3: xp = u @ W_xp^T + b_xp -> (dt, Bm, Cm); delta = softplus(dt @ W_dt^T + b_dt).
// Block = 128 threads, thread = token: u in VGPRs, weights in LDS (uniform reads).
__global__ __launch_bounds__(128) void k3_xproj(
    const float* __restrict__ u_conv,
    const float* __restrict__ W_xp, const float* __restrict__ b_xp,
    const float* __restrict__ W_dt, const float* __restrict__ b_dt,
    float* __restrict__ delta, float* __restrict__ Bm, float* __restrict__ Cm)
{
    __shared__ float Wx[36 * 128];   // 18 KB
    __shared__ float Wd[512];
    __shared__ float bxs[36];
    __shared__ float bds[128];
    int tid = threadIdx.x;
    for (int i = tid; i < 1152; i += 128)
        *(float4*)&Wx[i * 4] = *(const float4*)&W_xp[i * 4];
    *(float4*)&Wd[tid * 4] = *(const float4*)&W_dt[tid * 4];
    if (tid < 36) bxs[tid] = b_xp[tid];
    bds[tid] = b_dt[tid];
    int g = blockIdx.x * 128 + tid;
    float4 u[32];
    #pragma unroll
    for (int q = 0; q < 32; ++q) u[q] = *(const float4*)&u_conv[g * 128 + q * 4];
    __syncthreads();
    auto dotrow = [&](int j) -> float {
        float a0=0.f,a1=0.f,a2=0.f,a3=0.f;
        #pragma unroll
        for (int q = 0; q < 32; ++q) {
            float4 w = *(const float4*)&Wx[j * 128 + q * 4];   // uniform broadcast
            a0 += u[q].x * w.x; a1 += u[q].y * w.y;
            a2 += u[q].z * w.z; a3 += u[q].w * w.w;
        }
        return (a0+a1)+(a2+a3) + bxs[j];
    };
    float dtv[4];
    #pragma unroll
    for (int j = 0; j < 4; ++j) dtv[j] = dotrow(j);
    for (int j = 4; j < 20; ++j)  Bm[g * 16 + (j - 4)]  = dotrow(j);
    for (int j = 20; j < 36; ++j) Cm[g * 16 + (j - 20)] = dotrow(j);
    for (int d4 = 0; d4 < 32; ++d4) {
        float4 w0 = *(const float4*)&Wd[(4*d4+0)*4];
        float4 w1 = *(const float4*)&Wd[(4*d4+1)*4];
        float4 w2 = *(const float4*)&Wd[(4*d4+2)*4];
        float4 w3 = *(const float4*)&Wd[(4*d4+3)*4];
        float4 bdv = *(const float4*)&bds[d4*4];
        float4 r;
        r.x = softplus_(bdv.x + dtv[0]*w0.x + dtv[1]*w0.y + dtv[2]*w0.z + dtv[3]*w0.w);
        r.y = softplus_(bdv.y + dtv[0]*w1.x + dtv[1]*w1.y + dtv[2]*w1.z + dtv[3]*w1.w);
        r.z = softplus_(bdv.z + dtv[0]*w2.x + dtv[1]*w2.y + dtv[2]*w2.z + dtv[3]*w2.w);
        r.w = softplus_(bdv.w + dtv[0]*w3.x + dtv[1]*w3.y + dtv[2]*w3.z + dtv[3]*w3.w);
        *(float4*)&delta[g * 128 + d4 * 4] = r;
    }
}

// K4a: per-chunk (P = prod a, Q = local scan end from 0). thread = (b,chunk,d,n)
__global__ __launch_bounds__(256) void k4a_chunk(
    const float* __restrict__ delta, const float* __restrict__ u_conv,
    const float* __restrict__ Bm, const float* __restrict__ A_log,
    float* __restrict__ P, float* __restrict__ Q)
{
    int bid = blockIdx.x;
    int b = bid >> 8, c = (bid >> 3) & 31, dblk = bid & 7;
    int tid = threadIdx.x;
    int d = dblk * 16 + (tid >> 4), n = tid & 15;
    float Aval = -__expf(A_log[d * 16 + n]);
    float Pp = 1.f, Qq = 0.f;
    int g0 = b * LL + c * LC;
    for (int t = 0; t < LC; ++t) {
        int g = g0 + t;
        float dl = delta[g * 128 + d];
        float uu = u_conv[g * 128 + d];
        float bm = Bm[g * 16 + n];
        float a = __expf(dl * Aval);
        Pp *= a;
        Qq = a * Qq + dl * uu * bm;
    }
    int idx = ((b * NCHUNK + c) * 128 + d) * 16 + n;
    P[idx] = Pp; Q[idx] = Qq;
}

// K4b: carry scan across chunks. thread = (b,d,n), loop c.
__global__ __launch_bounds__(256) void k4b_carry(
    const float* __restrict__ P, const float* __restrict__ Q, float* __restrict__ Hinit)
{
    int tid = blockIdx.x * 256 + threadIdx.x;  // 0..16383
    int b = tid >> 11, dn = tid & 2047;
    float carry = 0.f;
    for (int c = 0; c < NCHUNK; ++c) {
        int idx = (b * NCHUNK + c) * 2048 + dn;
        Hinit[idx] = carry;
        carry = P[idx] * carry + Q[idx];
    }
}

// K4c: replay chunk from Hinit, y[t,d] = sum_n h*C + D*u, y *= silu(z)
__global__ __launch_bounds__(256) void k4c_scan(
    const float* __restrict__ delta, const float* __restrict__ u_conv,
    const float* __restrict__ Bm, const float* __restrict__ Cm,
    const float* __restrict__ z_silu, const float* __restrict__ A_log,
    const float* __restrict__ D_param, const float* __restrict__ Hinit,
    float* __restrict__ y_pre)
{
    int bid = blockIdx.x;
    int b = bid >> 8, c = (bid >> 3) & 31, dblk = bid & 7;
    int tid = threadIdx.x;
    int d = dblk * 16 + (tid >> 4), n = tid & 15;
    float Aval = -__expf(A_log[d * 16 + n]);
    float h = Hinit[((b * NCHUNK + c) * 128 + d) * 16 + n];
    float Dp = D_param[d];
    int g0 = b * LL + c * LC;
    for (int t = 0; t < LC; ++t) {
        int g = g0 + t;
        float dl = delta[g * 128 + d];
        float uu = u_conv[g * 128 + d];
        float bm = Bm[g * 16 + n];
        float cm = Cm[g * 16 + n];
        float a = __expf(dl * Aval);
        h = a * h + dl * uu * bm;
        float yv = h * cm;
        yv += __shfl_xor(yv, 1, 64);
        yv += __shfl_xor(yv, 2, 64);
        yv += __shfl_xor(yv, 4, 64);
        yv += __shfl_xor(yv, 8, 64);
        if (n == 0) {
            float y = yv + Dp * uu;
            y *= z_silu[g * 128 + d];
            y_pre[g * 128 + d] = y;
        }
    }
}

// K5: out = x + y_pre @ W_out^T + b_out.
// Block = 128 threads, thread = token: y in VGPRs, W_out in LDS (uniform reads).
__global__ __launch_bounds__(128) void k5_outproj(
    const float* __restrict__ y_pre, const float* __restrict__ W_out,
    const float* __restrict__ b_out, const float* __restrict__ x,
    float* __restrict__ out)
{
    __shared__ float Wo[8192];   // 32 KB
    __shared__ float bos[64];
    int tid = threadIdx.x;
    for (int i = tid; i < 2048; i += 128)
        *(float4*)&Wo[i * 4] = *(const float4*)&W_out[i * 4];
    if (tid < 64) bos[tid] = b_out[tid];
    int g = blockIdx.x * 128 + tid;
    float4 y[32];
    #pragma unroll
    for (int q = 0; q < 32; ++q) y[q] = *(const float4*)&y_pre[g * 128 + q * 4];
    __syncthreads();
    for (int m4 = 0; m4 < 16; ++m4) {
        float rr[4];
        #pragma unroll
        for (int mm = 0; mm < 4; ++mm) {
            int m = m4 * 4 + mm;
            float a0=0.f,a1=0.f,a2=0.f,a3=0.f;
            #pragma unroll
            for (int q = 0; q < 32; ++q) {
                float4 w = *(const float4*)&Wo[m * 128 + q * 4];   // uniform broadcast
                a0 += y[q].x * w.x; a1 += y[q].y * w.y;
                a2 += y[q].z * w.z; a3 += y[q].w * w.w;
            }
            rr[mm] = (a0+a1)+(a2+a3) + bos[m];
        }
        float4 xv = *(const float4*)&x[g * 64 + m4 * 4];
        float4 res;
        res.x = rr[0] + xv.x; res.y = rr[1] + xv.y;
        res.z = rr[2] + xv.z; res.w = rr[3] + xv.w;
        *(float4*)&out[g * 64 + m4 * 4] = res;
    }
}

extern "C" void kernel_launch(void* const* d_in, const int* in_sizes, int n_in,
                              void* d_out, int out_size, void* d_ws, size_t ws_size,
                              hipStream_t stream)
{
    const float* x       = (const float*)d_in[0];
    const float* w_norm  = (const float*)d_in[1];
    const float* W_in    = (const float*)d_in[2];
    const float* b_in    = (const float*)d_in[3];
    const float* W_conv  = (const float*)d_in[4];
    const float* b_conv  = (const float*)d_in[5];
    const float* W_xp    = (const float*)d_in[6];
    const float* b_xp    = (const float*)d_in[7];
    const float* W_dt    = (const float*)d_in[8];
    const float* b_dt    = (const float*)d_in[9];
    const float* W_out   = (const float*)d_in[10];
    const float* b_out   = (const float*)d_in[11];
    const float* A_log   = (const float*)d_in[12];
    const float* D_param = (const float*)d_in[13];
    float* ws = (float*)d_ws;

    float* u_raw  = ws;                    // 4M floats (B,L,128)
    float* z_silu = ws + 4194304;          // 4M
    float* u_conv = ws + 8388608;          // 4M
    float* delta  = ws + 12582912;         // 4M
    float* Bm     = ws + 16777216;         // 512K (B,L,16)
    float* Cm     = Bm + 524288;           // 512K
    float* P      = Cm + 524288;           // 512K (B,C,128,16)
    float* Q      = P + 524288;            // 512K
    float* Hinit  = Q + 524288;            // 512K
    float* y_pre  = u_raw;                 // reuse: u_raw dead after k2
    float* out    = (float*)d_out;

    k1_norm_inproj<<<1024, 128, 0, stream>>>(x, w_norm, W_in, b_in, u_raw, z_silu);
    k2_conv<<<1024, 256, 0, stream>>>(u_raw, W_conv, b_conv, u_conv);
    k3_xproj<<<256, 128, 0, stream>>>(u_conv, W_xp, b_xp, W_dt, b_dt, delta, Bm, Cm);
    k4a_chunk<<<2048, 256, 0, stream>>>(delta, u_conv, Bm, A_log, P, Q);
    k4b_carry<<<64, 256, 0, stream>>>(P, Q, Hinit);
    k4c_scan<<<2048, 256, 0, stream>>>(delta, u_conv, Bm, Cm, z_silu, A_log, D_param, Hinit, y_pre);
    k5_outproj<<<256, 128, 0, stream>>>(y_pre, W_out, b_out, x, out);
}

// Round 3
// 467.201 us; speedup vs baseline: 1.3646x; 1.1672x over previous
//
#include <hip/hip_runtime.h>
#include <math.h>

#define D_MODEL 64
#define D_STATE 16
#define D_INNER 128
#define DT_RANK 4
#define BB 8
#define LL 4096
#define NTOK (BB*LL)      // 32768
#define EPSV 1e-6f
#define NCHUNK 32
#define LC (LL/NCHUNK)    // 128

typedef __attribute__((ext_vector_type(8))) short bf16x8;
typedef __attribute__((ext_vector_type(4))) float f32x4;

__device__ __forceinline__ float sig_(float v) { return 1.f / (1.f + __expf(-v)); }
__device__ __forceinline__ float softplus_(float v) {
    return (v > 20.f) ? v : __logf(1.f + __expf(v));
}
__device__ __forceinline__ unsigned short f2bf(float x) {
    unsigned int u = __float_as_uint(x);
    u += 0x7fff + ((u >> 16) & 1);      // round-to-nearest-even
    return (unsigned short)(u >> 16);
}

// K1: RMSNorm + in_proj + silu(z). thread = channel o; weights in VGPRs
// (w_norm folded); 32-token x tile in LDS, uniform b128 broadcast reads.
// u output is bf16 (feeds the MFMA conv).
__global__ __launch_bounds__(128) void k1_norm_inproj(
    const float* __restrict__ x, const float* __restrict__ w_norm,
    const float* __restrict__ W_in, const float* __restrict__ b_in,
    unsigned short* __restrict__ u_bf, float* __restrict__ z_silu)
{
    __shared__ float xs[32 * 68];   // row stride 68 floats - conflict-free
    __shared__ float rs[32];
    int tid = threadIdx.x;          // output channel o in [0,128)
    int tb = blockIdx.x * 32;
    float wu[64], wz[64];
    #pragma unroll
    for (int q = 0; q < 16; ++q) {
        float4 a  = *(const float4*)&W_in[tid * 64 + q * 4];
        float4 b  = *(const float4*)&W_in[(tid + 128) * 64 + q * 4];
        float4 wn = *(const float4*)&w_norm[q * 4];
        wu[4*q+0] = a.x * wn.x; wu[4*q+1] = a.y * wn.y;
        wu[4*q+2] = a.z * wn.z; wu[4*q+3] = a.w * wn.w;
        wz[4*q+0] = b.x * wn.x; wz[4*q+1] = b.y * wn.y;
        wz[4*q+2] = b.z * wn.z; wz[4*q+3] = b.w * wn.w;
    }
    for (int i = tid; i < 512; i += 128) {
        int t = i >> 4, q = i & 15;
        *(float4*)&xs[t * 68 + q * 4] = *(const float4*)&x[(tb + t) * 64 + q * 4];
    }
    __syncthreads();
    if (tid < 32) {
        float ss = 0.f;
        #pragma unroll
        for (int q = 0; q < 16; ++q) {
            float4 v = *(const float4*)&xs[tid * 68 + q * 4];
            ss += v.x*v.x + v.y*v.y + v.z*v.z + v.w*v.w;
        }
        rs[tid] = rsqrtf(ss * (1.f / 64.f) + EPSV);
    }
    __syncthreads();
    float bu = b_in[tid], bz = b_in[tid + 128];
    for (int t = 0; t < 32; ++t) {
        float au0=0.f,au1=0.f,au2=0.f,au3=0.f;
        float az0=0.f,az1=0.f,az2=0.f,az3=0.f;
        #pragma unroll
        for (int q = 0; q < 16; ++q) {
            float4 v = *(const float4*)&xs[t * 68 + q * 4];   // uniform broadcast
            au0 += v.x * wu[4*q+0]; au1 += v.y * wu[4*q+1];
            au2 += v.z * wu[4*q+2]; au3 += v.w * wu[4*q+3];
            az0 += v.x * wz[4*q+0]; az1 += v.y * wz[4*q+1];
            az2 += v.z * wz[4*q+2]; az3 += v.w * wz[4*q+3];
        }
        float r = rs[t];
        float uv = ((au0+au1)+(au2+au3)) * r + bu;
        float zv = ((az0+az1)+(az2+az3)) * r + bz;
        int g = tb + t;
        u_bf[g * 128 + tid]   = f2bf(uv);
        z_silu[g * 128 + tid] = zv * sig_(zv);
    }
}

// K2 pack: W_conv (O=128, I=128, K=4) -> bf16 Bp[kk][o][c]
__global__ __launch_bounds__(256) void k2_pack(
    const float* __restrict__ W_conv, unsigned short* __restrict__ Bp)
{
    int i = blockIdx.x * 256 + threadIdx.x;   // 65536
    int kk = i >> 14, o = (i >> 7) & 127, c = i & 127;
    Bp[i] = f2bf(W_conv[o * 512 + c * 4 + kk]);
}

// K2: conv1d as 4 shifted bf16 GEMMs via MFMA.
// u_conv[t][o] = silu( sum_kk sum_c u[t-3+kk][c] * Bp[kk][o][c] + b_conv[o] )
// Block = 256 thr (4 waves), 64 tokens/block; wave = 16 tokens x 128 outputs.
__global__ __launch_bounds__(256) void k2_conv_mfma(
    const unsigned short* __restrict__ u_bf, const unsigned short* __restrict__ Bp,
    const float* __restrict__ b_conv, float* __restrict__ u_conv)
{
    int tid = threadIdx.x;
    int wave = tid >> 6, lane = tid & 63;
    int quad = lane >> 4, l16 = lane & 15;
    int tb = blockIdx.x * 64;
    int bbase = tb & ~4095;                 // batch start (64 | 4096)
    int t0 = tb + wave * 16;
    f32x4 acc[8];
    #pragma unroll
    for (int og = 0; og < 8; ++og) acc[og] = (f32x4){0.f, 0.f, 0.f, 0.f};
    int row_base = t0 + l16 - 3;
    #pragma unroll
    for (int kk = 0; kk < 4; ++kk) {
        int row = row_base + kk;
        #pragma unroll
        for (int cs = 0; cs < 4; ++cs) {
            int kbase = cs * 32 + quad * 8;
            bf16x8 a = {0,0,0,0,0,0,0,0};
            if (row >= bbase)
                a = *(const bf16x8*)&u_bf[row * 128 + kbase];
            #pragma unroll
            for (int og = 0; og < 8; ++og) {
                bf16x8 b = *(const bf16x8*)&Bp[kk * 16384 + (og * 16 + l16) * 128 + kbase];
                acc[og] = __builtin_amdgcn_mfma_f32_16x16x32_bf16(a, b, acc[og], 0, 0, 0);
            }
        }
    }
    // epilogue: C[row][col]: col(o16)=lane&15, row(t16)=quad*4+reg
    #pragma unroll
    for (int og = 0; og < 8; ++og) {
        int o = og * 16 + l16;
        float bc = b_conv[o];
        #pragma unroll
        for (int r = 0; r < 4; ++r) {
            int t = t0 + quad * 4 + r;
            float v = acc[og][r] + bc;
            u_conv[t * 128 + o] = v * sig_(v);
        }
    }
}

// K3: xp = u @ W_xp^T + b_xp -> (dt, Bm, Cm); delta = softplus(dt @ W_dt^T + b_dt).
// thread = token: u in VGPRs, weights in LDS (uniform reads).
__global__ __launch_bounds__(128) void k3_xproj(
    const float* __restrict__ u_conv,
    const float* __restrict__ W_xp, const float* __restrict__ b_xp,
    const float* __restrict__ W_dt, const float* __restrict__ b_dt,
    float* __restrict__ delta, float* __restrict__ Bm, float* __restrict__ Cm)
{
    __shared__ float Wx[36 * 128];
    __shared__ float Wd[512];
    __shared__ float bxs[36];
    __shared__ float bds[128];
    int tid = threadIdx.x;
    for (int i = tid; i < 1152; i += 128)
        *(float4*)&Wx[i * 4] = *(const float4*)&W_xp[i * 4];
    *(float4*)&Wd[tid * 4] = *(const float4*)&W_dt[tid * 4];
    if (tid < 36) bxs[tid] = b_xp[tid];
    bds[tid] = b_dt[tid];
    int g = blockIdx.x * 128 + tid;
    float4 u[32];
    #pragma unroll
    for (int q = 0; q < 32; ++q) u[q] = *(const float4*)&u_conv[g * 128 + q * 4];
    __syncthreads();
    auto dotrow = [&](int j) -> float {
        float a0=0.f,a1=0.f,a2=0.f,a3=0.f;
        #pragma unroll
        for (int q = 0; q < 32; ++q) {
            float4 w = *(const float4*)&Wx[j * 128 + q * 4];   // uniform broadcast
            a0 += u[q].x * w.x; a1 += u[q].y * w.y;
            a2 += u[q].z * w.z; a3 += u[q].w * w.w;
        }
        return (a0+a1)+(a2+a3) + bxs[j];
    };
    float dtv[4];
    #pragma unroll
    for (int j = 0; j < 4; ++j) dtv[j] = dotrow(j);
    for (int j = 4; j < 20; ++j)  Bm[g * 16 + (j - 4)]  = dotrow(j);
    for (int j = 20; j < 36; ++j) Cm[g * 16 + (j - 20)] = dotrow(j);
    for (int d4 = 0; d4 < 32; ++d4) {
        float4 w0 = *(const float4*)&Wd[(4*d4+0)*4];
        float4 w1 = *(const float4*)&Wd[(4*d4+1)*4];
        float4 w2 = *(const float4*)&Wd[(4*d4+2)*4];
        float4 w3 = *(const float4*)&Wd[(4*d4+3)*4];
        float4 bdv = *(const float4*)&bds[d4*4];
        float4 r;
        r.x = softplus_(bdv.x + dtv[0]*w0.x + dtv[1]*w0.y + dtv[2]*w0.z + dtv[3]*w0.w);
        r.y = softplus_(bdv.y + dtv[0]*w1.x + dtv[1]*w1.y + dtv[2]*w1.z + dtv[3]*w1.w);
        r.z = softplus_(bdv.z + dtv[0]*w2.x + dtv[1]*w2.y + dtv[2]*w2.z + dtv[3]*w2.w);
        r.w = softplus_(bdv.w + dtv[0]*w3.x + dtv[1]*w3.y + dtv[2]*w3.z + dtv[3]*w3.w);
        *(float4*)&delta[g * 128 + d4 * 4] = r;
    }
}

// K4a: per-chunk (P = prod a, Q = local scan end from 0). thread = (b,chunk,d,n)
__global__ __launch_bounds__(256) void k4a_chunk(
    const float* __restrict__ delta, const float* __restrict__ u_conv,
    const float* __restrict__ Bm, const float* __restrict__ A_log,
    float* __restrict__ P, float* __restrict__ Q)
{
    int bid = blockIdx.x;
    int b = bid >> 8, c = (bid >> 3) & 31, dblk = bid & 7;
    int tid = threadIdx.x;
    int d = dblk * 16 + (tid >> 4), n = tid & 15;
    float Aval = -__expf(A_log[d * 16 + n]);
    float Pp = 1.f, Qq = 0.f;
    int g0 = b * LL + c * LC;
    for (int t = 0; t < LC; ++t) {
        int g = g0 + t;
        float dl = delta[g * 128 + d];
        float uu = u_conv[g * 128 + d];
        float bm = Bm[g * 16 + n];
        float a = __expf(dl * Aval);
        Pp *= a;
        Qq = a * Qq + dl * uu * bm;
    }
    int idx = ((b * NCHUNK + c) * 128 + d) * 16 + n;
    P[idx] = Pp; Q[idx] = Qq;
}

// K4b: carry scan across chunks. thread = (b,d,n), loop c.
__global__ __launch_bounds__(256) void k4b_carry(
    const float* __restrict__ P, const float* __restrict__ Q, float* __restrict__ Hinit)
{
    int tid = blockIdx.x * 256 + threadIdx.x;  // 0..16383
    int b = tid >> 11, dn = tid & 2047;
    float carry = 0.f;
    for (int c = 0; c < NCHUNK; ++c) {
        int idx = (b * NCHUNK + c) * 2048 + dn;
        Hinit[idx] = carry;
        carry = P[idx] * carry + Q[idx];
    }
}

// K4c: replay chunk from Hinit, y[t,d] = sum_n h*C + D*u, y *= silu(z)
__global__ __launch_bounds__(256) void k4c_scan(
    const float* __restrict__ delta, const float* __restrict__ u_conv,
    const float* __restrict__ Bm, const float* __restrict__ Cm,
    const float* __restrict__ z_silu, const float* __restrict__ A_log,
    const float* __restrict__ D_param, const float* __restrict__ Hinit,
    float* __restrict__ y_pre)
{
    int bid = blockIdx.x;
    int b = bid >> 8, c = (bid >> 3) & 31, dblk = bid & 7;
    int tid = threadIdx.x;
    int d = dblk * 16 + (tid >> 4), n = tid & 15;
    float Aval = -__expf(A_log[d * 16 + n]);
    float h = Hinit[((b * NCHUNK + c) * 128 + d) * 16 + n];
    float Dp = D_param[d];
    int g0 = b * LL + c * LC;
    for (int t = 0; t < LC; ++t) {
        int g = g0 + t;
        float dl = delta[g * 128 + d];
        float uu = u_conv[g * 128 + d];
        float bm = Bm[g * 16 + n];
        float cm = Cm[g * 16 + n];
        float a = __expf(dl * Aval);
        h = a * h + dl * uu * bm;
        float yv = h * cm;
        yv += __shfl_xor(yv, 1, 64);
        yv += __shfl_xor(yv, 2, 64);
        yv += __shfl_xor(yv, 4, 64);
        yv += __shfl_xor(yv, 8, 64);
        if (n == 0) {
            float y = yv + Dp * uu;
            y *= z_silu[g * 128 + d];
            y_pre[g * 128 + d] = y;
        }
    }
}

// K5: out = x + y_pre @ W_out^T + b_out. thread = token: y in VGPRs, W_out in LDS.
__global__ __launch_bounds__(128) void k5_outproj(
    const float* __restrict__ y_pre, const float* __restrict__ W_out,
    const float* __restrict__ b_out, const float* __restrict__ x,
    float* __restrict__ out)
{
    __shared__ float Wo[8192];
    __shared__ float bos[64];
    int tid = threadIdx.x;
    for (int i = tid; i < 2048; i += 128)
        *(float4*)&Wo[i * 4] = *(const float4*)&W_out[i * 4];
    if (tid < 64) bos[tid] = b_out[tid];
    int g = blockIdx.x * 128 + tid;
    float4 y[32];
    #pragma unroll
    for (int q = 0; q < 32; ++q) y[q] = *(const float4*)&y_pre[g * 128 + q * 4];
    __syncthreads();
    for (int m4 = 0; m4 < 16; ++m4) {
        float rr[4];
        #pragma unroll
        for (int mm = 0; mm < 4; ++mm) {
            int m = m4 * 4 + mm;
            float a0=0.f,a1=0.f,a2=0.f,a3=0.f;
            #pragma unroll
            for (int q = 0; q < 32; ++q) {
                float4 w = *(const float4*)&Wo[m * 128 + q * 4];   // uniform broadcast
                a0 += y[q].x * w.x; a1 += y[q].y * w.y;
                a2 += y[q].z * w.z; a3 += y[q].w * w.w;
            }
            rr[mm] = (a0+a1)+(a2+a3) + bos[m];
        }
        float4 xv = *(const float4*)&x[g * 64 + m4 * 4];
        float4 res;
        res.x = rr[0] + xv.x; res.y = rr[1] + xv.y;
        res.z = rr[2] + xv.z; res.w = rr[3] + xv.w;
        *(float4*)&out[g * 64 + m4 * 4] = res;
    }
}

extern "C" void kernel_launch(void* const* d_in, const int* in_sizes, int n_in,
                              void* d_out, int out_size, void* d_ws, size_t ws_size,
                              hipStream_t stream)
{
    const float* x       = (const float*)d_in[0];
    const float* w_norm  = (const float*)d_in[1];
    const float* W_in    = (const float*)d_in[2];
    const float* b_in    = (const float*)d_in[3];
    const float* W_conv  = (const float*)d_in[4];
    const float* b_conv  = (const float*)d_in[5];
    const float* W_xp    = (const float*)d_in[6];
    const float* b_xp    = (const float*)d_in[7];
    const float* W_dt    = (const float*)d_in[8];
    const float* b_dt    = (const float*)d_in[9];
    const float* W_out   = (const float*)d_in[10];
    const float* b_out   = (const float*)d_in[11];
    const float* A_log   = (const float*)d_in[12];
    const float* D_param = (const float*)d_in[13];
    float* ws = (float*)d_ws;

    // region 0 (4M floats): u_bf16 (first 2M floats' worth) then reused as y_pre
    unsigned short* u_bf = (unsigned short*)ws;   // 4M bf16 = 8 MB (dead after k2)
    float* y_pre  = ws;                           // reuse region 0 after k2
    float* z_silu = ws + 4194304;
    float* u_conv = ws + 8388608;
    float* delta  = ws + 12582912;
    float* Bm     = ws + 16777216;
    float* Cm     = Bm + 524288;
    float* P      = Cm + 524288;
    float* Q      = P + 524288;
    float* Hinit  = Q + 524288;
    unsigned short* Bp = (unsigned short*)(Hinit + 524288);  // 64K bf16 = 128 KB
    float* out    = (float*)d_out;

    k2_pack<<<256, 256, 0, stream>>>(W_conv, Bp);
    k1_norm_inproj<<<1024, 128, 0, stream>>>(x, w_norm, W_in, b_in, u_bf, z_silu);
    k2_conv_mfma<<<512, 256, 0, stream>>>(u_bf, Bp, b_conv, u_conv);
    k3_xproj<<<256, 128, 0, stream>>>(u_conv, W_xp, b_xp, W_dt, b_dt, delta, Bm, Cm);
    k4a_chunk<<<2048, 256, 0, stream>>>(delta, u_conv, Bm, A_log, P, Q);
    k4b_carry<<<64, 256, 0, stream>>>(P, Q, Hinit);
    k4c_scan<<<2048, 256, 0, stream>>>(delta, u_conv, Bm, Cm, z_silu, A_log, D_param, Hinit, y_pre);
    k5_outproj<<<256, 128, 0, stream>>>(y_pre, W_out, b_out, x, out);
}

// Round 4
// 255.952 us; speedup vs baseline: 2.4909x; 1.8253x over previous
//
#include <hip/hip_runtime.h>
#include <math.h>

#define D_MODEL 64
#define D_STATE 16
#define D_INNER 128
#define DT_RANK 4
#define BB 8
#define LL 4096
#define NTOK (BB*LL)      // 32768
#define EPSV 1e-6f
#define NCHUNK 64
#define LC (LL/NCHUNK)    // 64

typedef __attribute__((ext_vector_type(8))) short bf16x8;
typedef __attribute__((ext_vector_type(4))) float f32x4;

__device__ __forceinline__ float sig_(float v) { return 1.f / (1.f + __expf(-v)); }
__device__ __forceinline__ float softplus_(float v) {
    return (v > 20.f) ? v : __logf(1.f + __expf(v));
}
__device__ __forceinline__ unsigned short f2bf(float x) {
    unsigned int u = __float_as_uint(x);
    u += 0x7fff + ((u >> 16) & 1);      // RNE
    return (unsigned short)(u >> 16);
}
__device__ __forceinline__ float bf2f(unsigned short u) {
    return __uint_as_float(((unsigned int)u) << 16);
}

// K1: RMSNorm + in_proj + silu(z). thread = channel o; weights in VGPRs.
// u and silu(z) outputs in bf16.
__global__ __launch_bounds__(128) void k1_norm_inproj(
    const float* __restrict__ x, const float* __restrict__ w_norm,
    const float* __restrict__ W_in, const float* __restrict__ b_in,
    unsigned short* __restrict__ u_bf, unsigned short* __restrict__ z_bf)
{
    __shared__ float xs[32 * 68];
    __shared__ float rs[32];
    int tid = threadIdx.x;
    int tb = blockIdx.x * 32;
    float wu[64], wz[64];
    #pragma unroll
    for (int q = 0; q < 16; ++q) {
        float4 a  = *(const float4*)&W_in[tid * 64 + q * 4];
        float4 b  = *(const float4*)&W_in[(tid + 128) * 64 + q * 4];
        float4 wn = *(const float4*)&w_norm[q * 4];
        wu[4*q+0] = a.x * wn.x; wu[4*q+1] = a.y * wn.y;
        wu[4*q+2] = a.z * wn.z; wu[4*q+3] = a.w * wn.w;
        wz[4*q+0] = b.x * wn.x; wz[4*q+1] = b.y * wn.y;
        wz[4*q+2] = b.z * wn.z; wz[4*q+3] = b.w * wn.w;
    }
    for (int i = tid; i < 512; i += 128) {
        int t = i >> 4, q = i & 15;
        *(float4*)&xs[t * 68 + q * 4] = *(const float4*)&x[(tb + t) * 64 + q * 4];
    }
    __syncthreads();
    if (tid < 32) {
        float ss = 0.f;
        #pragma unroll
        for (int q = 0; q < 16; ++q) {
            float4 v = *(const float4*)&xs[tid * 68 + q * 4];
            ss += v.x*v.x + v.y*v.y + v.z*v.z + v.w*v.w;
        }
        rs[tid] = rsqrtf(ss * (1.f / 64.f) + EPSV);
    }
    __syncthreads();
    float bu = b_in[tid], bz = b_in[tid + 128];
    for (int t = 0; t < 32; ++t) {
        float au0=0.f,au1=0.f,au2=0.f,au3=0.f;
        float az0=0.f,az1=0.f,az2=0.f,az3=0.f;
        #pragma unroll
        for (int q = 0; q < 16; ++q) {
            float4 v = *(const float4*)&xs[t * 68 + q * 4];
            au0 += v.x * wu[4*q+0]; au1 += v.y * wu[4*q+1];
            au2 += v.z * wu[4*q+2]; au3 += v.w * wu[4*q+3];
            az0 += v.x * wz[4*q+0]; az1 += v.y * wz[4*q+1];
            az2 += v.z * wz[4*q+2]; az3 += v.w * wz[4*q+3];
        }
        float r = rs[t];
        float uv = ((au0+au1)+(au2+au3)) * r + bu;
        float zv = ((az0+az1)+(az2+az3)) * r + bz;
        int g = tb + t;
        u_bf[g * 128 + tid] = f2bf(uv);
        z_bf[g * 128 + tid] = f2bf(zv * sig_(zv));
    }
}

// K2 pack: W_conv (O,I,K) -> bf16 Bp[kk][o][c]
__global__ __launch_bounds__(256) void k2_pack(
    const float* __restrict__ W_conv, unsigned short* __restrict__ Bp)
{
    int i = blockIdx.x * 256 + threadIdx.x;
    int kk = i >> 14, o = (i >> 7) & 127, c = i & 127;
    Bp[i] = f2bf(W_conv[o * 512 + c * 4 + kk]);
}

// pack W_xp (36x128, zero-pad to 48) and W_out (64x128) to bf16
__global__ __launch_bounds__(256) void k35_pack(
    const float* __restrict__ W_xp, const float* __restrict__ W_out,
    unsigned short* __restrict__ Wxp_bf, unsigned short* __restrict__ Wout_bf)
{
    int i = blockIdx.x * 256 + threadIdx.x;   // 14336
    if (i < 6144) {
        int j = i >> 7;
        Wxp_bf[i] = (j < 36) ? f2bf(W_xp[i]) : (unsigned short)0;
    } else if (i < 14336) {
        int i2 = i - 6144;
        Wout_bf[i2] = f2bf(W_out[i2]);
    }
}

// K2: conv1d as 4 shifted bf16 GEMMs via MFMA; output u_conv bf16 (+silu).
__global__ __launch_bounds__(256) void k2_conv_mfma(
    const unsigned short* __restrict__ u_bf, const unsigned short* __restrict__ Bp,
    const float* __restrict__ b_conv, unsigned short* __restrict__ u_cbf)
{
    int tid = threadIdx.x;
    int wave = tid >> 6, lane = tid & 63;
    int quad = lane >> 4, l16 = lane & 15;
    int tb = blockIdx.x * 64;
    int bbase = tb & ~4095;
    int t0 = tb + wave * 16;
    f32x4 acc[8];
    #pragma unroll
    for (int og = 0; og < 8; ++og) acc[og] = (f32x4){0.f, 0.f, 0.f, 0.f};
    int row_base = t0 + l16 - 3;
    #pragma unroll
    for (int kk = 0; kk < 4; ++kk) {
        int row = row_base + kk;
        #pragma unroll
        for (int cs = 0; cs < 4; ++cs) {
            int kbase = cs * 32 + quad * 8;
            bf16x8 a = {0,0,0,0,0,0,0,0};
            if (row >= bbase)
                a = *(const bf16x8*)&u_bf[row * 128 + kbase];
            #pragma unroll
            for (int og = 0; og < 8; ++og) {
                bf16x8 b = *(const bf16x8*)&Bp[kk * 16384 + (og * 16 + l16) * 128 + kbase];
                acc[og] = __builtin_amdgcn_mfma_f32_16x16x32_bf16(a, b, acc[og], 0, 0, 0);
            }
        }
    }
    #pragma unroll
    for (int og = 0; og < 8; ++og) {
        int o = og * 16 + l16;
        float bc = b_conv[o];
        #pragma unroll
        for (int r = 0; r < 4; ++r) {
            int t = t0 + quad * 4 + r;
            float v = acc[og][r] + bc;
            u_cbf[t * 128 + o] = f2bf(v * sig_(v));
        }
    }
}

// K3: xp = u @ W_xp^T (MFMA, N padded 36->48) -> Bm,Cm (fp32) + dt -> LDS;
// then delta = softplus(dt @ W_dt^T + b_dt) fp32.
__global__ __launch_bounds__(256) void k3_xproj_mfma(
    const unsigned short* __restrict__ u_cbf, const unsigned short* __restrict__ Wxp_bf,
    const float* __restrict__ b_xp,
    const float* __restrict__ W_dt, const float* __restrict__ b_dt,
    float* __restrict__ delta, float* __restrict__ Bm, float* __restrict__ Cm)
{
    __shared__ float dts[64][4];
    __shared__ float Wd[512];
    __shared__ float bds[128];
    int tid = threadIdx.x;
    if (tid < 128) *(float4*)&Wd[tid * 4] = *(const float4*)&W_dt[tid * 4];
    else if (tid < 160) *(float4*)&bds[(tid - 128) * 4] = *(const float4*)&b_dt[(tid - 128) * 4];
    int wave = tid >> 6, lane = tid & 63;
    int quad = lane >> 4, l16 = lane & 15;
    int t0 = blockIdx.x * 64 + wave * 16;
    f32x4 acc[3];
    #pragma unroll
    for (int nt = 0; nt < 3; ++nt) acc[nt] = (f32x4){0.f, 0.f, 0.f, 0.f};
    #pragma unroll
    for (int cs = 0; cs < 4; ++cs) {
        int kbase = cs * 32 + quad * 8;
        bf16x8 a = *(const bf16x8*)&u_cbf[(t0 + l16) * 128 + kbase];
        #pragma unroll
        for (int nt = 0; nt < 3; ++nt) {
            bf16x8 b = *(const bf16x8*)&Wxp_bf[(nt * 16 + l16) * 128 + kbase];
            acc[nt] = __builtin_amdgcn_mfma_f32_16x16x32_bf16(a, b, acc[nt], 0, 0, 0);
        }
    }
    #pragma unroll
    for (int nt = 0; nt < 3; ++nt) {
        int j = nt * 16 + l16;
        float bx = (j < 36) ? b_xp[j] : 0.f;
        #pragma unroll
        for (int r = 0; r < 4; ++r) {
            int t = t0 + quad * 4 + r;
            float val = acc[nt][r] + bx;
            if (j < 4)       dts[wave * 16 + quad * 4 + r][j] = val;
            else if (j < 20) Bm[t * 16 + (j - 4)]  = val;
            else if (j < 36) Cm[t * 16 + (j - 20)] = val;
        }
    }
    __syncthreads();
    int tokloc = tid >> 2, dgrp = tid & 3;
    float dt0 = dts[tokloc][0], dt1 = dts[tokloc][1],
          dt2 = dts[tokloc][2], dt3 = dts[tokloc][3];
    int g = blockIdx.x * 64 + tokloc;
    #pragma unroll
    for (int d4 = 0; d4 < 8; ++d4) {
        int d = dgrp * 32 + d4 * 4;
        float4 w0 = *(const float4*)&Wd[(d + 0) * 4];
        float4 w1 = *(const float4*)&Wd[(d + 1) * 4];
        float4 w2 = *(const float4*)&Wd[(d + 2) * 4];
        float4 w3 = *(const float4*)&Wd[(d + 3) * 4];
        float4 bdv = *(const float4*)&bds[d];
        float4 r;
        r.x = softplus_(bdv.x + dt0*w0.x + dt1*w0.y + dt2*w0.z + dt3*w0.w);
        r.y = softplus_(bdv.y + dt0*w1.x + dt1*w1.y + dt2*w1.z + dt3*w1.w);
        r.z = softplus_(bdv.z + dt0*w2.x + dt1*w2.y + dt2*w2.z + dt3*w2.w);
        r.w = softplus_(bdv.w + dt0*w3.x + dt1*w3.y + dt2*w3.z + dt3*w3.w);
        *(float4*)&delta[g * 128 + d] = r;
    }
}

// K4a: per-chunk (P,Q). thread = (b,c,d, ngroup of 4 states). 4 h-chains/thread.
__global__ __launch_bounds__(256) void k4a_chunk(
    const float* __restrict__ delta, const unsigned short* __restrict__ u_cbf,
    const float* __restrict__ Bm, const float* __restrict__ A_log,
    float* __restrict__ P, float* __restrict__ Q)
{
    int bid = blockIdx.x;                    // 8 x 64 x 2 = 1024
    int b = bid >> 7, c = (bid >> 1) & 63, half = bid & 1;
    int tid = threadIdx.x, lane = tid & 63;
    int d = half * 64 + (tid >> 6) * 16 + (lane >> 2);
    int ng = lane & 3;
    float4 Av = *(const float4*)&A_log[d * 16 + ng * 4];
    float A0 = -__expf(Av.x), A1 = -__expf(Av.y), A2 = -__expf(Av.z), A3 = -__expf(Av.w);
    float P0=1.f,P1=1.f,P2=1.f,P3=1.f, Q0=0.f,Q1=0.f,Q2=0.f,Q3=0.f;
    int g0 = b * LL + c * LC;
    for (int t = 0; t < LC; ++t) {
        int g = g0 + t;
        float dl = delta[g * 128 + d];
        float uu = bf2f(u_cbf[g * 128 + d]);
        float4 bm = *(const float4*)&Bm[g * 16 + ng * 4];
        float du = dl * uu;
        float a0 = __expf(dl * A0), a1 = __expf(dl * A1),
              a2 = __expf(dl * A2), a3 = __expf(dl * A3);
        P0 *= a0; P1 *= a1; P2 *= a2; P3 *= a3;
        Q0 = a0 * Q0 + du * bm.x; Q1 = a1 * Q1 + du * bm.y;
        Q2 = a2 * Q2 + du * bm.z; Q3 = a3 * Q3 + du * bm.w;
    }
    int idx = (b * NCHUNK + c) * 2048 + d * 16 + ng * 4;
    *(float4*)&P[idx] = (float4){P0, P1, P2, P3};
    *(float4*)&Q[idx] = (float4){Q0, Q1, Q2, Q3};
}

// K4b: carry scan across chunks.
__global__ __launch_bounds__(256) void k4b_carry(
    const float* __restrict__ P, const float* __restrict__ Q, float* __restrict__ Hinit)
{
    int tid = blockIdx.x * 256 + threadIdx.x;  // 16384
    int b = tid >> 11, dn = tid & 2047;
    float carry = 0.f;
    for (int c = 0; c < NCHUNK; ++c) {
        int idx = (b * NCHUNK + c) * 2048 + dn;
        Hinit[idx] = carry;
        carry = P[idx] * carry + Q[idx];
    }
}

// K4c: replay from Hinit; y = (sum_n h*C) + D*u, y *= silu(z); bf16 out.
__global__ __launch_bounds__(256) void k4c_scan(
    const float* __restrict__ delta, const unsigned short* __restrict__ u_cbf,
    const float* __restrict__ Bm, const float* __restrict__ Cm,
    const unsigned short* __restrict__ z_bf, const float* __restrict__ A_log,
    const float* __restrict__ D_param, const float* __restrict__ Hinit,
    unsigned short* __restrict__ y_bf)
{
    int bid = blockIdx.x;
    int b = bid >> 7, c = (bid >> 1) & 63, half = bid & 1;
    int tid = threadIdx.x, lane = tid & 63;
    int d = half * 64 + (tid >> 6) * 16 + (lane >> 2);
    int ng = lane & 3;
    float4 Av = *(const float4*)&A_log[d * 16 + ng * 4];
    float A0 = -__expf(Av.x), A1 = -__expf(Av.y), A2 = -__expf(Av.z), A3 = -__expf(Av.w);
    float4 h = *(const float4*)&Hinit[(b * NCHUNK + c) * 2048 + d * 16 + ng * 4];
    float Dp = D_param[d];
    int g0 = b * LL + c * LC;
    for (int t = 0; t < LC; ++t) {
        int g = g0 + t;
        float dl = delta[g * 128 + d];
        float uu = bf2f(u_cbf[g * 128 + d]);
        float4 bm = *(const float4*)&Bm[g * 16 + ng * 4];
        float4 cm = *(const float4*)&Cm[g * 16 + ng * 4];
        float du = dl * uu;
        float a0 = __expf(dl * A0), a1 = __expf(dl * A1),
              a2 = __expf(dl * A2), a3 = __expf(dl * A3);
        h.x = a0 * h.x + du * bm.x; h.y = a1 * h.y + du * bm.y;
        h.z = a2 * h.z + du * bm.z; h.w = a3 * h.w + du * bm.w;
        float yv = h.x * cm.x + h.y * cm.y + h.z * cm.z + h.w * cm.w;
        yv += __shfl_xor(yv, 1, 64);
        yv += __shfl_xor(yv, 2, 64);
        if (ng == 0) {
            float y = yv + Dp * uu;
            y *= bf2f(z_bf[g * 128 + d]);
            y_bf[g * 128 + d] = f2bf(y);
        }
    }
}

// K5: out = x + y @ W_out^T + b_out via MFMA (N=64).
__global__ __launch_bounds__(256) void k5_outproj_mfma(
    const unsigned short* __restrict__ y_bf, const unsigned short* __restrict__ Wout_bf,
    const float* __restrict__ b_out, const float* __restrict__ x,
    float* __restrict__ out)
{
    int tid = threadIdx.x;
    int wave = tid >> 6, lane = tid & 63;
    int quad = lane >> 4, l16 = lane & 15;
    int t0 = blockIdx.x * 64 + wave * 16;
    f32x4 acc[4];
    #pragma unroll
    for (int nt = 0; nt < 4; ++nt) acc[nt] = (f32x4){0.f, 0.f, 0.f, 0.f};
    #pragma unroll
    for (int cs = 0; cs < 4; ++cs) {
        int kbase = cs * 32 + quad * 8;
        bf16x8 a = *(const bf16x8*)&y_bf[(t0 + l16) * 128 + kbase];
        #pragma unroll
        for (int nt = 0; nt < 4; ++nt) {
            bf16x8 b = *(const bf16x8*)&Wout_bf[(nt * 16 + l16) * 128 + kbase];
            acc[nt] = __builtin_amdgcn_mfma_f32_16x16x32_bf16(a, b, acc[nt], 0, 0, 0);
        }
    }
    #pragma unroll
    for (int nt = 0; nt < 4; ++nt) {
        int m = nt * 16 + l16;
        float bo = b_out[m];
        #pragma unroll
        for (int r = 0; r < 4; ++r) {
            int t = t0 + quad * 4 + r;
            out[t * 64 + m] = acc[nt][r] + bo + x[t * 64 + m];
        }
    }
}

extern "C" void kernel_launch(void* const* d_in, const int* in_sizes, int n_in,
                              void* d_out, int out_size, void* d_ws, size_t ws_size,
                              hipStream_t stream)
{
    const float* x       = (const float*)d_in[0];
    const float* w_norm  = (const float*)d_in[1];
    const float* W_in    = (const float*)d_in[2];
    const float* b_in    = (const float*)d_in[3];
    const float* W_conv  = (const float*)d_in[4];
    const float* b_conv  = (const float*)d_in[5];
    const float* W_xp    = (const float*)d_in[6];
    const float* b_xp    = (const float*)d_in[7];
    const float* W_dt    = (const float*)d_in[8];
    const float* b_dt    = (const float*)d_in[9];
    const float* W_out   = (const float*)d_in[10];
    const float* b_out   = (const float*)d_in[11];
    const float* A_log   = (const float*)d_in[12];
    const float* D_param = (const float*)d_in[13];
    float* ws = (float*)d_ws;

    unsigned short* u_bf = (unsigned short*)ws;            // 4.2M bf16, dead after k2
    unsigned short* y_bf = (unsigned short*)ws;            // reuse after k4c
    unsigned short* z_bf = (unsigned short*)(ws + 2097152);
    unsigned short* u_cbf= (unsigned short*)(ws + 4194304);
    float* delta  = ws + 6291456;                          // 4.2M fp32
    float* Bm     = ws + 10485760;                         // 512K
    float* Cm     = ws + 11010048;                         // 512K
    float* P      = ws + 11534336;                         // 1M
    float* Q      = ws + 12582912;                         // 1M
    float* Hinit  = ws + 13631488;                         // 1M
    unsigned short* Bp      = (unsigned short*)(ws + 14680064);  // 64K bf16
    unsigned short* Wxp_bf  = (unsigned short*)(ws + 14712832);  // 6144 bf16
    unsigned short* Wout_bf = (unsigned short*)(ws + 14715904);  // 8192 bf16
    float* out    = (float*)d_out;

    k2_pack<<<256, 256, 0, stream>>>(W_conv, Bp);
    k35_pack<<<56, 256, 0, stream>>>(W_xp, W_out, Wxp_bf, Wout_bf);
    k1_norm_inproj<<<1024, 128, 0, stream>>>(x, w_norm, W_in, b_in, u_bf, z_bf);
    k2_conv_mfma<<<512, 256, 0, stream>>>(u_bf, Bp, b_conv, u_cbf);
    k3_xproj_mfma<<<512, 256, 0, stream>>>(u_cbf, Wxp_bf, b_xp, W_dt, b_dt, delta, Bm, Cm);
    k4a_chunk<<<1024, 256, 0, stream>>>(delta, u_cbf, Bm, A_log, P, Q);
    k4b_carry<<<64, 256, 0, stream>>>(P, Q, Hinit);
    k4c_scan<<<1024, 256, 0, stream>>>(delta, u_cbf, Bm, Cm, z_bf, A_log, D_param, Hinit, y_bf);
    k5_outproj_mfma<<<512, 256, 0, stream>>>(y_bf, Wout_bf, b_out, x, out);
}

// Round 5
// 229.404 us; speedup vs baseline: 2.7792x; 1.1157x over previous
//
#include <hip/hip_runtime.h>
#include <math.h>

#define D_MODEL 64
#define D_STATE 16
#define D_INNER 128
#define DT_RANK 4
#define BB 8
#define LL 4096
#define NTOK (BB*LL)      // 32768
#define EPSV 1e-6f
#define NCHUNK 64
#define LC (LL/NCHUNK)    // 64

typedef __attribute__((ext_vector_type(8))) short bf16x8;
typedef __attribute__((ext_vector_type(4))) float f32x4;

__device__ __forceinline__ float sig_(float v) { return 1.f / (1.f + __expf(-v)); }
__device__ __forceinline__ float softplus_(float v) {
    return (v > 20.f) ? v : __logf(1.f + __expf(v));
}
__device__ __forceinline__ unsigned short f2bf(float x) {
    unsigned int u = __float_as_uint(x);
    u += 0x7fff + ((u >> 16) & 1);      // RNE
    return (unsigned short)(u >> 16);
}
__device__ __forceinline__ float bf2f(unsigned short u) {
    return __uint_as_float(((unsigned int)u) << 16);
}

// K1: RMSNorm + in_proj + silu(z). thread = channel o; weights in VGPRs.
__global__ __launch_bounds__(128) void k1_norm_inproj(
    const float* __restrict__ x, const float* __restrict__ w_norm,
    const float* __restrict__ W_in, const float* __restrict__ b_in,
    unsigned short* __restrict__ u_bf, unsigned short* __restrict__ z_bf)
{
    __shared__ float xs[32 * 68];
    __shared__ float rs[32];
    int tid = threadIdx.x;
    int tb = blockIdx.x * 32;
    float wu[64], wz[64];
    #pragma unroll
    for (int q = 0; q < 16; ++q) {
        float4 a  = *(const float4*)&W_in[tid * 64 + q * 4];
        float4 b  = *(const float4*)&W_in[(tid + 128) * 64 + q * 4];
        float4 wn = *(const float4*)&w_norm[q * 4];
        wu[4*q+0] = a.x * wn.x; wu[4*q+1] = a.y * wn.y;
        wu[4*q+2] = a.z * wn.z; wu[4*q+3] = a.w * wn.w;
        wz[4*q+0] = b.x * wn.x; wz[4*q+1] = b.y * wn.y;
        wz[4*q+2] = b.z * wn.z; wz[4*q+3] = b.w * wn.w;
    }
    for (int i = tid; i < 512; i += 128) {
        int t = i >> 4, q = i & 15;
        *(float4*)&xs[t * 68 + q * 4] = *(const float4*)&x[(tb + t) * 64 + q * 4];
    }
    __syncthreads();
    if (tid < 32) {
        float ss = 0.f;
        #pragma unroll
        for (int q = 0; q < 16; ++q) {
            float4 v = *(const float4*)&xs[tid * 68 + q * 4];
            ss += v.x*v.x + v.y*v.y + v.z*v.z + v.w*v.w;
        }
        rs[tid] = rsqrtf(ss * (1.f / 64.f) + EPSV);
    }
    __syncthreads();
    float bu = b_in[tid], bz = b_in[tid + 128];
    for (int t = 0; t < 32; ++t) {
        float au0=0.f,au1=0.f,au2=0.f,au3=0.f;
        float az0=0.f,az1=0.f,az2=0.f,az3=0.f;
        #pragma unroll
        for (int q = 0; q < 16; ++q) {
            float4 v = *(const float4*)&xs[t * 68 + q * 4];
            au0 += v.x * wu[4*q+0]; au1 += v.y * wu[4*q+1];
            au2 += v.z * wu[4*q+2]; au3 += v.w * wu[4*q+3];
            az0 += v.x * wz[4*q+0]; az1 += v.y * wz[4*q+1];
            az2 += v.z * wz[4*q+2]; az3 += v.w * wz[4*q+3];
        }
        float r = rs[t];
        float uv = ((au0+au1)+(au2+au3)) * r + bu;
        float zv = ((az0+az1)+(az2+az3)) * r + bz;
        int g = tb + t;
        u_bf[g * 128 + tid] = f2bf(uv);
        z_bf[g * 128 + tid] = f2bf(zv * sig_(zv));
    }
}

// K2 pack: W_conv (O,I,K) -> bf16 Bp[kk][o][c]
__global__ __launch_bounds__(256) void k2_pack(
    const float* __restrict__ W_conv, unsigned short* __restrict__ Bp)
{
    int i = blockIdx.x * 256 + threadIdx.x;
    int kk = i >> 14, o = (i >> 7) & 127, c = i & 127;
    Bp[i] = f2bf(W_conv[o * 512 + c * 4 + kk]);
}

// pack W_xp (36x128, zero-pad to 48) and W_out (64x128) to bf16
__global__ __launch_bounds__(256) void k35_pack(
    const float* __restrict__ W_xp, const float* __restrict__ W_out,
    unsigned short* __restrict__ Wxp_bf, unsigned short* __restrict__ Wout_bf)
{
    int i = blockIdx.x * 256 + threadIdx.x;   // 14336
    if (i < 6144) {
        int j = i >> 7;
        Wxp_bf[i] = (j < 36) ? f2bf(W_xp[i]) : (unsigned short)0;
    } else if (i < 14336) {
        int i2 = i - 6144;
        Wout_bf[i2] = f2bf(W_out[i2]);
    }
}

// K2: conv1d as 4 shifted bf16 GEMMs via MFMA; output u_conv bf16 (+silu).
__global__ __launch_bounds__(256) void k2_conv_mfma(
    const unsigned short* __restrict__ u_bf, const unsigned short* __restrict__ Bp,
    const float* __restrict__ b_conv, unsigned short* __restrict__ u_cbf)
{
    int tid = threadIdx.x;
    int wave = tid >> 6, lane = tid & 63;
    int quad = lane >> 4, l16 = lane & 15;
    int tb = blockIdx.x * 64;
    int bbase = tb & ~4095;
    int t0 = tb + wave * 16;
    f32x4 acc[8];
    #pragma unroll
    for (int og = 0; og < 8; ++og) acc[og] = (f32x4){0.f, 0.f, 0.f, 0.f};
    int row_base = t0 + l16 - 3;
    #pragma unroll
    for (int kk = 0; kk < 4; ++kk) {
        int row = row_base + kk;
        #pragma unroll
        for (int cs = 0; cs < 4; ++cs) {
            int kbase = cs * 32 + quad * 8;
            bf16x8 a = {0,0,0,0,0,0,0,0};
            if (row >= bbase)
                a = *(const bf16x8*)&u_bf[row * 128 + kbase];
            #pragma unroll
            for (int og = 0; og < 8; ++og) {
                bf16x8 b = *(const bf16x8*)&Bp[kk * 16384 + (og * 16 + l16) * 128 + kbase];
                acc[og] = __builtin_amdgcn_mfma_f32_16x16x32_bf16(a, b, acc[og], 0, 0, 0);
            }
        }
    }
    #pragma unroll
    for (int og = 0; og < 8; ++og) {
        int o = og * 16 + l16;
        float bc = b_conv[o];
        #pragma unroll
        for (int r = 0; r < 4; ++r) {
            int t = t0 + quad * 4 + r;
            float v = acc[og][r] + bc;
            u_cbf[t * 128 + o] = f2bf(v * sig_(v));
        }
    }
}

// K3: xp = u @ W_xp^T (MFMA, N padded 36->48) -> Bm,Cm (fp32) + dt -> LDS;
// then delta = softplus(dt @ W_dt^T + b_dt) fp32.
__global__ __launch_bounds__(256) void k3_xproj_mfma(
    const unsigned short* __restrict__ u_cbf, const unsigned short* __restrict__ Wxp_bf,
    const float* __restrict__ b_xp,
    const float* __restrict__ W_dt, const float* __restrict__ b_dt,
    float* __restrict__ delta, float* __restrict__ Bm, float* __restrict__ Cm)
{
    __shared__ float dts[64][4];
    __shared__ float Wd[512];
    __shared__ float bds[128];
    int tid = threadIdx.x;
    if (tid < 128) *(float4*)&Wd[tid * 4] = *(const float4*)&W_dt[tid * 4];
    else if (tid < 160) *(float4*)&bds[(tid - 128) * 4] = *(const float4*)&b_dt[(tid - 128) * 4];
    int wave = tid >> 6, lane = tid & 63;
    int quad = lane >> 4, l16 = lane & 15;
    int t0 = blockIdx.x * 64 + wave * 16;
    f32x4 acc[3];
    #pragma unroll
    for (int nt = 0; nt < 3; ++nt) acc[nt] = (f32x4){0.f, 0.f, 0.f, 0.f};
    #pragma unroll
    for (int cs = 0; cs < 4; ++cs) {
        int kbase = cs * 32 + quad * 8;
        bf16x8 a = *(const bf16x8*)&u_cbf[(t0 + l16) * 128 + kbase];
        #pragma unroll
        for (int nt = 0; nt < 3; ++nt) {
            bf16x8 b = *(const bf16x8*)&Wxp_bf[(nt * 16 + l16) * 128 + kbase];
            acc[nt] = __builtin_amdgcn_mfma_f32_16x16x32_bf16(a, b, acc[nt], 0, 0, 0);
        }
    }
    #pragma unroll
    for (int nt = 0; nt < 3; ++nt) {
        int j = nt * 16 + l16;
        float bx = (j < 36) ? b_xp[j] : 0.f;
        #pragma unroll
        for (int r = 0; r < 4; ++r) {
            int t = t0 + quad * 4 + r;
            float val = acc[nt][r] + bx;
            if (j < 4)       dts[wave * 16 + quad * 4 + r][j] = val;
            else if (j < 20) Bm[t * 16 + (j - 4)]  = val;
            else if (j < 36) Cm[t * 16 + (j - 20)] = val;
        }
    }
    __syncthreads();
    int tokloc = tid >> 2, dgrp = tid & 3;
    float dt0 = dts[tokloc][0], dt1 = dts[tokloc][1],
          dt2 = dts[tokloc][2], dt3 = dts[tokloc][3];
    int g = blockIdx.x * 64 + tokloc;
    #pragma unroll
    for (int d4 = 0; d4 < 8; ++d4) {
        int d = dgrp * 32 + d4 * 4;
        float4 w0 = *(const float4*)&Wd[(d + 0) * 4];
        float4 w1 = *(const float4*)&Wd[(d + 1) * 4];
        float4 w2 = *(const float4*)&Wd[(d + 2) * 4];
        float4 w3 = *(const float4*)&Wd[(d + 3) * 4];
        float4 bdv = *(const float4*)&bds[d];
        float4 r;
        r.x = softplus_(bdv.x + dt0*w0.x + dt1*w0.y + dt2*w0.z + dt3*w0.w);
        r.y = softplus_(bdv.y + dt0*w1.x + dt1*w1.y + dt2*w1.z + dt3*w1.w);
        r.z = softplus_(bdv.z + dt0*w2.x + dt1*w2.y + dt2*w2.z + dt3*w2.w);
        r.w = softplus_(bdv.w + dt0*w3.x + dt1*w3.y + dt2*w3.z + dt3*w3.w);
        *(float4*)&delta[g * 128 + d] = r;
    }
}

// K4a: per-chunk (P,Q) with LDS-staged tiles. Block = (b, chunk, d-half).
__global__ __launch_bounds__(256) void k4a_chunk(
    const float* __restrict__ delta, const unsigned short* __restrict__ u_cbf,
    const float* __restrict__ Bm, const float* __restrict__ A_log,
    float* __restrict__ P, float* __restrict__ Q)
{
    __shared__ float dls[LC * 64];            // 16KB [t][dloc]
    __shared__ unsigned short uls[LC * 64];   // 8KB
    __shared__ float bls[LC * 16];            // 4KB
    int bid = blockIdx.x;                     // 8 x 64 x 2 = 1024
    int b = bid >> 7, c = (bid >> 1) & 63, half = bid & 1;
    int tid = threadIdx.x, lane = tid & 63;
    int g0 = b * LL + c * LC;
    int d0 = half * 64;
    for (int i = tid; i < LC * 16; i += 256) {
        int row = i >> 4, q = i & 15;
        *(float4*)&dls[row * 64 + q * 4] =
            *(const float4*)&delta[(g0 + row) * 128 + d0 + q * 4];
    }
    for (int i = tid; i < LC * 8; i += 256) {
        int row = i >> 3, q = i & 7;
        *(float4*)&uls[row * 64 + q * 8] =
            *(const float4*)&u_cbf[(g0 + row) * 128 + d0 + q * 8];
    }
    for (int i = tid; i < LC * 4; i += 256) {
        int row = i >> 2, q = i & 3;
        *(float4*)&bls[row * 16 + q * 4] =
            *(const float4*)&Bm[(g0 + row) * 16 + q * 4];
    }
    int dloc = (tid >> 6) * 16 + (lane >> 2);
    int d = d0 + dloc;
    int ng = lane & 3;
    float4 Av = *(const float4*)&A_log[d * 16 + ng * 4];
    float A0 = -__expf(Av.x), A1 = -__expf(Av.y), A2 = -__expf(Av.z), A3 = -__expf(Av.w);
    float P0=1.f,P1=1.f,P2=1.f,P3=1.f, Q0=0.f,Q1=0.f,Q2=0.f,Q3=0.f;
    __syncthreads();
    for (int t = 0; t < LC; ++t) {
        float dl = dls[t * 64 + dloc];
        float uu = bf2f(uls[t * 64 + dloc]);
        float4 bm = *(const float4*)&bls[t * 16 + ng * 4];
        float du = dl * uu;
        float a0 = __expf(dl * A0), a1 = __expf(dl * A1),
              a2 = __expf(dl * A2), a3 = __expf(dl * A3);
        P0 *= a0; P1 *= a1; P2 *= a2; P3 *= a3;
        Q0 = a0 * Q0 + du * bm.x; Q1 = a1 * Q1 + du * bm.y;
        Q2 = a2 * Q2 + du * bm.z; Q3 = a3 * Q3 + du * bm.w;
    }
    int idx = (b * NCHUNK + c) * 2048 + d * 16 + ng * 4;
    *(float4*)&P[idx] = (float4){P0, P1, P2, P3};
    *(float4*)&Q[idx] = (float4){Q0, Q1, Q2, Q3};
}

// K4b: carry scan across chunks.
__global__ __launch_bounds__(256) void k4b_carry(
    const float* __restrict__ P, const float* __restrict__ Q, float* __restrict__ Hinit)
{
    int tid = blockIdx.x * 256 + threadIdx.x;  // 16384
    int b = tid >> 11, dn = tid & 2047;
    float carry = 0.f;
    for (int c = 0; c < NCHUNK; ++c) {
        int idx = (b * NCHUNK + c) * 2048 + dn;
        Hinit[idx] = carry;
        carry = P[idx] * carry + Q[idx];
    }
}

// K4c: replay from Hinit with LDS-staged tiles; y = (sum_n h*C) + D*u, *silu(z).
__global__ __launch_bounds__(256) void k4c_scan(
    const float* __restrict__ delta, const unsigned short* __restrict__ u_cbf,
    const float* __restrict__ Bm, const float* __restrict__ Cm,
    const unsigned short* __restrict__ z_bf, const float* __restrict__ A_log,
    const float* __restrict__ D_param, const float* __restrict__ Hinit,
    unsigned short* __restrict__ y_bf)
{
    __shared__ float dls[LC * 64];            // 16KB
    __shared__ unsigned short uls[LC * 64];   // 8KB
    __shared__ float bls[LC * 16];            // 4KB
    __shared__ float cls[LC * 16];            // 4KB
    __shared__ unsigned short zls[LC * 64];   // 8KB
    int bid = blockIdx.x;
    int b = bid >> 7, c = (bid >> 1) & 63, half = bid & 1;
    int tid = threadIdx.x, lane = tid & 63;
    int g0 = b * LL + c * LC;
    int d0 = half * 64;
    for (int i = tid; i < LC * 16; i += 256) {
        int row = i >> 4, q = i & 15;
        *(float4*)&dls[row * 64 + q * 4] =
            *(const float4*)&delta[(g0 + row) * 128 + d0 + q * 4];
    }
    for (int i = tid; i < LC * 8; i += 256) {
        int row = i >> 3, q = i & 7;
        *(float4*)&uls[row * 64 + q * 8] =
            *(const float4*)&u_cbf[(g0 + row) * 128 + d0 + q * 8];
        *(float4*)&zls[row * 64 + q * 8] =
            *(const float4*)&z_bf[(g0 + row) * 128 + d0 + q * 8];
    }
    for (int i = tid; i < LC * 4; i += 256) {
        int row = i >> 2, q = i & 3;
        *(float4*)&bls[row * 16 + q * 4] =
            *(const float4*)&Bm[(g0 + row) * 16 + q * 4];
        *(float4*)&cls[row * 16 + q * 4] =
            *(const float4*)&Cm[(g0 + row) * 16 + q * 4];
    }
    int dloc = (tid >> 6) * 16 + (lane >> 2);
    int d = d0 + dloc;
    int ng = lane & 3;
    float4 Av = *(const float4*)&A_log[d * 16 + ng * 4];
    float A0 = -__expf(Av.x), A1 = -__expf(Av.y), A2 = -__expf(Av.z), A3 = -__expf(Av.w);
    float4 h = *(const float4*)&Hinit[(b * NCHUNK + c) * 2048 + d * 16 + ng * 4];
    float Dp = D_param[d];
    __syncthreads();
    for (int t = 0; t < LC; ++t) {
        float dl = dls[t * 64 + dloc];
        float uu = bf2f(uls[t * 64 + dloc]);
        float4 bm = *(const float4*)&bls[t * 16 + ng * 4];
        float4 cm = *(const float4*)&cls[t * 16 + ng * 4];
        float du = dl * uu;
        float a0 = __expf(dl * A0), a1 = __expf(dl * A1),
              a2 = __expf(dl * A2), a3 = __expf(dl * A3);
        h.x = a0 * h.x + du * bm.x; h.y = a1 * h.y + du * bm.y;
        h.z = a2 * h.z + du * bm.z; h.w = a3 * h.w + du * bm.w;
        float yv = h.x * cm.x + h.y * cm.y + h.z * cm.z + h.w * cm.w;
        yv += __shfl_xor(yv, 1, 64);
        yv += __shfl_xor(yv, 2, 64);
        if (ng == 0) {
            float y = yv + Dp * uu;
            y *= bf2f(zls[t * 64 + dloc]);
            y_bf[(g0 + t) * 128 + d] = f2bf(y);
        }
    }
}

// K5: out = x + y @ W_out^T + b_out via MFMA (N=64).
__global__ __launch_bounds__(256) void k5_outproj_mfma(
    const unsigned short* __restrict__ y_bf, const unsigned short* __restrict__ Wout_bf,
    const float* __restrict__ b_out, const float* __restrict__ x,
    float* __restrict__ out)
{
    int tid = threadIdx.x;
    int wave = tid >> 6, lane = tid & 63;
    int quad = lane >> 4, l16 = lane & 15;
    int t0 = blockIdx.x * 64 + wave * 16;
    f32x4 acc[4];
    #pragma unroll
    for (int nt = 0; nt < 4; ++nt) acc[nt] = (f32x4){0.f, 0.f, 0.f, 0.f};
    #pragma unroll
    for (int cs = 0; cs < 4; ++cs) {
        int kbase = cs * 32 + quad * 8;
        bf16x8 a = *(const bf16x8*)&y_bf[(t0 + l16) * 128 + kbase];
        #pragma unroll
        for (int nt = 0; nt < 4; ++nt) {
            bf16x8 b = *(const bf16x8*)&Wout_bf[(nt * 16 + l16) * 128 + kbase];
            acc[nt] = __builtin_amdgcn_mfma_f32_16x16x32_bf16(a, b, acc[nt], 0, 0, 0);
        }
    }
    #pragma unroll
    for (int nt = 0; nt < 4; ++nt) {
        int m = nt * 16 + l16;
        float bo = b_out[m];
        #pragma unroll
        for (int r = 0; r < 4; ++r) {
            int t = t0 + quad * 4 + r;
            out[t * 64 + m] = acc[nt][r] + bo + x[t * 64 + m];
        }
    }
}

extern "C" void kernel_launch(void* const* d_in, const int* in_sizes, int n_in,
                              void* d_out, int out_size, void* d_ws, size_t ws_size,
                              hipStream_t stream)
{
    const float* x       = (const float*)d_in[0];
    const float* w_norm  = (const float*)d_in[1];
    const float* W_in    = (const float*)d_in[2];
    const float* b_in    = (const float*)d_in[3];
    const float* W_conv  = (const float*)d_in[4];
    const float* b_conv  = (const float*)d_in[5];
    const float* W_xp    = (const float*)d_in[6];
    const float* b_xp    = (const float*)d_in[7];
    const float* W_dt    = (const float*)d_in[8];
    const float* b_dt    = (const float*)d_in[9];
    const float* W_out   = (const float*)d_in[10];
    const float* b_out   = (const float*)d_in[11];
    const float* A_log   = (const float*)d_in[12];
    const float* D_param = (const float*)d_in[13];
    float* ws = (float*)d_ws;

    unsigned short* u_bf = (unsigned short*)ws;            // dead after k2
    unsigned short* y_bf = (unsigned short*)ws;            // reuse after k4c
    unsigned short* z_bf = (unsigned short*)(ws + 2097152);
    unsigned short* u_cbf= (unsigned short*)(ws + 4194304);
    float* delta  = ws + 6291456;
    float* Bm     = ws + 10485760;
    float* Cm     = ws + 11010048;
    float* P      = ws + 11534336;
    float* Q      = ws + 12582912;
    float* Hinit  = ws + 13631488;
    unsigned short* Bp      = (unsigned short*)(ws + 14680064);
    unsigned short* Wxp_bf  = (unsigned short*)(ws + 14712832);
    unsigned short* Wout_bf = (unsigned short*)(ws + 14715904);
    float* out    = (float*)d_out;

    k2_pack<<<256, 256, 0, stream>>>(W_conv, Bp);
    k35_pack<<<56, 256, 0, stream>>>(W_xp, W_out, Wxp_bf, Wout_bf);
    k1_norm_inproj<<<1024, 128, 0, stream>>>(x, w_norm, W_in, b_in, u_bf, z_bf);
    k2_conv_mfma<<<512, 256, 0, stream>>>(u_bf, Bp, b_conv, u_cbf);
    k3_xproj_mfma<<<512, 256, 0, stream>>>(u_cbf, Wxp_bf, b_xp, W_dt, b_dt, delta, Bm, Cm);
    k4a_chunk<<<1024, 256, 0, stream>>>(delta, u_cbf, Bm, A_log, P, Q);
    k4b_carry<<<64, 256, 0, stream>>>(P, Q, Hinit);
    k4c_scan<<<1024, 256, 0, stream>>>(delta, u_cbf, Bm, Cm, z_bf, A_log, D_param, Hinit, y_bf);
    k5_outproj_mfma<<<512, 256, 0, stream>>>(y_bf, Wout_bf, b_out, x, out);
}

// Round 6
// 209.643 us; speedup vs baseline: 3.0412x; 1.0943x over previous
//
#include <hip/hip_runtime.h>
#include <math.h>

#define D_MODEL 64
#define D_STATE 16
#define D_INNER 128
#define DT_RANK 4
#define BB 8
#define LL 4096
#define NTOK (BB*LL)      // 32768
#define EPSV 1e-6f
#define NCHUNK 64
#define LC (LL/NCHUNK)    // 64

typedef __attribute__((ext_vector_type(8))) short bf16x8;
typedef __attribute__((ext_vector_type(4))) float f32x4;

__device__ __forceinline__ float sig_(float v) { return 1.f / (1.f + __expf(-v)); }
__device__ __forceinline__ float softplus_(float v) {
    return (v > 20.f) ? v : __logf(1.f + __expf(v));
}
__device__ __forceinline__ unsigned short f2bf(float x) {
    unsigned int u = __float_as_uint(x);
    u += 0x7fff + ((u >> 16) & 1);      // RNE
    return (unsigned short)(u >> 16);
}
__device__ __forceinline__ float bf2f(unsigned short u) {
    return __uint_as_float(((unsigned int)u) << 16);
}

// pack W_in (256x64) * w_norm -> bf16
__global__ __launch_bounds__(256) void k1_pack(
    const float* __restrict__ W_in, const float* __restrict__ w_norm,
    unsigned short* __restrict__ Win_bf)
{
    int i = blockIdx.x * 256 + threadIdx.x;   // 16384
    Win_bf[i] = f2bf(W_in[i] * w_norm[i & 63]);
}

// K1: fused RMSNorm + in_proj via MFMA + silu(z). 64 tokens/block, 4 waves.
__global__ __launch_bounds__(256) void k1_fused(
    const float* __restrict__ x, const unsigned short* __restrict__ Win_bf,
    const float* __restrict__ b_in,
    unsigned short* __restrict__ u_bf, unsigned short* __restrict__ z_bf)
{
    __shared__ unsigned short axs[64 * 72];   // A-tile bf16, padded stride 72
    int tid = threadIdx.x;
    int tb = blockIdx.x * 64;
    // norm: thread = (token tid>>2, quarter tid&3); 16 floats contiguous
    {
        int t = tid >> 2, qt = tid & 3;
        float4 v[4];
        float ss = 0.f;
        #pragma unroll
        for (int j = 0; j < 4; ++j) {
            v[j] = *(const float4*)&x[(tb + t) * 64 + qt * 16 + j * 4];
            ss += v[j].x*v[j].x + v[j].y*v[j].y + v[j].z*v[j].z + v[j].w*v[j].w;
        }
        ss += __shfl_xor(ss, 1, 64);
        ss += __shfl_xor(ss, 2, 64);
        float r = rsqrtf(ss * (1.f / 64.f) + EPSV);
        unsigned short tmp[16];
        #pragma unroll
        for (int j = 0; j < 4; ++j) {
            tmp[4*j+0] = f2bf(v[j].x * r); tmp[4*j+1] = f2bf(v[j].y * r);
            tmp[4*j+2] = f2bf(v[j].z * r); tmp[4*j+3] = f2bf(v[j].w * r);
        }
        *(bf16x8*)&axs[t * 72 + qt * 16]     = *(bf16x8*)&tmp[0];
        *(bf16x8*)&axs[t * 72 + qt * 16 + 8] = *(bf16x8*)&tmp[8];
    }
    __syncthreads();
    int wave = tid >> 6, lane = tid & 63;
    int quad = lane >> 4, l16 = lane & 15;
    f32x4 acc[16];
    #pragma unroll
    for (int nt = 0; nt < 16; ++nt) acc[nt] = (f32x4){0.f, 0.f, 0.f, 0.f};
    bf16x8 a0 = *(const bf16x8*)&axs[(wave * 16 + l16) * 72 + quad * 8];
    bf16x8 a1 = *(const bf16x8*)&axs[(wave * 16 + l16) * 72 + 32 + quad * 8];
    #pragma unroll
    for (int nt = 0; nt < 16; ++nt) {
        bf16x8 b0 = *(const bf16x8*)&Win_bf[(nt * 16 + l16) * 64 + quad * 8];
        bf16x8 b1 = *(const bf16x8*)&Win_bf[(nt * 16 + l16) * 64 + 32 + quad * 8];
        acc[nt] = __builtin_amdgcn_mfma_f32_16x16x32_bf16(a0, b0, acc[nt], 0, 0, 0);
        acc[nt] = __builtin_amdgcn_mfma_f32_16x16x32_bf16(a1, b1, acc[nt], 0, 0, 0);
    }
    #pragma unroll
    for (int nt = 0; nt < 16; ++nt) {
        int o = nt * 16 + l16;          // 0..255
        float bo = b_in[o];
        #pragma unroll
        for (int r = 0; r < 4; ++r) {
            int t = tb + wave * 16 + quad * 4 + r;
            float v = acc[nt][r] + bo;
            if (o < 128) u_bf[t * 128 + o] = f2bf(v);
            else         z_bf[t * 128 + (o - 128)] = f2bf(v * sig_(v));
        }
    }
}

// K2 pack: W_conv (O,I,K) -> bf16 Bp[kk][o][c]
__global__ __launch_bounds__(256) void k2_pack(
    const float* __restrict__ W_conv, unsigned short* __restrict__ Bp)
{
    int i = blockIdx.x * 256 + threadIdx.x;
    int kk = i >> 14, o = (i >> 7) & 127, c = i & 127;
    Bp[i] = f2bf(W_conv[o * 512 + c * 4 + kk]);
}

// pack W_xp (36x128, zero-pad to 48) and W_out (64x128) to bf16
__global__ __launch_bounds__(256) void k35_pack(
    const float* __restrict__ W_xp, const float* __restrict__ W_out,
    unsigned short* __restrict__ Wxp_bf, unsigned short* __restrict__ Wout_bf)
{
    int i = blockIdx.x * 256 + threadIdx.x;   // 14336
    if (i < 6144) {
        int j = i >> 7;
        Wxp_bf[i] = (j < 36) ? f2bf(W_xp[i]) : (unsigned short)0;
    } else if (i < 14336) {
        int i2 = i - 6144;
        Wout_bf[i2] = f2bf(W_out[i2]);
    }
}

// K2: conv1d as 4 shifted bf16 GEMMs via MFMA; output u_conv bf16 (+silu).
__global__ __launch_bounds__(256) void k2_conv_mfma(
    const unsigned short* __restrict__ u_bf, const unsigned short* __restrict__ Bp,
    const float* __restrict__ b_conv, unsigned short* __restrict__ u_cbf)
{
    int tid = threadIdx.x;
    int wave = tid >> 6, lane = tid & 63;
    int quad = lane >> 4, l16 = lane & 15;
    int tb = blockIdx.x * 64;
    int bbase = tb & ~4095;
    int t0 = tb + wave * 16;
    f32x4 acc[8];
    #pragma unroll
    for (int og = 0; og < 8; ++og) acc[og] = (f32x4){0.f, 0.f, 0.f, 0.f};
    int row_base = t0 + l16 - 3;
    #pragma unroll
    for (int kk = 0; kk < 4; ++kk) {
        int row = row_base + kk;
        #pragma unroll
        for (int cs = 0; cs < 4; ++cs) {
            int kbase = cs * 32 + quad * 8;
            bf16x8 a = {0,0,0,0,0,0,0,0};
            if (row >= bbase)
                a = *(const bf16x8*)&u_bf[row * 128 + kbase];
            #pragma unroll
            for (int og = 0; og < 8; ++og) {
                bf16x8 b = *(const bf16x8*)&Bp[kk * 16384 + (og * 16 + l16) * 128 + kbase];
                acc[og] = __builtin_amdgcn_mfma_f32_16x16x32_bf16(a, b, acc[og], 0, 0, 0);
            }
        }
    }
    #pragma unroll
    for (int og = 0; og < 8; ++og) {
        int o = og * 16 + l16;
        float bc = b_conv[o];
        #pragma unroll
        for (int r = 0; r < 4; ++r) {
            int t = t0 + quad * 4 + r;
            float v = acc[og][r] + bc;
            u_cbf[t * 128 + o] = f2bf(v * sig_(v));
        }
    }
}

// K3: xp = u @ W_xp^T (MFMA, N padded 36->48) -> Bm,Cm (fp32) + dt -> LDS;
// then delta = softplus(dt @ W_dt^T + b_dt) fp32.
__global__ __launch_bounds__(256) void k3_xproj_mfma(
    const unsigned short* __restrict__ u_cbf, const unsigned short* __restrict__ Wxp_bf,
    const float* __restrict__ b_xp,
    const float* __restrict__ W_dt, const float* __restrict__ b_dt,
    float* __restrict__ delta, float* __restrict__ Bm, float* __restrict__ Cm)
{
    __shared__ float dts[64][4];
    __shared__ float Wd[512];
    __shared__ float bds[128];
    int tid = threadIdx.x;
    if (tid < 128) *(float4*)&Wd[tid * 4] = *(const float4*)&W_dt[tid * 4];
    else if (tid < 160) *(float4*)&bds[(tid - 128) * 4] = *(const float4*)&b_dt[(tid - 128) * 4];
    int wave = tid >> 6, lane = tid & 63;
    int quad = lane >> 4, l16 = lane & 15;
    int t0 = blockIdx.x * 64 + wave * 16;
    f32x4 acc[3];
    #pragma unroll
    for (int nt = 0; nt < 3; ++nt) acc[nt] = (f32x4){0.f, 0.f, 0.f, 0.f};
    #pragma unroll
    for (int cs = 0; cs < 4; ++cs) {
        int kbase = cs * 32 + quad * 8;
        bf16x8 a = *(const bf16x8*)&u_cbf[(t0 + l16) * 128 + kbase];
        #pragma unroll
        for (int nt = 0; nt < 3; ++nt) {
            bf16x8 b = *(const bf16x8*)&Wxp_bf[(nt * 16 + l16) * 128 + kbase];
            acc[nt] = __builtin_amdgcn_mfma_f32_16x16x32_bf16(a, b, acc[nt], 0, 0, 0);
        }
    }
    #pragma unroll
    for (int nt = 0; nt < 3; ++nt) {
        int j = nt * 16 + l16;
        float bx = (j < 36) ? b_xp[j] : 0.f;
        #pragma unroll
        for (int r = 0; r < 4; ++r) {
            int t = t0 + quad * 4 + r;
            float val = acc[nt][r] + bx;
            if (j < 4)       dts[wave * 16 + quad * 4 + r][j] = val;
            else if (j < 20) Bm[t * 16 + (j - 4)]  = val;
            else if (j < 36) Cm[t * 16 + (j - 20)] = val;
        }
    }
    __syncthreads();
    int tokloc = tid >> 2, dgrp = tid & 3;
    float dt0 = dts[tokloc][0], dt1 = dts[tokloc][1],
          dt2 = dts[tokloc][2], dt3 = dts[tokloc][3];
    int g = blockIdx.x * 64 + tokloc;
    #pragma unroll
    for (int d4 = 0; d4 < 8; ++d4) {
        int d = dgrp * 32 + d4 * 4;
        float4 w0 = *(const float4*)&Wd[(d + 0) * 4];
        float4 w1 = *(const float4*)&Wd[(d + 1) * 4];
        float4 w2 = *(const float4*)&Wd[(d + 2) * 4];
        float4 w3 = *(const float4*)&Wd[(d + 3) * 4];
        float4 bdv = *(const float4*)&bds[d];
        float4 r;
        r.x = softplus_(bdv.x + dt0*w0.x + dt1*w0.y + dt2*w0.z + dt3*w0.w);
        r.y = softplus_(bdv.y + dt0*w1.x + dt1*w1.y + dt2*w1.z + dt3*w1.w);
        r.z = softplus_(bdv.z + dt0*w2.x + dt1*w2.y + dt2*w2.z + dt3*w2.w);
        r.w = softplus_(bdv.w + dt0*w3.x + dt1*w3.y + dt2*w3.z + dt3*w3.w);
        *(float4*)&delta[g * 128 + d] = r;
    }
}

// K4a: per-chunk (P,Q) with LDS-staged tiles. Block = (b, chunk, d-half).
__global__ __launch_bounds__(256) void k4a_chunk(
    const float* __restrict__ delta, const unsigned short* __restrict__ u_cbf,
    const float* __restrict__ Bm, const float* __restrict__ A_log,
    float* __restrict__ P, float* __restrict__ Q)
{
    __shared__ float dls[LC * 64];            // 16KB [t][dloc]
    __shared__ unsigned short uls[LC * 64];   // 8KB
    __shared__ float bls[LC * 16];            // 4KB
    int bid = blockIdx.x;                     // 8 x 64 x 2 = 1024
    int b = bid >> 7, c = (bid >> 1) & 63, half = bid & 1;
    int tid = threadIdx.x, lane = tid & 63;
    int g0 = b * LL + c * LC;
    int d0 = half * 64;
    for (int i = tid; i < LC * 16; i += 256) {
        int row = i >> 4, q = i & 15;
        *(float4*)&dls[row * 64 + q * 4] =
            *(const float4*)&delta[(g0 + row) * 128 + d0 + q * 4];
    }
    for (int i = tid; i < LC * 8; i += 256) {
        int row = i >> 3, q = i & 7;
        *(float4*)&uls[row * 64 + q * 8] =
            *(const float4*)&u_cbf[(g0 + row) * 128 + d0 + q * 8];
    }
    for (int i = tid; i < LC * 4; i += 256) {
        int row = i >> 2, q = i & 3;
        *(float4*)&bls[row * 16 + q * 4] =
            *(const float4*)&Bm[(g0 + row) * 16 + q * 4];
    }
    int dloc = (tid >> 6) * 16 + (lane >> 2);
    int d = d0 + dloc;
    int ng = lane & 3;
    float4 Av = *(const float4*)&A_log[d * 16 + ng * 4];
    float A0 = -__expf(Av.x), A1 = -__expf(Av.y), A2 = -__expf(Av.z), A3 = -__expf(Av.w);
    float P0=1.f,P1=1.f,P2=1.f,P3=1.f, Q0=0.f,Q1=0.f,Q2=0.f,Q3=0.f;
    __syncthreads();
    for (int t = 0; t < LC; ++t) {
        float dl = dls[t * 64 + dloc];
        float uu = bf2f(uls[t * 64 + dloc]);
        float4 bm = *(const float4*)&bls[t * 16 + ng * 4];
        float du = dl * uu;
        float a0 = __expf(dl * A0), a1 = __expf(dl * A1),
              a2 = __expf(dl * A2), a3 = __expf(dl * A3);
        P0 *= a0; P1 *= a1; P2 *= a2; P3 *= a3;
        Q0 = a0 * Q0 + du * bm.x; Q1 = a1 * Q1 + du * bm.y;
        Q2 = a2 * Q2 + du * bm.z; Q3 = a3 * Q3 + du * bm.w;
    }
    int idx = (b * NCHUNK + c) * 2048 + d * 16 + ng * 4;
    *(float4*)&P[idx] = (float4){P0, P1, P2, P3};
    *(float4*)&Q[idx] = (float4){Q0, Q1, Q2, Q3};
}

// K4b: carry scan across chunks.
__global__ __launch_bounds__(256) void k4b_carry(
    const float* __restrict__ P, const float* __restrict__ Q, float* __restrict__ Hinit)
{
    int tid = blockIdx.x * 256 + threadIdx.x;  // 16384
    int b = tid >> 11, dn = tid & 2047;
    float carry = 0.f;
    for (int c = 0; c < NCHUNK; ++c) {
        int idx = (b * NCHUNK + c) * 2048 + dn;
        Hinit[idx] = carry;
        carry = P[idx] * carry + Q[idx];
    }
}

// K4c: replay from Hinit with LDS-staged tiles; y = (sum_n h*C) + D*u, *silu(z).
__global__ __launch_bounds__(256) void k4c_scan(
    const float* __restrict__ delta, const unsigned short* __restrict__ u_cbf,
    const float* __restrict__ Bm, const float* __restrict__ Cm,
    const unsigned short* __restrict__ z_bf, const float* __restrict__ A_log,
    const float* __restrict__ D_param, const float* __restrict__ Hinit,
    unsigned short* __restrict__ y_bf)
{
    __shared__ float dls[LC * 64];            // 16KB
    __shared__ unsigned short uls[LC * 64];   // 8KB
    __shared__ float bls[LC * 16];            // 4KB
    __shared__ float cls[LC * 16];            // 4KB
    __shared__ unsigned short zls[LC * 64];   // 8KB
    int bid = blockIdx.x;
    int b = bid >> 7, c = (bid >> 1) & 63, half = bid & 1;
    int tid = threadIdx.x, lane = tid & 63;
    int g0 = b * LL + c * LC;
    int d0 = half * 64;
    for (int i = tid; i < LC * 16; i += 256) {
        int row = i >> 4, q = i & 15;
        *(float4*)&dls[row * 64 + q * 4] =
            *(const float4*)&delta[(g0 + row) * 128 + d0 + q * 4];
    }
    for (int i = tid; i < LC * 8; i += 256) {
        int row = i >> 3, q = i & 7;
        *(float4*)&uls[row * 64 + q * 8] =
            *(const float4*)&u_cbf[(g0 + row) * 128 + d0 + q * 8];
        *(float4*)&zls[row * 64 + q * 8] =
            *(const float4*)&z_bf[(g0 + row) * 128 + d0 + q * 8];
    }
    for (int i = tid; i < LC * 4; i += 256) {
        int row = i >> 2, q = i & 3;
        *(float4*)&bls[row * 16 + q * 4] =
            *(const float4*)&Bm[(g0 + row) * 16 + q * 4];
        *(float4*)&cls[row * 16 + q * 4] =
            *(const float4*)&Cm[(g0 + row) * 16 + q * 4];
    }
    int dloc = (tid >> 6) * 16 + (lane >> 2);
    int d = d0 + dloc;
    int ng = lane & 3;
    float4 Av = *(const float4*)&A_log[d * 16 + ng * 4];
    float A0 = -__expf(Av.x), A1 = -__expf(Av.y), A2 = -__expf(Av.z), A3 = -__expf(Av.w);
    float4 h = *(const float4*)&Hinit[(b * NCHUNK + c) * 2048 + d * 16 + ng * 4];
    float Dp = D_param[d];
    __syncthreads();
    for (int t = 0; t < LC; ++t) {
        float dl = dls[t * 64 + dloc];
        float uu = bf2f(uls[t * 64 + dloc]);
        float4 bm = *(const float4*)&bls[t * 16 + ng * 4];
        float4 cm = *(const float4*)&cls[t * 16 + ng * 4];
        float du = dl * uu;
        float a0 = __expf(dl * A0), a1 = __expf(dl * A1),
              a2 = __expf(dl * A2), a3 = __expf(dl * A3);
        h.x = a0 * h.x + du * bm.x; h.y = a1 * h.y + du * bm.y;
        h.z = a2 * h.z + du * bm.z; h.w = a3 * h.w + du * bm.w;
        float yv = h.x * cm.x + h.y * cm.y + h.z * cm.z + h.w * cm.w;
        yv += __shfl_xor(yv, 1, 64);
        yv += __shfl_xor(yv, 2, 64);
        if (ng == 0) {
            float y = yv + Dp * uu;
            y *= bf2f(zls[t * 64 + dloc]);
            y_bf[(g0 + t) * 128 + d] = f2bf(y);
        }
    }
}

// K5: out = x + y @ W_out^T + b_out via MFMA (N=64).
__global__ __launch_bounds__(256) void k5_outproj_mfma(
    const unsigned short* __restrict__ y_bf, const unsigned short* __restrict__ Wout_bf,
    const float* __restrict__ b_out, const float* __restrict__ x,
    float* __restrict__ out)
{
    int tid = threadIdx.x;
    int wave = tid >> 6, lane = tid & 63;
    int quad = lane >> 4, l16 = lane & 15;
    int t0 = blockIdx.x * 64 + wave * 16;
    f32x4 acc[4];
    #pragma unroll
    for (int nt = 0; nt < 4; ++nt) acc[nt] = (f32x4){0.f, 0.f, 0.f, 0.f};
    #pragma unroll
    for (int cs = 0; cs < 4; ++cs) {
        int kbase = cs * 32 + quad * 8;
        bf16x8 a = *(const bf16x8*)&y_bf[(t0 + l16) * 128 + kbase];
        #pragma unroll
        for (int nt = 0; nt < 4; ++nt) {
            bf16x8 b = *(const bf16x8*)&Wout_bf[(nt * 16 + l16) * 128 + kbase];
            acc[nt] = __builtin_amdgcn_mfma_f32_16x16x32_bf16(a, b, acc[nt], 0, 0, 0);
        }
    }
    #pragma unroll
    for (int nt = 0; nt < 4; ++nt) {
        int m = nt * 16 + l16;
        float bo = b_out[m];
        #pragma unroll
        for (int r = 0; r < 4; ++r) {
            int t = t0 + quad * 4 + r;
            out[t * 64 + m] = acc[nt][r] + bo + x[t * 64 + m];
        }
    }
}

extern "C" void kernel_launch(void* const* d_in, const int* in_sizes, int n_in,
                              void* d_out, int out_size, void* d_ws, size_t ws_size,
                              hipStream_t stream)
{
    const float* x       = (const float*)d_in[0];
    const float* w_norm  = (const float*)d_in[1];
    const float* W_in    = (const float*)d_in[2];
    const float* b_in    = (const float*)d_in[3];
    const float* W_conv  = (const float*)d_in[4];
    const float* b_conv  = (const float*)d_in[5];
    const float* W_xp    = (const float*)d_in[6];
    const float* b_xp    = (const float*)d_in[7];
    const float* W_dt    = (const float*)d_in[8];
    const float* b_dt    = (const float*)d_in[9];
    const float* W_out   = (const float*)d_in[10];
    const float* b_out   = (const float*)d_in[11];
    const float* A_log   = (const float*)d_in[12];
    const float* D_param = (const float*)d_in[13];
    float* ws = (float*)d_ws;

    unsigned short* u_bf = (unsigned short*)ws;            // dead after k2
    unsigned short* y_bf = (unsigned short*)ws;            // reuse after k4c
    unsigned short* z_bf = (unsigned short*)(ws + 2097152);
    unsigned short* u_cbf= (unsigned short*)(ws + 4194304);
    float* delta  = ws + 6291456;
    float* Bm     = ws + 10485760;
    float* Cm     = ws + 11010048;
    float* P      = ws + 11534336;
    float* Q      = ws + 12582912;
    float* Hinit  = ws + 13631488;
    unsigned short* Bp      = (unsigned short*)(ws + 14680064);
    unsigned short* Wxp_bf  = (unsigned short*)(ws + 14712832);
    unsigned short* Wout_bf = (unsigned short*)(ws + 14715904);
    unsigned short* Win_bf  = (unsigned short*)(ws + 14720000);
    float* out    = (float*)d_out;

    k1_pack<<<64, 256, 0, stream>>>(W_in, w_norm, Win_bf);
    k2_pack<<<256, 256, 0, stream>>>(W_conv, Bp);
    k35_pack<<<56, 256, 0, stream>>>(W_xp, W_out, Wxp_bf, Wout_bf);
    k1_fused<<<512, 256, 0, stream>>>(x, Win_bf, b_in, u_bf, z_bf);
    k2_conv_mfma<<<512, 256, 0, stream>>>(u_bf, Bp, b_conv, u_cbf);
    k3_xproj_mfma<<<512, 256, 0, stream>>>(u_cbf, Wxp_bf, b_xp, W_dt, b_dt, delta, Bm, Cm);
    k4a_chunk<<<1024, 256, 0, stream>>>(delta, u_cbf, Bm, A_log, P, Q);
    k4b_carry<<<64, 256, 0, stream>>>(P, Q, Hinit);
    k4c_scan<<<1024, 256, 0, stream>>>(delta, u_cbf, Bm, Cm, z_bf, A_log, D_param, Hinit, y_bf);
    k5_outproj_mfma<<<512, 256, 0, stream>>>(y_bf, Wout_bf, b_out, x, out);
}

// Round 8
// 199.931 us; speedup vs baseline: 3.1889x; 1.0486x over previous
//
#include <hip/hip_runtime.h>
#include <math.h>

#define D_MODEL 64
#define D_STATE 16
#define D_INNER 128
#define DT_RANK 4
#define BB 8
#define LL 4096
#define NTOK (BB*LL)      // 32768
#define EPSV 1e-6f
#define NCHUNK 64
#define LC (LL/NCHUNK)    // 64
#define PAD 136           // LDS row stride (shorts): 16B-aligned, 2-way max alias

typedef __attribute__((ext_vector_type(8))) short bf16x8;
typedef __attribute__((ext_vector_type(4))) float f32x4;

__device__ __forceinline__ float sig_(float v) { return 1.f / (1.f + __expf(-v)); }
__device__ __forceinline__ float softplus_(float v) {
    return (v > 20.f) ? v : __logf(1.f + __expf(v));
}
__device__ __forceinline__ unsigned short f2bf(float x) {
    unsigned int u = __float_as_uint(x);
    u += 0x7fff + ((u >> 16) & 1);      // RNE
    return (unsigned short)(u >> 16);
}
__device__ __forceinline__ float bf2f(unsigned short u) {
    return __uint_as_float(((unsigned int)u) << 16);
}

// Pack all weights to bf16 in one kernel.
__global__ __launch_bounds__(256) void pack_all(
    const float* __restrict__ W_in, const float* __restrict__ w_norm,
    const float* __restrict__ W_conv, const float* __restrict__ W_xp,
    const float* __restrict__ W_out,
    unsigned short* __restrict__ Win_bf, unsigned short* __restrict__ Bp,
    unsigned short* __restrict__ Wxp_bf, unsigned short* __restrict__ Wout_bf)
{
    int i = blockIdx.x * 256 + threadIdx.x;
    if (i < 16384) {
        Win_bf[i] = f2bf(W_in[i] * w_norm[i & 63]);
    } else if (i < 81920) {
        int j = i - 16384;
        int kk = j >> 14, o = (j >> 7) & 127, c = j & 127;
        Bp[j] = f2bf(W_conv[o * 512 + c * 4 + kk]);
    } else if (i < 88064) {
        int j = i - 81920;
        Wxp_bf[j] = ((j >> 7) < 36) ? f2bf(W_xp[j]) : (unsigned short)0;
    } else if (i < 96256) {
        int j = i - 88064;
        Wout_bf[j] = f2bf(W_out[j]);
    }
}

// K1: fused RMSNorm + in_proj via MFMA + silu(z). 64 tokens/block, 4 waves.
__global__ __launch_bounds__(256) void k1_fused(
    const float* __restrict__ x, const unsigned short* __restrict__ Win_bf,
    const float* __restrict__ b_in,
    unsigned short* __restrict__ u_bf, unsigned short* __restrict__ z_bf)
{
    __shared__ unsigned short axs[64 * 72];
    int tid = threadIdx.x;
    int tb = blockIdx.x * 64;
    {
        int t = tid >> 2, qt = tid & 3;
        float4 v[4];
        float ss = 0.f;
        #pragma unroll
        for (int j = 0; j < 4; ++j) {
            v[j] = *(const float4*)&x[(tb + t) * 64 + qt * 16 + j * 4];
            ss += v[j].x*v[j].x + v[j].y*v[j].y + v[j].z*v[j].z + v[j].w*v[j].w;
        }
        ss += __shfl_xor(ss, 1, 64);
        ss += __shfl_xor(ss, 2, 64);
        float r = rsqrtf(ss * (1.f / 64.f) + EPSV);
        unsigned short tmp[16];
        #pragma unroll
        for (int j = 0; j < 4; ++j) {
            tmp[4*j+0] = f2bf(v[j].x * r); tmp[4*j+1] = f2bf(v[j].y * r);
            tmp[4*j+2] = f2bf(v[j].z * r); tmp[4*j+3] = f2bf(v[j].w * r);
        }
        *(bf16x8*)&axs[t * 72 + qt * 16]     = *(bf16x8*)&tmp[0];
        *(bf16x8*)&axs[t * 72 + qt * 16 + 8] = *(bf16x8*)&tmp[8];
    }
    __syncthreads();
    int wave = tid >> 6, lane = tid & 63;
    int quad = lane >> 4, l16 = lane & 15;
    f32x4 acc[16];
    #pragma unroll
    for (int nt = 0; nt < 16; ++nt) acc[nt] = (f32x4){0.f, 0.f, 0.f, 0.f};
    bf16x8 a0 = *(const bf16x8*)&axs[(wave * 16 + l16) * 72 + quad * 8];
    bf16x8 a1 = *(const bf16x8*)&axs[(wave * 16 + l16) * 72 + 32 + quad * 8];
    #pragma unroll
    for (int nt = 0; nt < 16; ++nt) {
        bf16x8 b0 = *(const bf16x8*)&Win_bf[(nt * 16 + l16) * 64 + quad * 8];
        bf16x8 b1 = *(const bf16x8*)&Win_bf[(nt * 16 + l16) * 64 + 32 + quad * 8];
        acc[nt] = __builtin_amdgcn_mfma_f32_16x16x32_bf16(a0, b0, acc[nt], 0, 0, 0);
        acc[nt] = __builtin_amdgcn_mfma_f32_16x16x32_bf16(a1, b1, acc[nt], 0, 0, 0);
    }
    #pragma unroll
    for (int nt = 0; nt < 16; ++nt) {
        int o = nt * 16 + l16;
        float bo = b_in[o];
        #pragma unroll
        for (int r = 0; r < 4; ++r) {
            int t = tb + wave * 16 + quad * 4 + r;
            float v = acc[nt][r] + bo;
            if (o < 128) u_bf[t * 128 + o] = f2bf(v);
            else         z_bf[t * 128 + (o - 128)] = f2bf(v * sig_(v));
        }
    }
}

// K2+K3 fused: conv1d (4 shifted bf16 MFMA GEMMs) + silu -> u_cbf (global)
// and LDS tile; then x-proj MFMA -> Bm,Cm + dt -> delta = softplus(...).
__global__ __launch_bounds__(256) void k2k3_fused(
    const unsigned short* __restrict__ u_bf, const unsigned short* __restrict__ Bp,
    const float* __restrict__ b_conv,
    const unsigned short* __restrict__ Wxp_bf, const float* __restrict__ b_xp,
    const float* __restrict__ W_dt, const float* __restrict__ b_dt,
    unsigned short* __restrict__ u_cbf, float* __restrict__ delta,
    float* __restrict__ Bm, float* __restrict__ Cm)
{
    __shared__ unsigned short uls[64 * PAD];   // 17.4 KB
    __shared__ float dts[64][4];
    __shared__ float Wd[512];
    __shared__ float bds[128];
    int tid = threadIdx.x;
    if (tid < 128) *(float4*)&Wd[tid * 4] = *(const float4*)&W_dt[tid * 4];
    else if (tid < 160) *(float4*)&bds[(tid - 128) * 4] = *(const float4*)&b_dt[(tid - 128) * 4];
    int wave = tid >> 6, lane = tid & 63;
    int quad = lane >> 4, l16 = lane & 15;
    int tb = blockIdx.x * 64;
    int bbase = tb & ~4095;
    int t0 = tb + wave * 16;
    f32x4 acc[8];
    #pragma unroll
    for (int og = 0; og < 8; ++og) acc[og] = (f32x4){0.f, 0.f, 0.f, 0.f};
    int row_base = t0 + l16 - 3;
    #pragma unroll
    for (int kk = 0; kk < 4; ++kk) {
        int row = row_base + kk;
        #pragma unroll
        for (int cs = 0; cs < 4; ++cs) {
            int kbase = cs * 32 + quad * 8;
            bf16x8 a = {0,0,0,0,0,0,0,0};
            if (row >= bbase)
                a = *(const bf16x8*)&u_bf[row * 128 + kbase];
            #pragma unroll
            for (int og = 0; og < 8; ++og) {
                bf16x8 b = *(const bf16x8*)&Bp[kk * 16384 + (og * 16 + l16) * 128 + kbase];
                acc[og] = __builtin_amdgcn_mfma_f32_16x16x32_bf16(a, b, acc[og], 0, 0, 0);
            }
        }
    }
    #pragma unroll
    for (int og = 0; og < 8; ++og) {
        int o = og * 16 + l16;
        float bc = b_conv[o];
        #pragma unroll
        for (int r = 0; r < 4; ++r) {
            int tloc = wave * 16 + quad * 4 + r;
            float v = acc[og][r] + bc;
            unsigned short ub = f2bf(v * sig_(v));
            u_cbf[(tb + tloc) * 128 + o] = ub;
            uls[tloc * PAD + o] = ub;
        }
    }
    __syncthreads();
    // x-proj: M=64 tokens (16/wave), N=48 (36 padded), K=128
    f32x4 xacc[3];
    #pragma unroll
    for (int nt = 0; nt < 3; ++nt) xacc[nt] = (f32x4){0.f, 0.f, 0.f, 0.f};
    #pragma unroll
    for (int cs = 0; cs < 4; ++cs) {
        int kbase = cs * 32 + quad * 8;
        bf16x8 a = *(const bf16x8*)&uls[(wave * 16 + l16) * PAD + kbase];
        #pragma unroll
        for (int nt = 0; nt < 3; ++nt) {
            bf16x8 b = *(const bf16x8*)&Wxp_bf[(nt * 16 + l16) * 128 + kbase];
            xacc[nt] = __builtin_amdgcn_mfma_f32_16x16x32_bf16(a, b, xacc[nt], 0, 0, 0);
        }
    }
    #pragma unroll
    for (int nt = 0; nt < 3; ++nt) {
        int j = nt * 16 + l16;
        float bx = (j < 36) ? b_xp[j] : 0.f;
        #pragma unroll
        for (int r = 0; r < 4; ++r) {
            int tloc = wave * 16 + quad * 4 + r;
            int t = tb + tloc;
            float val = xacc[nt][r] + bx;
            if (j < 4)       dts[tloc][j] = val;
            else if (j < 20) Bm[t * 16 + (j - 4)]  = val;
            else if (j < 36) Cm[t * 16 + (j - 20)] = val;
        }
    }
    __syncthreads();
    int tokloc = tid >> 2, dgrp = tid & 3;
    float dt0 = dts[tokloc][0], dt1 = dts[tokloc][1],
          dt2 = dts[tokloc][2], dt3 = dts[tokloc][3];
    int g = tb + tokloc;
    #pragma unroll
    for (int d4 = 0; d4 < 8; ++d4) {
        int d = dgrp * 32 + d4 * 4;
        float4 w0 = *(const float4*)&Wd[(d + 0) * 4];
        float4 w1 = *(const float4*)&Wd[(d + 1) * 4];
        float4 w2 = *(const float4*)&Wd[(d + 2) * 4];
        float4 w3 = *(const float4*)&Wd[(d + 3) * 4];
        float4 bdv = *(const float4*)&bds[d];
        float4 r;
        r.x = softplus_(bdv.x + dt0*w0.x + dt1*w0.y + dt2*w0.z + dt3*w0.w);
        r.y = softplus_(bdv.y + dt0*w1.x + dt1*w1.y + dt2*w1.z + dt3*w1.w);
        r.z = softplus_(bdv.z + dt0*w2.x + dt1*w2.y + dt2*w2.z + dt3*w2.w);
        r.w = softplus_(bdv.w + dt0*w3.x + dt1*w3.y + dt2*w3.z + dt3*w3.w);
        *(float4*)&delta[g * 128 + d] = r;
    }
}

// K4a: per-chunk (P,Q) with LDS-staged tiles. Block = (b, chunk, d-half).
__global__ __launch_bounds__(256) void k4a_chunk(
    const float* __restrict__ delta, const unsigned short* __restrict__ u_cbf,
    const float* __restrict__ Bm, const float* __restrict__ A_log,
    float* __restrict__ P, float* __restrict__ Q)
{
    __shared__ float dls[LC * 64];
    __shared__ unsigned short uls[LC * 64];
    __shared__ float bls[LC * 16];
    int bid = blockIdx.x;                     // 8 x 64 x 2 = 1024
    int b = bid >> 7, c = (bid >> 1) & 63, half = bid & 1;
    int tid = threadIdx.x, lane = tid & 63;
    int g0 = b * LL + c * LC;
    int d0 = half * 64;
    for (int i = tid; i < LC * 16; i += 256) {
        int row = i >> 4, q = i & 15;
        *(float4*)&dls[row * 64 + q * 4] =
            *(const float4*)&delta[(g0 + row) * 128 + d0 + q * 4];
    }
    for (int i = tid; i < LC * 8; i += 256) {
        int row = i >> 3, q = i & 7;
        *(float4*)&uls[row * 64 + q * 8] =
            *(const float4*)&u_cbf[(g0 + row) * 128 + d0 + q * 8];
    }
    for (int i = tid; i < LC * 4; i += 256) {
        int row = i >> 2, q = i & 3;
        *(float4*)&bls[row * 16 + q * 4] =
            *(const float4*)&Bm[(g0 + row) * 16 + q * 4];
    }
    int dloc = (tid >> 6) * 16 + (lane >> 2);
    int d = d0 + dloc;
    int ng = lane & 3;
    float4 Av = *(const float4*)&A_log[d * 16 + ng * 4];
    float A0 = -__expf(Av.x), A1 = -__expf(Av.y), A2 = -__expf(Av.z), A3 = -__expf(Av.w);
    float P0=1.f,P1=1.f,P2=1.f,P3=1.f, Q0=0.f,Q1=0.f,Q2=0.f,Q3=0.f;
    __syncthreads();
    for (int t = 0; t < LC; ++t) {
        float dl = dls[t * 64 + dloc];
        float uu = bf2f(uls[t * 64 + dloc]);
        float4 bm = *(const float4*)&bls[t * 16 + ng * 4];
        float du = dl * uu;
        float a0 = __expf(dl * A0), a1 = __expf(dl * A1),
              a2 = __expf(dl * A2), a3 = __expf(dl * A3);
        P0 *= a0; P1 *= a1; P2 *= a2; P3 *= a3;
        Q0 = a0 * Q0 + du * bm.x; Q1 = a1 * Q1 + du * bm.y;
        Q2 = a2 * Q2 + du * bm.z; Q3 = a3 * Q3 + du * bm.w;
    }
    int idx = (b * NCHUNK + c) * 2048 + d * 16 + ng * 4;
    *(float4*)&P[idx] = (float4){P0, P1, P2, P3};
    *(float4*)&Q[idx] = (float4){Q0, Q1, Q2, Q3};
}

// K4b: carry scan across chunks.
__global__ __launch_bounds__(256) void k4b_carry(
    const float* __restrict__ P, const float* __restrict__ Q, float* __restrict__ Hinit)
{
    int tid = blockIdx.x * 256 + threadIdx.x;  // 16384
    int b = tid >> 11, dn = tid & 2047;
    float carry = 0.f;
    for (int c = 0; c < NCHUNK; ++c) {
        int idx = (b * NCHUNK + c) * 2048 + dn;
        Hinit[idx] = carry;
        carry = P[idx] * carry + Q[idx];
    }
}

// K4c: replay from Hinit with LDS-staged tiles; y = (sum_n h*C) + D*u, *silu(z).
__global__ __launch_bounds__(256) void k4c_scan(
    const float* __restrict__ delta, const unsigned short* __restrict__ u_cbf,
    const float* __restrict__ Bm, const float* __restrict__ Cm,
    const unsigned short* __restrict__ z_bf, const float* __restrict__ A_log,
    const float* __restrict__ D_param, const float* __restrict__ Hinit,
    unsigned short* __restrict__ y_bf)
{
    __shared__ float dls[LC * 64];
    __shared__ unsigned short uls[LC * 64];
    __shared__ float bls[LC * 16];
    __shared__ float cls[LC * 16];
    __shared__ unsigned short zls[LC * 64];
    int bid = blockIdx.x;
    int b = bid >> 7, c = (bid >> 1) & 63, half = bid & 1;
    int tid = threadIdx.x, lane = tid & 63;
    int g0 = b * LL + c * LC;
    int d0 = half * 64;
    for (int i = tid; i < LC * 16; i += 256) {
        int row = i >> 4, q = i & 15;
        *(float4*)&dls[row * 64 + q * 4] =
            *(const float4*)&delta[(g0 + row) * 128 + d0 + q * 4];
    }
    for (int i = tid; i < LC * 8; i += 256) {
        int row = i >> 3, q = i & 7;
        *(float4*)&uls[row * 64 + q * 8] =
            *(const float4*)&u_cbf[(g0 + row) * 128 + d0 + q * 8];
        *(float4*)&zls[row * 64 + q * 8] =
            *(const float4*)&z_bf[(g0 + row) * 128 + d0 + q * 8];
    }
    for (int i = tid; i < LC * 4; i += 256) {
        int row = i >> 2, q = i & 3;
        *(float4*)&bls[row * 16 + q * 4] =
            *(const float4*)&Bm[(g0 + row) * 16 + q * 4];
        *(float4*)&cls[row * 16 + q * 4] =
            *(const float4*)&Cm[(g0 + row) * 16 + q * 4];
    }
    int dloc = (tid >> 6) * 16 + (lane >> 2);
    int d = d0 + dloc;
    int ng = lane & 3;
    float4 Av = *(const float4*)&A_log[d * 16 + ng * 4];
    float A0 = -__expf(Av.x), A1 = -__expf(Av.y), A2 = -__expf(Av.z), A3 = -__expf(Av.w);
    float4 h = *(const float4*)&Hinit[(b * NCHUNK + c) * 2048 + d * 16 + ng * 4];
    float Dp = D_param[d];
    __syncthreads();
    for (int t = 0; t < LC; ++t) {
        float dl = dls[t * 64 + dloc];
        float uu = bf2f(uls[t * 64 + dloc]);
        float4 bm = *(const float4*)&bls[t * 16 + ng * 4];
        float4 cm = *(const float4*)&cls[t * 16 + ng * 4];
        float du = dl * uu;
        float a0 = __expf(dl * A0), a1 = __expf(dl * A1),
              a2 = __expf(dl * A2), a3 = __expf(dl * A3);
        h.x = a0 * h.x + du * bm.x; h.y = a1 * h.y + du * bm.y;
        h.z = a2 * h.z + du * bm.z; h.w = a3 * h.w + du * bm.w;
        float yv = h.x * cm.x + h.y * cm.y + h.z * cm.z + h.w * cm.w;
        yv += __shfl_xor(yv, 1, 64);
        yv += __shfl_xor(yv, 2, 64);
        if (ng == 0) {
            float y = yv + Dp * uu;
            y *= bf2f(zls[t * 64 + dloc]);
            y_bf[(g0 + t) * 128 + d] = f2bf(y);
        }
    }
}

// K5: out = x + y @ W_out^T + b_out via MFMA (N=64).
__global__ __launch_bounds__(256) void k5_outproj_mfma(
    const unsigned short* __restrict__ y_bf, const unsigned short* __restrict__ Wout_bf,
    const float* __restrict__ b_out, const float* __restrict__ x,
    float* __restrict__ out)
{
    int tid = threadIdx.x;
    int wave = tid >> 6, lane = tid & 63;
    int quad = lane >> 4, l16 = lane & 15;
    int t0 = blockIdx.x * 64 + wave * 16;
    f32x4 acc[4];
    #pragma unroll
    for (int nt = 0; nt < 4; ++nt) acc[nt] = (f32x4){0.f, 0.f, 0.f, 0.f};
    #pragma unroll
    for (int cs = 0; cs < 4; ++cs) {
        int kbase = cs * 32 + quad * 8;
        bf16x8 a = *(const bf16x8*)&y_bf[(t0 + l16) * 128 + kbase];
        #pragma unroll
        for (int nt = 0; nt < 4; ++nt) {
            bf16x8 b = *(const bf16x8*)&Wout_bf[(nt * 16 + l16) * 128 + kbase];
            acc[nt] = __builtin_amdgcn_mfma_f32_16x16x32_bf16(a, b, acc[nt], 0, 0, 0);
        }
    }
    #pragma unroll
    for (int nt = 0; nt < 4; ++nt) {
        int m = nt * 16 + l16;
        float bo = b_out[m];
        #pragma unroll
        for (int r = 0; r < 4; ++r) {
            int t = t0 + quad * 4 + r;
            out[t * 64 + m] = acc[nt][r] + bo + x[t * 64 + m];
        }
    }
}

extern "C" void kernel_launch(void* const* d_in, const int* in_sizes, int n_in,
                              void* d_out, int out_size, void* d_ws, size_t ws_size,
                              hipStream_t stream)
{
    const float* x       = (const float*)d_in[0];
    const float* w_norm  = (const float*)d_in[1];
    const float* W_in    = (const float*)d_in[2];
    const float* b_in    = (const float*)d_in[3];
    const float* W_conv  = (const float*)d_in[4];
    const float* b_conv  = (const float*)d_in[5];
    const float* W_xp    = (const float*)d_in[6];
    const float* b_xp    = (const float*)d_in[7];
    const float* W_dt    = (const float*)d_in[8];
    const float* b_dt    = (const float*)d_in[9];
    const float* W_out   = (const float*)d_in[10];
    const float* b_out   = (const float*)d_in[11];
    const float* A_log   = (const float*)d_in[12];
    const float* D_param = (const float*)d_in[13];
    float* ws = (float*)d_ws;

    unsigned short* u_bf = (unsigned short*)ws;            // dead after k2k3
    unsigned short* y_bf = (unsigned short*)ws;            // reuse after k4c
    unsigned short* z_bf = (unsigned short*)(ws + 2097152);
    unsigned short* u_cbf= (unsigned short*)(ws + 4194304);
    float* delta  = ws + 6291456;
    float* Bm     = ws + 10485760;
    float* Cm     = ws + 11010048;
    float* P      = ws + 11534336;
    float* Q      = ws + 12582912;
    float* Hinit  = ws + 13631488;
    unsigned short* Bp      = (unsigned short*)(ws + 14680064);
    unsigned short* Wxp_bf  = (unsigned short*)(ws + 14712832);
    unsigned short* Wout_bf = (unsigned short*)(ws + 14715904);
    unsigned short* Win_bf  = (unsigned short*)(ws + 14720000);
    float* out    = (float*)d_out;

    pack_all<<<376, 256, 0, stream>>>(W_in, w_norm, W_conv, W_xp, W_out,
                                      Win_bf, Bp, Wxp_bf, Wout_bf);
    k1_fused<<<512, 256, 0, stream>>>(x, Win_bf, b_in, u_bf, z_bf);
    k2k3_fused<<<512, 256, 0, stream>>>(u_bf, Bp, b_conv, Wxp_bf, b_xp,
                                        W_dt, b_dt, u_cbf, delta, Bm, Cm);
    k4a_chunk<<<1024, 256, 0, stream>>>(delta, u_cbf, Bm, A_log, P, Q);
    k4b_carry<<<64, 256, 0, stream>>>(P, Q, Hinit);
    k4c_scan<<<1024, 256, 0, stream>>>(delta, u_cbf, Bm, Cm, z_bf, A_log,
                                       D_param, Hinit, y_bf);
    k5_outproj_mfma<<<512, 256, 0, stream>>>(y_bf, Wout_bf, b_out, x, out);
}

// Round 9
// 196.915 us; speedup vs baseline: 3.2378x; 1.0153x over previous
//
#include <hip/hip_runtime.h>
#include <math.h>

#define D_MODEL 64
#define D_STATE 16
#define D_INNER 128
#define DT_RANK 4
#define BB 8
#define LL 4096
#define NTOK (BB*LL)      // 32768
#define EPSV 1e-6f
#define NCHUNK 64
#define LC (LL/NCHUNK)    // 64
#define PAD 136           // bf16 LDS row stride (shorts)
#define PADF 132          // fp32 LDS row stride (floats)

typedef __attribute__((ext_vector_type(8))) short bf16x8;
typedef __attribute__((ext_vector_type(4))) float f32x4;

__device__ __forceinline__ float sig_(float v) { return 1.f / (1.f + __expf(-v)); }
__device__ __forceinline__ float softplus_(float v) {
    return (v > 20.f) ? v : __logf(1.f + __expf(v));
}
__device__ __forceinline__ unsigned short f2bf(float x) {
    unsigned int u = __float_as_uint(x);
    u += 0x7fff + ((u >> 16) & 1);      // RNE
    return (unsigned short)(u >> 16);
}
__device__ __forceinline__ float bf2f(unsigned short u) {
    return __uint_as_float(((unsigned int)u) << 16);
}

// Pack all weights to bf16 in one kernel.
__global__ __launch_bounds__(256) void pack_all(
    const float* __restrict__ W_in, const float* __restrict__ w_norm,
    const float* __restrict__ W_conv, const float* __restrict__ W_xp,
    const float* __restrict__ W_out,
    unsigned short* __restrict__ Win_bf, unsigned short* __restrict__ Bp,
    unsigned short* __restrict__ Wxp_bf, unsigned short* __restrict__ Wout_bf)
{
    int i = blockIdx.x * 256 + threadIdx.x;
    if (i < 16384) {
        Win_bf[i] = f2bf(W_in[i] * w_norm[i & 63]);
    } else if (i < 81920) {
        int j = i - 16384;
        int kk = j >> 14, o = (j >> 7) & 127, c = j & 127;
        Bp[j] = f2bf(W_conv[o * 512 + c * 4 + kk]);
    } else if (i < 88064) {
        int j = i - 81920;
        Wxp_bf[j] = ((j >> 7) < 36) ? f2bf(W_xp[j]) : (unsigned short)0;
    } else if (i < 96256) {
        int j = i - 88064;
        Wout_bf[j] = f2bf(W_out[j]);
    }
}

// K1: fused RMSNorm + in_proj via MFMA + silu(z). 64 tokens/block, 4 waves.
__global__ __launch_bounds__(256) void k1_fused(
    const float* __restrict__ x, const unsigned short* __restrict__ Win_bf,
    const float* __restrict__ b_in,
    unsigned short* __restrict__ u_bf, unsigned short* __restrict__ z_bf)
{
    __shared__ unsigned short axs[64 * 72];
    int tid = threadIdx.x;
    int tb = blockIdx.x * 64;
    {
        int t = tid >> 2, qt = tid & 3;
        float4 v[4];
        float ss = 0.f;
        #pragma unroll
        for (int j = 0; j < 4; ++j) {
            v[j] = *(const float4*)&x[(tb + t) * 64 + qt * 16 + j * 4];
            ss += v[j].x*v[j].x + v[j].y*v[j].y + v[j].z*v[j].z + v[j].w*v[j].w;
        }
        ss += __shfl_xor(ss, 1, 64);
        ss += __shfl_xor(ss, 2, 64);
        float r = rsqrtf(ss * (1.f / 64.f) + EPSV);
        unsigned short tmp[16];
        #pragma unroll
        for (int j = 0; j < 4; ++j) {
            tmp[4*j+0] = f2bf(v[j].x * r); tmp[4*j+1] = f2bf(v[j].y * r);
            tmp[4*j+2] = f2bf(v[j].z * r); tmp[4*j+3] = f2bf(v[j].w * r);
        }
        *(bf16x8*)&axs[t * 72 + qt * 16]     = *(bf16x8*)&tmp[0];
        *(bf16x8*)&axs[t * 72 + qt * 16 + 8] = *(bf16x8*)&tmp[8];
    }
    __syncthreads();
    int wave = tid >> 6, lane = tid & 63;
    int quad = lane >> 4, l16 = lane & 15;
    f32x4 acc[16];
    #pragma unroll
    for (int nt = 0; nt < 16; ++nt) acc[nt] = (f32x4){0.f, 0.f, 0.f, 0.f};
    bf16x8 a0 = *(const bf16x8*)&axs[(wave * 16 + l16) * 72 + quad * 8];
    bf16x8 a1 = *(const bf16x8*)&axs[(wave * 16 + l16) * 72 + 32 + quad * 8];
    #pragma unroll
    for (int nt = 0; nt < 16; ++nt) {
        bf16x8 b0 = *(const bf16x8*)&Win_bf[(nt * 16 + l16) * 64 + quad * 8];
        bf16x8 b1 = *(const bf16x8*)&Win_bf[(nt * 16 + l16) * 64 + 32 + quad * 8];
        acc[nt] = __builtin_amdgcn_mfma_f32_16x16x32_bf16(a0, b0, acc[nt], 0, 0, 0);
        acc[nt] = __builtin_amdgcn_mfma_f32_16x16x32_bf16(a1, b1, acc[nt], 0, 0, 0);
    }
    #pragma unroll
    for (int nt = 0; nt < 16; ++nt) {
        int o = nt * 16 + l16;
        float bo = b_in[o];
        #pragma unroll
        for (int r = 0; r < 4; ++r) {
            int t = tb + wave * 16 + quad * 4 + r;
            float v = acc[nt][r] + bo;
            if (o < 128) u_bf[t * 128 + o] = f2bf(v);
            else         z_bf[t * 128 + (o - 128)] = f2bf(v * sig_(v));
        }
    }
}

// K2+K3+K4a fused: conv1d MFMA + silu -> u_cbf + LDS; x-proj MFMA -> Bm,Cm
// (+ Bm LDS); delta epilogue -> delta global + fp32 LDS; then chunk P/Q scan
// (block == one chunk: blockIdx.x == b*NCHUNK + c).
__global__ __launch_bounds__(256) void k2k3a_fused(
    const unsigned short* __restrict__ u_bf, const unsigned short* __restrict__ Bp,
    const float* __restrict__ b_conv,
    const unsigned short* __restrict__ Wxp_bf, const float* __restrict__ b_xp,
    const float* __restrict__ W_dt, const float* __restrict__ b_dt,
    const float* __restrict__ A_log,
    unsigned short* __restrict__ u_cbf, float* __restrict__ delta,
    float* __restrict__ Bm, float* __restrict__ Cm,
    float* __restrict__ P, float* __restrict__ Q)
{
    __shared__ unsigned short uls[64 * PAD];   // 17.4 KB (bf16 u_conv)
    __shared__ float dls[64 * PADF];           // 33.8 KB (fp32 delta)
    __shared__ float bls[64 * 16];             // 4 KB (fp32 Bm)
    __shared__ float dts[64][4];
    __shared__ float Wd[512];
    __shared__ float bds[128];
    int tid = threadIdx.x;
    if (tid < 128) *(float4*)&Wd[tid * 4] = *(const float4*)&W_dt[tid * 4];
    else if (tid < 160) *(float4*)&bds[(tid - 128) * 4] = *(const float4*)&b_dt[(tid - 128) * 4];
    int wave = tid >> 6, lane = tid & 63;
    int quad = lane >> 4, l16 = lane & 15;
    int tb = blockIdx.x * 64;
    int bbase = tb & ~4095;
    int t0 = tb + wave * 16;
    // ---- phase 1: conv ----
    f32x4 acc[8];
    #pragma unroll
    for (int og = 0; og < 8; ++og) acc[og] = (f32x4){0.f, 0.f, 0.f, 0.f};
    int row_base = t0 + l16 - 3;
    #pragma unroll
    for (int kk = 0; kk < 4; ++kk) {
        int row = row_base + kk;
        #pragma unroll
        for (int cs = 0; cs < 4; ++cs) {
            int kbase = cs * 32 + quad * 8;
            bf16x8 a = {0,0,0,0,0,0,0,0};
            if (row >= bbase)
                a = *(const bf16x8*)&u_bf[row * 128 + kbase];
            #pragma unroll
            for (int og = 0; og < 8; ++og) {
                bf16x8 b = *(const bf16x8*)&Bp[kk * 16384 + (og * 16 + l16) * 128 + kbase];
                acc[og] = __builtin_amdgcn_mfma_f32_16x16x32_bf16(a, b, acc[og], 0, 0, 0);
            }
        }
    }
    #pragma unroll
    for (int og = 0; og < 8; ++og) {
        int o = og * 16 + l16;
        float bc = b_conv[o];
        #pragma unroll
        for (int r = 0; r < 4; ++r) {
            int tloc = wave * 16 + quad * 4 + r;
            float v = acc[og][r] + bc;
            unsigned short ub = f2bf(v * sig_(v));
            u_cbf[(tb + tloc) * 128 + o] = ub;
            uls[tloc * PAD + o] = ub;
        }
    }
    __syncthreads();
    // ---- phase 2: x-proj (M=64, N=48 padded, K=128) ----
    f32x4 xacc[3];
    #pragma unroll
    for (int nt = 0; nt < 3; ++nt) xacc[nt] = (f32x4){0.f, 0.f, 0.f, 0.f};
    #pragma unroll
    for (int cs = 0; cs < 4; ++cs) {
        int kbase = cs * 32 + quad * 8;
        bf16x8 a = *(const bf16x8*)&uls[(wave * 16 + l16) * PAD + kbase];
        #pragma unroll
        for (int nt = 0; nt < 3; ++nt) {
            bf16x8 b = *(const bf16x8*)&Wxp_bf[(nt * 16 + l16) * 128 + kbase];
            xacc[nt] = __builtin_amdgcn_mfma_f32_16x16x32_bf16(a, b, xacc[nt], 0, 0, 0);
        }
    }
    #pragma unroll
    for (int nt = 0; nt < 3; ++nt) {
        int j = nt * 16 + l16;
        float bx = (j < 36) ? b_xp[j] : 0.f;
        #pragma unroll
        for (int r = 0; r < 4; ++r) {
            int tloc = wave * 16 + quad * 4 + r;
            int t = tb + tloc;
            float val = xacc[nt][r] + bx;
            if (j < 4) {
                dts[tloc][j] = val;
            } else if (j < 20) {
                Bm[t * 16 + (j - 4)] = val;
                bls[tloc * 16 + (j - 4)] = val;
            } else if (j < 36) {
                Cm[t * 16 + (j - 20)] = val;
            }
        }
    }
    __syncthreads();
    // ---- phase 3: delta = softplus(dt @ W_dt^T + b_dt) ----
    {
        int tokloc = tid >> 2, dgrp = tid & 3;
        float dt0 = dts[tokloc][0], dt1 = dts[tokloc][1],
              dt2 = dts[tokloc][2], dt3 = dts[tokloc][3];
        int g = tb + tokloc;
        #pragma unroll
        for (int d4 = 0; d4 < 8; ++d4) {
            int d = dgrp * 32 + d4 * 4;
            float4 w0 = *(const float4*)&Wd[(d + 0) * 4];
            float4 w1 = *(const float4*)&Wd[(d + 1) * 4];
            float4 w2 = *(const float4*)&Wd[(d + 2) * 4];
            float4 w3 = *(const float4*)&Wd[(d + 3) * 4];
            float4 bdv = *(const float4*)&bds[d];
            float4 r;
            r.x = softplus_(bdv.x + dt0*w0.x + dt1*w0.y + dt2*w0.z + dt3*w0.w);
            r.y = softplus_(bdv.y + dt0*w1.x + dt1*w1.y + dt2*w1.z + dt3*w1.w);
            r.z = softplus_(bdv.z + dt0*w2.x + dt1*w2.y + dt2*w2.z + dt3*w2.w);
            r.w = softplus_(bdv.w + dt0*w3.x + dt1*w3.y + dt2*w3.z + dt3*w3.w);
            *(float4*)&delta[g * 128 + d] = r;
            *(float4*)&dls[tokloc * PADF + d] = r;
        }
    }
    __syncthreads();
    // ---- phase 4: chunk P/Q scan (thread = d=tid>>1, n-oct=tid&1; 8 chains) ----
    {
        int d = tid >> 1;
        int nb = (tid & 1) * 8;
        float4 Av0 = *(const float4*)&A_log[d * 16 + nb];
        float4 Av1 = *(const float4*)&A_log[d * 16 + nb + 4];
        float A0 = -__expf(Av0.x), A1 = -__expf(Av0.y),
              A2 = -__expf(Av0.z), A3 = -__expf(Av0.w);
        float A4 = -__expf(Av1.x), A5 = -__expf(Av1.y),
              A6 = -__expf(Av1.z), A7 = -__expf(Av1.w);
        float P0=1.f,P1=1.f,P2=1.f,P3=1.f,P4=1.f,P5=1.f,P6=1.f,P7=1.f;
        float Q0=0.f,Q1=0.f,Q2=0.f,Q3=0.f,Q4=0.f,Q5=0.f,Q6=0.f,Q7=0.f;
        for (int t = 0; t < LC; ++t) {
            float dl = dls[t * PADF + d];
            float uu = bf2f(uls[t * PAD + d]);
            float4 bm0 = *(const float4*)&bls[t * 16 + nb];
            float4 bm1 = *(const float4*)&bls[t * 16 + nb + 4];
            float du = dl * uu;
            float a0 = __expf(dl * A0), a1 = __expf(dl * A1),
                  a2 = __expf(dl * A2), a3 = __expf(dl * A3);
            float a4 = __expf(dl * A4), a5 = __expf(dl * A5),
                  a6 = __expf(dl * A6), a7 = __expf(dl * A7);
            P0 *= a0; P1 *= a1; P2 *= a2; P3 *= a3;
            P4 *= a4; P5 *= a5; P6 *= a6; P7 *= a7;
            Q0 = a0 * Q0 + du * bm0.x; Q1 = a1 * Q1 + du * bm0.y;
            Q2 = a2 * Q2 + du * bm0.z; Q3 = a3 * Q3 + du * bm0.w;
            Q4 = a4 * Q4 + du * bm1.x; Q5 = a5 * Q5 + du * bm1.y;
            Q6 = a6 * Q6 + du * bm1.z; Q7 = a7 * Q7 + du * bm1.w;
        }
        int idx = blockIdx.x * 2048 + d * 16 + nb;   // blockIdx.x == b*NCHUNK+c
        *(float4*)&P[idx]     = (float4){P0, P1, P2, P3};
        *(float4*)&P[idx + 4] = (float4){P4, P5, P6, P7};
        *(float4*)&Q[idx]     = (float4){Q0, Q1, Q2, Q3};
        *(float4*)&Q[idx + 4] = (float4){Q4, Q5, Q6, Q7};
    }
}

// K4b: carry scan across chunks.
__global__ __launch_bounds__(256) void k4b_carry(
    const float* __restrict__ P, const float* __restrict__ Q, float* __restrict__ Hinit)
{
    int tid = blockIdx.x * 256 + threadIdx.x;  // 16384
    int b = tid >> 11, dn = tid & 2047;
    float carry = 0.f;
    for (int c = 0; c < NCHUNK; ++c) {
        int idx = (b * NCHUNK + c) * 2048 + dn;
        Hinit[idx] = carry;
        carry = P[idx] * carry + Q[idx];
    }
}

// K4c: replay from Hinit with LDS-staged tiles; y = (sum_n h*C) + D*u, *silu(z).
__global__ __launch_bounds__(256) void k4c_scan(
    const float* __restrict__ delta, const unsigned short* __restrict__ u_cbf,
    const float* __restrict__ Bm, const float* __restrict__ Cm,
    const unsigned short* __restrict__ z_bf, const float* __restrict__ A_log,
    const float* __restrict__ D_param, const float* __restrict__ Hinit,
    unsigned short* __restrict__ y_bf)
{
    __shared__ float dls[LC * 64];
    __shared__ unsigned short uls[LC * 64];
    __shared__ float bls[LC * 16];
    __shared__ float cls[LC * 16];
    __shared__ unsigned short zls[LC * 64];
    int bid = blockIdx.x;
    int b = bid >> 7, c = (bid >> 1) & 63, half = bid & 1;
    int tid = threadIdx.x, lane = tid & 63;
    int g0 = b * LL + c * LC;
    int d0 = half * 64;
    for (int i = tid; i < LC * 16; i += 256) {
        int row = i >> 4, q = i & 15;
        *(float4*)&dls[row * 64 + q * 4] =
            *(const float4*)&delta[(g0 + row) * 128 + d0 + q * 4];
    }
    for (int i = tid; i < LC * 8; i += 256) {
        int row = i >> 3, q = i & 7;
        *(float4*)&uls[row * 64 + q * 8] =
            *(const float4*)&u_cbf[(g0 + row) * 128 + d0 + q * 8];
        *(float4*)&zls[row * 64 + q * 8] =
            *(const float4*)&z_bf[(g0 + row) * 128 + d0 + q * 8];
    }
    for (int i = tid; i < LC * 4; i += 256) {
        int row = i >> 2, q = i & 3;
        *(float4*)&bls[row * 16 + q * 4] =
            *(const float4*)&Bm[(g0 + row) * 16 + q * 4];
        *(float4*)&cls[row * 16 + q * 4] =
            *(const float4*)&Cm[(g0 + row) * 16 + q * 4];
    }
    int dloc = (tid >> 6) * 16 + (lane >> 2);
    int d = d0 + dloc;
    int ng = lane & 3;
    float4 Av = *(const float4*)&A_log[d * 16 + ng * 4];
    float A0 = -__expf(Av.x), A1 = -__expf(Av.y), A2 = -__expf(Av.z), A3 = -__expf(Av.w);
    float4 h = *(const float4*)&Hinit[(b * NCHUNK + c) * 2048 + d * 16 + ng * 4];
    float Dp = D_param[d];
    __syncthreads();
    for (int t = 0; t < LC; ++t) {
        float dl = dls[t * 64 + dloc];
        float uu = bf2f(uls[t * 64 + dloc]);
        float4 bm = *(const float4*)&bls[t * 16 + ng * 4];
        float4 cm = *(const float4*)&cls[t * 16 + ng * 4];
        float du = dl * uu;
        float a0 = __expf(dl * A0), a1 = __expf(dl * A1),
              a2 = __expf(dl * A2), a3 = __expf(dl * A3);
        h.x = a0 * h.x + du * bm.x; h.y = a1 * h.y + du * bm.y;
        h.z = a2 * h.z + du * bm.z; h.w = a3 * h.w + du * bm.w;
        float yv = h.x * cm.x + h.y * cm.y + h.z * cm.z + h.w * cm.w;
        yv += __shfl_xor(yv, 1, 64);
        yv += __shfl_xor(yv, 2, 64);
        if (ng == 0) {
            float y = yv + Dp * uu;
            y *= bf2f(zls[t * 64 + dloc]);
            y_bf[(g0 + t) * 128 + d] = f2bf(y);
        }
    }
}

// K5: out = x + y @ W_out^T + b_out via MFMA (N=64).
__global__ __launch_bounds__(256) void k5_outproj_mfma(
    const unsigned short* __restrict__ y_bf, const unsigned short* __restrict__ Wout_bf,
    const float* __restrict__ b_out, const float* __restrict__ x,
    float* __restrict__ out)
{
    int tid = threadIdx.x;
    int wave = tid >> 6, lane = tid & 63;
    int quad = lane >> 4, l16 = lane & 15;
    int t0 = blockIdx.x * 64 + wave * 16;
    f32x4 acc[4];
    #pragma unroll
    for (int nt = 0; nt < 4; ++nt) acc[nt] = (f32x4){0.f, 0.f, 0.f, 0.f};
    #pragma unroll
    for (int cs = 0; cs < 4; ++cs) {
        int kbase = cs * 32 + quad * 8;
        bf16x8 a = *(const bf16x8*)&y_bf[(t0 + l16) * 128 + kbase];
        #pragma unroll
        for (int nt = 0; nt < 4; ++nt) {
            bf16x8 b = *(const bf16x8*)&Wout_bf[(nt * 16 + l16) * 128 + kbase];
            acc[nt] = __builtin_amdgcn_mfma_f32_16x16x32_bf16(a, b, acc[nt], 0, 0, 0);
        }
    }
    #pragma unroll
    for (int nt = 0; nt < 4; ++nt) {
        int m = nt * 16 + l16;
        float bo = b_out[m];
        #pragma unroll
        for (int r = 0; r < 4; ++r) {
            int t = t0 + quad * 4 + r;
            out[t * 64 + m] = acc[nt][r] + bo + x[t * 64 + m];
        }
    }
}

extern "C" void kernel_launch(void* const* d_in, const int* in_sizes, int n_in,
                              void* d_out, int out_size, void* d_ws, size_t ws_size,
                              hipStream_t stream)
{
    const float* x       = (const float*)d_in[0];
    const float* w_norm  = (const float*)d_in[1];
    const float* W_in    = (const float*)d_in[2];
    const float* b_in    = (const float*)d_in[3];
    const float* W_conv  = (const float*)d_in[4];
    const float* b_conv  = (const float*)d_in[5];
    const float* W_xp    = (const float*)d_in[6];
    const float* b_xp    = (const float*)d_in[7];
    const float* W_dt    = (const float*)d_in[8];
    const float* b_dt    = (const float*)d_in[9];
    const float* W_out   = (const float*)d_in[10];
    const float* b_out   = (const float*)d_in[11];
    const float* A_log   = (const float*)d_in[12];
    const float* D_param = (const float*)d_in[13];
    float* ws = (float*)d_ws;

    unsigned short* u_bf = (unsigned short*)ws;            // dead after k2k3a
    unsigned short* y_bf = (unsigned short*)ws;            // reuse after k4c
    unsigned short* z_bf = (unsigned short*)(ws + 2097152);
    unsigned short* u_cbf= (unsigned short*)(ws + 4194304);
    float* delta  = ws + 6291456;
    float* Bm     = ws + 10485760;
    float* Cm     = ws + 11010048;
    float* P      = ws + 11534336;
    float* Q      = ws + 12582912;
    float* Hinit  = ws + 13631488;
    unsigned short* Bp      = (unsigned short*)(ws + 14680064);
    unsigned short* Wxp_bf  = (unsigned short*)(ws + 14712832);
    unsigned short* Wout_bf = (unsigned short*)(ws + 14715904);
    unsigned short* Win_bf  = (unsigned short*)(ws + 14720000);
    float* out    = (float*)d_out;

    pack_all<<<376, 256, 0, stream>>>(W_in, w_norm, W_conv, W_xp, W_out,
                                      Win_bf, Bp, Wxp_bf, Wout_bf);
    k1_fused<<<512, 256, 0, stream>>>(x, Win_bf, b_in, u_bf, z_bf);
    k2k3a_fused<<<512, 256, 0, stream>>>(u_bf, Bp, b_conv, Wxp_bf, b_xp,
                                         W_dt, b_dt, A_log,
                                         u_cbf, delta, Bm, Cm, P, Q);
    k4b_carry<<<64, 256, 0, stream>>>(P, Q, Hinit);
    k4c_scan<<<1024, 256, 0, stream>>>(delta, u_cbf, Bm, Cm, z_bf, A_log,
                                       D_param, Hinit, y_bf);
    k5_outproj_mfma<<<512, 256, 0, stream>>>(y_bf, Wout_bf, b_out, x, out);
}

// Round 10
// 188.855 us; speedup vs baseline: 3.3759x; 1.0427x over previous
//
#include <hip/hip_runtime.h>
#include <math.h>

#define D_MODEL 64
#define D_STATE 16
#define D_INNER 128
#define DT_RANK 4
#define BB 8
#define LL 4096
#define NTOK (BB*LL)      // 32768
#define EPSV 1e-6f
#define NCHUNK 64
#define LC (LL/NCHUNK)    // 64
#define PAD 136           // bf16 LDS row stride (shorts)
#define PADF 132          // fp32 LDS row stride (floats)

typedef __attribute__((ext_vector_type(8))) short bf16x8;
typedef __attribute__((ext_vector_type(4))) float f32x4;

__device__ __forceinline__ float sig_(float v) { return 1.f / (1.f + __expf(-v)); }
__device__ __forceinline__ float softplus_(float v) {
    return (v > 20.f) ? v : __logf(1.f + __expf(v));
}
__device__ __forceinline__ unsigned short f2bf(float x) {
    unsigned int u = __float_as_uint(x);
    u += 0x7fff + ((u >> 16) & 1);      // RNE
    return (unsigned short)(u >> 16);
}
__device__ __forceinline__ float bf2f(unsigned short u) {
    return __uint_as_float(((unsigned int)u) << 16);
}
__device__ __forceinline__ unsigned int pack2bf(float a, float b) {
    return (unsigned int)f2bf(a) | ((unsigned int)f2bf(b) << 16);
}

// Pack all weights to bf16 in one kernel.
__global__ __launch_bounds__(256) void pack_all(
    const float* __restrict__ W_in, const float* __restrict__ w_norm,
    const float* __restrict__ W_conv, const float* __restrict__ W_xp,
    const float* __restrict__ W_out,
    unsigned short* __restrict__ Win_bf, unsigned short* __restrict__ Bp,
    unsigned short* __restrict__ Wxp_bf, unsigned short* __restrict__ Wout_bf)
{
    int i = blockIdx.x * 256 + threadIdx.x;
    if (i < 16384) {
        Win_bf[i] = f2bf(W_in[i] * w_norm[i & 63]);
    } else if (i < 81920) {
        int j = i - 16384;
        int kk = j >> 14, o = (j >> 7) & 127, c = j & 127;
        Bp[j] = f2bf(W_conv[o * 512 + c * 4 + kk]);
    } else if (i < 88064) {
        int j = i - 81920;
        Wxp_bf[j] = ((j >> 7) < 36) ? f2bf(W_xp[j]) : (unsigned short)0;
    } else if (i < 96256) {
        int j = i - 88064;
        Wout_bf[j] = f2bf(W_out[j]);
    }
}

// K1: fused RMSNorm + in_proj via MFMA + silu(z). 64 tokens/block, 4 waves.
__global__ __launch_bounds__(256) void k1_fused(
    const float* __restrict__ x, const unsigned short* __restrict__ Win_bf,
    const float* __restrict__ b_in,
    unsigned short* __restrict__ u_bf, unsigned short* __restrict__ z_bf)
{
    __shared__ unsigned short axs[64 * 72];
    int tid = threadIdx.x;
    int tb = blockIdx.x * 64;
    {
        int t = tid >> 2, qt = tid & 3;
        float4 v[4];
        float ss = 0.f;
        #pragma unroll
        for (int j = 0; j < 4; ++j) {
            v[j] = *(const float4*)&x[(tb + t) * 64 + qt * 16 + j * 4];
            ss += v[j].x*v[j].x + v[j].y*v[j].y + v[j].z*v[j].z + v[j].w*v[j].w;
        }
        ss += __shfl_xor(ss, 1, 64);
        ss += __shfl_xor(ss, 2, 64);
        float r = rsqrtf(ss * (1.f / 64.f) + EPSV);
        unsigned short tmp[16];
        #pragma unroll
        for (int j = 0; j < 4; ++j) {
            tmp[4*j+0] = f2bf(v[j].x * r); tmp[4*j+1] = f2bf(v[j].y * r);
            tmp[4*j+2] = f2bf(v[j].z * r); tmp[4*j+3] = f2bf(v[j].w * r);
        }
        *(bf16x8*)&axs[t * 72 + qt * 16]     = *(bf16x8*)&tmp[0];
        *(bf16x8*)&axs[t * 72 + qt * 16 + 8] = *(bf16x8*)&tmp[8];
    }
    __syncthreads();
    int wave = tid >> 6, lane = tid & 63;
    int quad = lane >> 4, l16 = lane & 15;
    f32x4 acc[16];
    #pragma unroll
    for (int nt = 0; nt < 16; ++nt) acc[nt] = (f32x4){0.f, 0.f, 0.f, 0.f};
    bf16x8 a0 = *(const bf16x8*)&axs[(wave * 16 + l16) * 72 + quad * 8];
    bf16x8 a1 = *(const bf16x8*)&axs[(wave * 16 + l16) * 72 + 32 + quad * 8];
    #pragma unroll
    for (int nt = 0; nt < 16; ++nt) {
        bf16x8 b0 = *(const bf16x8*)&Win_bf[(nt * 16 + l16) * 64 + quad * 8];
        bf16x8 b1 = *(const bf16x8*)&Win_bf[(nt * 16 + l16) * 64 + 32 + quad * 8];
        acc[nt] = __builtin_amdgcn_mfma_f32_16x16x32_bf16(a0, b0, acc[nt], 0, 0, 0);
        acc[nt] = __builtin_amdgcn_mfma_f32_16x16x32_bf16(a1, b1, acc[nt], 0, 0, 0);
    }
    #pragma unroll
    for (int nt = 0; nt < 16; ++nt) {
        int o = nt * 16 + l16;
        float bo = b_in[o];
        #pragma unroll
        for (int r = 0; r < 4; ++r) {
            int t = tb + wave * 16 + quad * 4 + r;
            float v = acc[nt][r] + bo;
            if (o < 128) u_bf[t * 128 + o] = f2bf(v);
            else         z_bf[t * 128 + (o - 128)] = f2bf(v * sig_(v));
        }
    }
}

// K2+K3+K4a fused: conv1d MFMA + silu -> u_cbf + LDS; x-proj MFMA -> Bm,Cm
// (+ Bm LDS); delta epilogue -> delta global + fp32 LDS; then chunk P/Q scan
// (block == one chunk: blockIdx.x == b*NCHUNK + c).
__global__ __launch_bounds__(256) void k2k3a_fused(
    const unsigned short* __restrict__ u_bf, const unsigned short* __restrict__ Bp,
    const float* __restrict__ b_conv,
    const unsigned short* __restrict__ Wxp_bf, const float* __restrict__ b_xp,
    const float* __restrict__ W_dt, const float* __restrict__ b_dt,
    const float* __restrict__ A_log,
    unsigned short* __restrict__ u_cbf, float* __restrict__ delta,
    float* __restrict__ Bm, float* __restrict__ Cm,
    float* __restrict__ P, float* __restrict__ Q)
{
    __shared__ unsigned short uls[64 * PAD];   // 17.4 KB (bf16 u_conv)
    __shared__ float dls[64 * PADF];           // 33.8 KB (fp32 delta)
    __shared__ float bls[64 * 16];             // 4 KB (fp32 Bm)
    __shared__ float dts[64][4];
    __shared__ float Wd[512];
    __shared__ float bds[128];
    int tid = threadIdx.x;
    if (tid < 128) *(float4*)&Wd[tid * 4] = *(const float4*)&W_dt[tid * 4];
    else if (tid < 160) *(float4*)&bds[(tid - 128) * 4] = *(const float4*)&b_dt[(tid - 128) * 4];
    int wave = tid >> 6, lane = tid & 63;
    int quad = lane >> 4, l16 = lane & 15;
    int tb = blockIdx.x * 64;
    int bbase = tb & ~4095;
    int t0 = tb + wave * 16;
    // ---- phase 1: conv ----
    f32x4 acc[8];
    #pragma unroll
    for (int og = 0; og < 8; ++og) acc[og] = (f32x4){0.f, 0.f, 0.f, 0.f};
    int row_base = t0 + l16 - 3;
    #pragma unroll
    for (int kk = 0; kk < 4; ++kk) {
        int row = row_base + kk;
        #pragma unroll
        for (int cs = 0; cs < 4; ++cs) {
            int kbase = cs * 32 + quad * 8;
            bf16x8 a = {0,0,0,0,0,0,0,0};
            if (row >= bbase)
                a = *(const bf16x8*)&u_bf[row * 128 + kbase];
            #pragma unroll
            for (int og = 0; og < 8; ++og) {
                bf16x8 b = *(const bf16x8*)&Bp[kk * 16384 + (og * 16 + l16) * 128 + kbase];
                acc[og] = __builtin_amdgcn_mfma_f32_16x16x32_bf16(a, b, acc[og], 0, 0, 0);
            }
        }
    }
    #pragma unroll
    for (int og = 0; og < 8; ++og) {
        int o = og * 16 + l16;
        float bc = b_conv[o];
        #pragma unroll
        for (int r = 0; r < 4; ++r) {
            int tloc = wave * 16 + quad * 4 + r;
            float v = acc[og][r] + bc;
            unsigned short ub = f2bf(v * sig_(v));
            u_cbf[(tb + tloc) * 128 + o] = ub;
            uls[tloc * PAD + o] = ub;
        }
    }
    __syncthreads();
    // ---- phase 2: x-proj (M=64, N=48 padded, K=128) ----
    f32x4 xacc[3];
    #pragma unroll
    for (int nt = 0; nt < 3; ++nt) xacc[nt] = (f32x4){0.f, 0.f, 0.f, 0.f};
    #pragma unroll
    for (int cs = 0; cs < 4; ++cs) {
        int kbase = cs * 32 + quad * 8;
        bf16x8 a = *(const bf16x8*)&uls[(wave * 16 + l16) * PAD + kbase];
        #pragma unroll
        for (int nt = 0; nt < 3; ++nt) {
            bf16x8 b = *(const bf16x8*)&Wxp_bf[(nt * 16 + l16) * 128 + kbase];
            xacc[nt] = __builtin_amdgcn_mfma_f32_16x16x32_bf16(a, b, xacc[nt], 0, 0, 0);
        }
    }
    #pragma unroll
    for (int nt = 0; nt < 3; ++nt) {
        int j = nt * 16 + l16;
        float bx = (j < 36) ? b_xp[j] : 0.f;
        #pragma unroll
        for (int r = 0; r < 4; ++r) {
            int tloc = wave * 16 + quad * 4 + r;
            int t = tb + tloc;
            float val = xacc[nt][r] + bx;
            if (j < 4) {
                dts[tloc][j] = val;
            } else if (j < 20) {
                Bm[t * 16 + (j - 4)] = val;
                bls[tloc * 16 + (j - 4)] = val;
            } else if (j < 36) {
                Cm[t * 16 + (j - 20)] = val;
            }
        }
    }
    __syncthreads();
    // ---- phase 3: delta = softplus(dt @ W_dt^T + b_dt) ----
    {
        int tokloc = tid >> 2, dgrp = tid & 3;
        float dt0 = dts[tokloc][0], dt1 = dts[tokloc][1],
              dt2 = dts[tokloc][2], dt3 = dts[tokloc][3];
        int g = tb + tokloc;
        #pragma unroll
        for (int d4 = 0; d4 < 8; ++d4) {
            int d = dgrp * 32 + d4 * 4;
            float4 w0 = *(const float4*)&Wd[(d + 0) * 4];
            float4 w1 = *(const float4*)&Wd[(d + 1) * 4];
            float4 w2 = *(const float4*)&Wd[(d + 2) * 4];
            float4 w3 = *(const float4*)&Wd[(d + 3) * 4];
            float4 bdv = *(const float4*)&bds[d];
            float4 r;
            r.x = softplus_(bdv.x + dt0*w0.x + dt1*w0.y + dt2*w0.z + dt3*w0.w);
            r.y = softplus_(bdv.y + dt0*w1.x + dt1*w1.y + dt2*w1.z + dt3*w1.w);
            r.z = softplus_(bdv.z + dt0*w2.x + dt1*w2.y + dt2*w2.z + dt3*w2.w);
            r.w = softplus_(bdv.w + dt0*w3.x + dt1*w3.y + dt2*w3.z + dt3*w3.w);
            *(float4*)&delta[g * 128 + d] = r;
            *(float4*)&dls[tokloc * PADF + d] = r;
        }
    }
    __syncthreads();
    // ---- phase 4: chunk P/Q scan (thread = d=tid>>1, n-oct=tid&1; 8 chains) ----
    {
        int d = tid >> 1;
        int nb = (tid & 1) * 8;
        float4 Av0 = *(const float4*)&A_log[d * 16 + nb];
        float4 Av1 = *(const float4*)&A_log[d * 16 + nb + 4];
        float A0 = -__expf(Av0.x), A1 = -__expf(Av0.y),
              A2 = -__expf(Av0.z), A3 = -__expf(Av0.w);
        float A4 = -__expf(Av1.x), A5 = -__expf(Av1.y),
              A6 = -__expf(Av1.z), A7 = -__expf(Av1.w);
        float P0=1.f,P1=1.f,P2=1.f,P3=1.f,P4=1.f,P5=1.f,P6=1.f,P7=1.f;
        float Q0=0.f,Q1=0.f,Q2=0.f,Q3=0.f,Q4=0.f,Q5=0.f,Q6=0.f,Q7=0.f;
        for (int t = 0; t < LC; ++t) {
            float dl = dls[t * PADF + d];
            float uu = bf2f(uls[t * PAD + d]);
            float4 bm0 = *(const float4*)&bls[t * 16 + nb];
            float4 bm1 = *(const float4*)&bls[t * 16 + nb + 4];
            float du = dl * uu;
            float a0 = __expf(dl * A0), a1 = __expf(dl * A1),
                  a2 = __expf(dl * A2), a3 = __expf(dl * A3);
            float a4 = __expf(dl * A4), a5 = __expf(dl * A5),
                  a6 = __expf(dl * A6), a7 = __expf(dl * A7);
            P0 *= a0; P1 *= a1; P2 *= a2; P3 *= a3;
            P4 *= a4; P5 *= a5; P6 *= a6; P7 *= a7;
            Q0 = a0 * Q0 + du * bm0.x; Q1 = a1 * Q1 + du * bm0.y;
            Q2 = a2 * Q2 + du * bm0.z; Q3 = a3 * Q3 + du * bm0.w;
            Q4 = a4 * Q4 + du * bm1.x; Q5 = a5 * Q5 + du * bm1.y;
            Q6 = a6 * Q6 + du * bm1.z; Q7 = a7 * Q7 + du * bm1.w;
        }
        int idx = blockIdx.x * 2048 + d * 16 + nb;   // blockIdx.x == b*NCHUNK+c
        *(float4*)&P[idx]     = (float4){P0, P1, P2, P3};
        *(float4*)&P[idx + 4] = (float4){P4, P5, P6, P7};
        *(float4*)&Q[idx]     = (float4){Q0, Q1, Q2, Q3};
        *(float4*)&Q[idx + 4] = (float4){Q4, Q5, Q6, Q7};
    }
}

// K4b: carry scan across chunks.
__global__ __launch_bounds__(256) void k4b_carry(
    const float* __restrict__ P, const float* __restrict__ Q, float* __restrict__ Hinit)
{
    int tid = blockIdx.x * 256 + threadIdx.x;  // 16384
    int b = tid >> 11, dn = tid & 2047;
    float carry = 0.f;
    for (int c = 0; c < NCHUNK; ++c) {
        int idx = (b * NCHUNK + c) * 2048 + dn;
        Hinit[idx] = carry;
        carry = P[idx] * carry + Q[idx];
    }
}

// K4c+K5 fused (v2, 57.4 KB LDS): full-d chunk replay -> y into yzls (which is
// preloaded with z: read-then-overwrite by the same thread) -> out-proj MFMA
// + residual. Block = (b, chunk) = blockIdx.x; thread = (d=tid>>1, n-oct=tid&1).
__global__ __launch_bounds__(256) void k4c5_fused(
    const float* __restrict__ delta, const unsigned short* __restrict__ u_cbf,
    const float* __restrict__ Bm, const float* __restrict__ Cm,
    const unsigned short* __restrict__ z_bf, const float* __restrict__ A_log,
    const float* __restrict__ D_param, const float* __restrict__ Hinit,
    const unsigned short* __restrict__ Wout_bf, const float* __restrict__ b_out,
    const float* __restrict__ x, float* __restrict__ out)
{
    __shared__ unsigned short dls[LC * 128];   // bf16 delta, 16 KB
    __shared__ unsigned short uls[LC * 128];   // 16 KB
    __shared__ float bls[LC * 16];             // 4 KB
    __shared__ float cls[LC * 16];             // 4 KB
    __shared__ unsigned short yzls[LC * PAD];  // 17.4 KB: z preload -> y
    int bid = blockIdx.x;                      // 512 = b*NCHUNK + c
    int tid = threadIdx.x, lane = tid & 63;
    int g0 = bid * 64;
    // stage delta fp32 -> bf16
    for (int i = tid; i < LC * 32; i += 256) {
        int row = i >> 5, q = i & 31;
        float4 v = *(const float4*)&delta[(g0 + row) * 128 + q * 4];
        uint2 pk; pk.x = pack2bf(v.x, v.y); pk.y = pack2bf(v.z, v.w);
        *(uint2*)&dls[row * 128 + q * 4] = pk;
    }
    for (int i = tid; i < LC * 16; i += 256) {
        int row = i >> 4, q = i & 15;
        *(float4*)&uls[row * 128 + q * 8] =
            *(const float4*)&u_cbf[(g0 + row) * 128 + q * 8];
        *(float4*)&yzls[row * PAD + q * 8] =
            *(const float4*)&z_bf[(g0 + row) * 128 + q * 8];
    }
    for (int i = tid; i < LC * 4; i += 256) {
        int row = i >> 2, q = i & 3;
        *(float4*)&bls[row * 16 + q * 4] = *(const float4*)&Bm[(g0 + row) * 16 + q * 4];
        *(float4*)&cls[row * 16 + q * 4] = *(const float4*)&Cm[(g0 + row) * 16 + q * 4];
    }
    int d = tid >> 1;
    int nb = (tid & 1) * 8;
    float4 Av0 = *(const float4*)&A_log[d * 16 + nb];
    float4 Av1 = *(const float4*)&A_log[d * 16 + nb + 4];
    float A0 = -__expf(Av0.x), A1 = -__expf(Av0.y), A2 = -__expf(Av0.z), A3 = -__expf(Av0.w);
    float A4 = -__expf(Av1.x), A5 = -__expf(Av1.y), A6 = -__expf(Av1.z), A7 = -__expf(Av1.w);
    int hbase = bid * 2048 + d * 16 + nb;
    float4 h0 = *(const float4*)&Hinit[hbase];
    float4 h1 = *(const float4*)&Hinit[hbase + 4];
    float Dp = D_param[d];
    __syncthreads();
    for (int t = 0; t < LC; ++t) {
        float dl = bf2f(dls[t * 128 + d]);
        float uu = bf2f(uls[t * 128 + d]);
        float4 bm0 = *(const float4*)&bls[t * 16 + nb];
        float4 bm1 = *(const float4*)&bls[t * 16 + nb + 4];
        float4 cm0 = *(const float4*)&cls[t * 16 + nb];
        float4 cm1 = *(const float4*)&cls[t * 16 + nb + 4];
        float du = dl * uu;
        float a0 = __expf(dl * A0), a1 = __expf(dl * A1),
              a2 = __expf(dl * A2), a3 = __expf(dl * A3);
        float a4 = __expf(dl * A4), a5 = __expf(dl * A5),
              a6 = __expf(dl * A6), a7 = __expf(dl * A7);
        h0.x = a0 * h0.x + du * bm0.x; h0.y = a1 * h0.y + du * bm0.y;
        h0.z = a2 * h0.z + du * bm0.z; h0.w = a3 * h0.w + du * bm0.w;
        h1.x = a4 * h1.x + du * bm1.x; h1.y = a5 * h1.y + du * bm1.y;
        h1.z = a6 * h1.z + du * bm1.z; h1.w = a7 * h1.w + du * bm1.w;
        float yv = h0.x * cm0.x + h0.y * cm0.y + h0.z * cm0.z + h0.w * cm0.w
                 + h1.x * cm1.x + h1.y * cm1.y + h1.z * cm1.z + h1.w * cm1.w;
        yv += __shfl_xor(yv, 1, 64);
        if ((tid & 1) == 0) {
            float y = yv + Dp * uu;
            y *= bf2f(yzls[t * PAD + d]);      // z (preloaded)
            yzls[t * PAD + d] = f2bf(y);       // overwrite with y (same thread)
        }
    }
    __syncthreads();
    // out-proj: M=64 tokens (16/wave), N=64, K=128; out = x + y@W_out^T + b_out
    int wave = tid >> 6;
    int quad = lane >> 4, l16 = lane & 15;
    f32x4 oacc[4];
    #pragma unroll
    for (int nt = 0; nt < 4; ++nt) oacc[nt] = (f32x4){0.f, 0.f, 0.f, 0.f};
    #pragma unroll
    for (int cs = 0; cs < 4; ++cs) {
        int kbase = cs * 32 + quad * 8;
        bf16x8 a = *(const bf16x8*)&yzls[(wave * 16 + l16) * PAD + kbase];
        #pragma unroll
        for (int nt = 0; nt < 4; ++nt) {
            bf16x8 bb = *(const bf16x8*)&Wout_bf[(nt * 16 + l16) * 128 + kbase];
            oacc[nt] = __builtin_amdgcn_mfma_f32_16x16x32_bf16(a, bb, oacc[nt], 0, 0, 0);
        }
    }
    #pragma unroll
    for (int nt = 0; nt < 4; ++nt) {
        int m = nt * 16 + l16;
        float bo = b_out[m];
        #pragma unroll
        for (int r = 0; r < 4; ++r) {
            int t = g0 + wave * 16 + quad * 4 + r;
            out[t * 64 + m] = oacc[nt][r] + bo + x[t * 64 + m];
        }
    }
}

extern "C" void kernel_launch(void* const* d_in, const int* in_sizes, int n_in,
                              void* d_out, int out_size, void* d_ws, size_t ws_size,
                              hipStream_t stream)
{
    const float* x       = (const float*)d_in[0];
    const float* w_norm  = (const float*)d_in[1];
    const float* W_in    = (const float*)d_in[2];
    const float* b_in    = (const float*)d_in[3];
    const float* W_conv  = (const float*)d_in[4];
    const float* b_conv  = (const float*)d_in[5];
    const float* W_xp    = (const float*)d_in[6];
    const float* b_xp    = (const float*)d_in[7];
    const float* W_dt    = (const float*)d_in[8];
    const float* b_dt    = (const float*)d_in[9];
    const float* W_out   = (const float*)d_in[10];
    const float* b_out   = (const float*)d_in[11];
    const float* A_log   = (const float*)d_in[12];
    const float* D_param = (const float*)d_in[13];
    float* ws = (float*)d_ws;

    unsigned short* u_bf = (unsigned short*)ws;            // dead after k2k3a
    unsigned short* z_bf = (unsigned short*)(ws + 2097152);
    unsigned short* u_cbf= (unsigned short*)(ws + 4194304);
    float* delta  = ws + 6291456;
    float* Bm     = ws + 10485760;
    float* Cm     = ws + 11010048;
    float* P      = ws + 11534336;
    float* Q      = ws + 12582912;
    float* Hinit  = ws + 13631488;
    unsigned short* Bp      = (unsigned short*)(ws + 14680064);
    unsigned short* Wxp_bf  = (unsigned short*)(ws + 14712832);
    unsigned short* Wout_bf = (unsigned short*)(ws + 14715904);
    unsigned short* Win_bf  = (unsigned short*)(ws + 14720000);
    float* out    = (float*)d_out;

    pack_all<<<376, 256, 0, stream>>>(W_in, w_norm, W_conv, W_xp, W_out,
                                      Win_bf, Bp, Wxp_bf, Wout_bf);
    k1_fused<<<512, 256, 0, stream>>>(x, Win_bf, b_in, u_bf, z_bf);
    k2k3a_fused<<<512, 256, 0, stream>>>(u_bf, Bp, b_conv, Wxp_bf, b_xp,
                                         W_dt, b_dt, A_log,
                                         u_cbf, delta, Bm, Cm, P, Q);
    k4b_carry<<<64, 256, 0, stream>>>(P, Q, Hinit);
    k4c5_fused<<<512, 256, 0, stream>>>(delta, u_cbf, Bm, Cm, z_bf, A_log,
                                        D_param, Hinit, Wout_bf, b_out, x, out);
}

// Round 11
// 184.009 us; speedup vs baseline: 3.4648x; 1.0263x over previous
//
#include <hip/hip_runtime.h>
#include <math.h>

#define D_MODEL 64
#define D_STATE 16
#define D_INNER 128
#define DT_RANK 4
#define BB 8
#define LL 4096
#define NTOK (BB*LL)      // 32768
#define EPSV 1e-6f
#define NCHUNK 64
#define LC (LL/NCHUNK)    // 64
#define PAD 136           // bf16 LDS row stride (shorts)

typedef __attribute__((ext_vector_type(8))) short bf16x8;
typedef __attribute__((ext_vector_type(4))) float f32x4;

__device__ __forceinline__ float sig_(float v) { return 1.f / (1.f + __expf(-v)); }
__device__ __forceinline__ float softplus_(float v) {
    return (v > 20.f) ? v : __logf(1.f + __expf(v));
}
__device__ __forceinline__ unsigned short f2bf(float x) {
    unsigned int u = __float_as_uint(x);
    u += 0x7fff + ((u >> 16) & 1);      // RNE
    return (unsigned short)(u >> 16);
}
__device__ __forceinline__ float bf2f(unsigned short u) {
    return __uint_as_float(((unsigned int)u) << 16);
}
__device__ __forceinline__ unsigned int pack2bf(float a, float b) {
    return (unsigned int)f2bf(a) | ((unsigned int)f2bf(b) << 16);
}

// Pack all weights to bf16 in one kernel.
__global__ __launch_bounds__(256) void pack_all(
    const float* __restrict__ W_in, const float* __restrict__ w_norm,
    const float* __restrict__ W_conv, const float* __restrict__ W_xp,
    const float* __restrict__ W_out,
    unsigned short* __restrict__ Win_bf, unsigned short* __restrict__ Bp,
    unsigned short* __restrict__ Wxp_bf, unsigned short* __restrict__ Wout_bf)
{
    int i = blockIdx.x * 256 + threadIdx.x;
    if (i < 16384) {
        Win_bf[i] = f2bf(W_in[i] * w_norm[i & 63]);
    } else if (i < 81920) {
        int j = i - 16384;
        int kk = j >> 14, o = (j >> 7) & 127, c = j & 127;
        Bp[j] = f2bf(W_conv[o * 512 + c * 4 + kk]);
    } else if (i < 88064) {
        int j = i - 81920;
        Wxp_bf[j] = ((j >> 7) < 36) ? f2bf(W_xp[j]) : (unsigned short)0;
    } else if (i < 96256) {
        int j = i - 88064;
        Wout_bf[j] = f2bf(W_out[j]);
    }
}

// K1: fused RMSNorm + in_proj via MFMA + silu(z). 64 tokens/block, 4 waves.
__global__ __launch_bounds__(256) void k1_fused(
    const float* __restrict__ x, const unsigned short* __restrict__ Win_bf,
    const float* __restrict__ b_in,
    unsigned short* __restrict__ u_bf, unsigned short* __restrict__ z_bf)
{
    __shared__ unsigned short axs[64 * 72];
    int tid = threadIdx.x;
    int tb = blockIdx.x * 64;
    {
        int t = tid >> 2, qt = tid & 3;
        float4 v[4];
        float ss = 0.f;
        #pragma unroll
        for (int j = 0; j < 4; ++j) {
            v[j] = *(const float4*)&x[(tb + t) * 64 + qt * 16 + j * 4];
            ss += v[j].x*v[j].x + v[j].y*v[j].y + v[j].z*v[j].z + v[j].w*v[j].w;
        }
        ss += __shfl_xor(ss, 1, 64);
        ss += __shfl_xor(ss, 2, 64);
        float r = rsqrtf(ss * (1.f / 64.f) + EPSV);
        unsigned short tmp[16];
        #pragma unroll
        for (int j = 0; j < 4; ++j) {
            tmp[4*j+0] = f2bf(v[j].x * r); tmp[4*j+1] = f2bf(v[j].y * r);
            tmp[4*j+2] = f2bf(v[j].z * r); tmp[4*j+3] = f2bf(v[j].w * r);
        }
        *(bf16x8*)&axs[t * 72 + qt * 16]     = *(bf16x8*)&tmp[0];
        *(bf16x8*)&axs[t * 72 + qt * 16 + 8] = *(bf16x8*)&tmp[8];
    }
    __syncthreads();
    int wave = tid >> 6, lane = tid & 63;
    int quad = lane >> 4, l16 = lane & 15;
    f32x4 acc[16];
    #pragma unroll
    for (int nt = 0; nt < 16; ++nt) acc[nt] = (f32x4){0.f, 0.f, 0.f, 0.f};
    bf16x8 a0 = *(const bf16x8*)&axs[(wave * 16 + l16) * 72 + quad * 8];
    bf16x8 a1 = *(const bf16x8*)&axs[(wave * 16 + l16) * 72 + 32 + quad * 8];
    #pragma unroll
    for (int nt = 0; nt < 16; ++nt) {
        bf16x8 b0 = *(const bf16x8*)&Win_bf[(nt * 16 + l16) * 64 + quad * 8];
        bf16x8 b1 = *(const bf16x8*)&Win_bf[(nt * 16 + l16) * 64 + 32 + quad * 8];
        acc[nt] = __builtin_amdgcn_mfma_f32_16x16x32_bf16(a0, b0, acc[nt], 0, 0, 0);
        acc[nt] = __builtin_amdgcn_mfma_f32_16x16x32_bf16(a1, b1, acc[nt], 0, 0, 0);
    }
    #pragma unroll
    for (int nt = 0; nt < 16; ++nt) {
        int o = nt * 16 + l16;
        float bo = b_in[o];
        #pragma unroll
        for (int r = 0; r < 4; ++r) {
            int t = tb + wave * 16 + quad * 4 + r;
            float v = acc[nt][r] + bo;
            if (o < 128) u_bf[t * 128 + o] = f2bf(v);
            else         z_bf[t * 128 + (o - 128)] = f2bf(v * sig_(v));
        }
    }
}

// K2+K3+K4a fused: conv1d MFMA + silu -> u_cbf + LDS; x-proj MFMA -> Bm,Cm
// (+ Bm LDS); delta (bf16) -> global + LDS; then chunk P/Q scan.
// Block == one chunk: blockIdx.x == b*NCHUNK + c.  LDS ~42.5 KB -> 3 blocks/CU.
__global__ __launch_bounds__(256) void k2k3a_fused(
    const unsigned short* __restrict__ u_bf, const unsigned short* __restrict__ Bp,
    const float* __restrict__ b_conv,
    const unsigned short* __restrict__ Wxp_bf, const float* __restrict__ b_xp,
    const float* __restrict__ W_dt, const float* __restrict__ b_dt,
    const float* __restrict__ A_log,
    unsigned short* __restrict__ u_cbf, unsigned short* __restrict__ delta_bf,
    float* __restrict__ Bm, float* __restrict__ Cm,
    float* __restrict__ P, float* __restrict__ Q)
{
    __shared__ unsigned short uls[64 * PAD];   // 17.4 KB (bf16 u_conv)
    __shared__ unsigned short dls[64 * PAD];   // 17.4 KB (bf16 delta)
    __shared__ float bls[64 * 16];             // 4 KB (fp32 Bm)
    __shared__ float dts[64][4];
    __shared__ float Wd[512];
    __shared__ float bds[128];
    int tid = threadIdx.x;
    if (tid < 128) *(float4*)&Wd[tid * 4] = *(const float4*)&W_dt[tid * 4];
    else if (tid < 160) *(float4*)&bds[(tid - 128) * 4] = *(const float4*)&b_dt[(tid - 128) * 4];
    int wave = tid >> 6, lane = tid & 63;
    int quad = lane >> 4, l16 = lane & 15;
    int tb = blockIdx.x * 64;
    int bbase = tb & ~4095;
    int t0 = tb + wave * 16;
    // ---- phase 1: conv ----
    f32x4 acc[8];
    #pragma unroll
    for (int og = 0; og < 8; ++og) acc[og] = (f32x4){0.f, 0.f, 0.f, 0.f};
    int row_base = t0 + l16 - 3;
    #pragma unroll
    for (int kk = 0; kk < 4; ++kk) {
        int row = row_base + kk;
        #pragma unroll
        for (int cs = 0; cs < 4; ++cs) {
            int kbase = cs * 32 + quad * 8;
            bf16x8 a = {0,0,0,0,0,0,0,0};
            if (row >= bbase)
                a = *(const bf16x8*)&u_bf[row * 128 + kbase];
            #pragma unroll
            for (int og = 0; og < 8; ++og) {
                bf16x8 b = *(const bf16x8*)&Bp[kk * 16384 + (og * 16 + l16) * 128 + kbase];
                acc[og] = __builtin_amdgcn_mfma_f32_16x16x32_bf16(a, b, acc[og], 0, 0, 0);
            }
        }
    }
    #pragma unroll
    for (int og = 0; og < 8; ++og) {
        int o = og * 16 + l16;
        float bc = b_conv[o];
        #pragma unroll
        for (int r = 0; r < 4; ++r) {
            int tloc = wave * 16 + quad * 4 + r;
            float v = acc[og][r] + bc;
            unsigned short ub = f2bf(v * sig_(v));
            u_cbf[(tb + tloc) * 128 + o] = ub;
            uls[tloc * PAD + o] = ub;
        }
    }
    __syncthreads();
    // ---- phase 2: x-proj (M=64, N=48 padded, K=128) ----
    f32x4 xacc[3];
    #pragma unroll
    for (int nt = 0; nt < 3; ++nt) xacc[nt] = (f32x4){0.f, 0.f, 0.f, 0.f};
    #pragma unroll
    for (int cs = 0; cs < 4; ++cs) {
        int kbase = cs * 32 + quad * 8;
        bf16x8 a = *(const bf16x8*)&uls[(wave * 16 + l16) * PAD + kbase];
        #pragma unroll
        for (int nt = 0; nt < 3; ++nt) {
            bf16x8 b = *(const bf16x8*)&Wxp_bf[(nt * 16 + l16) * 128 + kbase];
            xacc[nt] = __builtin_amdgcn_mfma_f32_16x16x32_bf16(a, b, xacc[nt], 0, 0, 0);
        }
    }
    #pragma unroll
    for (int nt = 0; nt < 3; ++nt) {
        int j = nt * 16 + l16;
        float bx = (j < 36) ? b_xp[j] : 0.f;
        #pragma unroll
        for (int r = 0; r < 4; ++r) {
            int tloc = wave * 16 + quad * 4 + r;
            int t = tb + tloc;
            float val = xacc[nt][r] + bx;
            if (j < 4) {
                dts[tloc][j] = val;
            } else if (j < 20) {
                Bm[t * 16 + (j - 4)] = val;
                bls[tloc * 16 + (j - 4)] = val;
            } else if (j < 36) {
                Cm[t * 16 + (j - 20)] = val;
            }
        }
    }
    __syncthreads();
    // ---- phase 3: delta = softplus(dt @ W_dt^T + b_dt), bf16 out ----
    {
        int tokloc = tid >> 2, dgrp = tid & 3;
        float dt0 = dts[tokloc][0], dt1 = dts[tokloc][1],
              dt2 = dts[tokloc][2], dt3 = dts[tokloc][3];
        int g = tb + tokloc;
        #pragma unroll
        for (int d4 = 0; d4 < 8; ++d4) {
            int d = dgrp * 32 + d4 * 4;
            float4 w0 = *(const float4*)&Wd[(d + 0) * 4];
            float4 w1 = *(const float4*)&Wd[(d + 1) * 4];
            float4 w2 = *(const float4*)&Wd[(d + 2) * 4];
            float4 w3 = *(const float4*)&Wd[(d + 3) * 4];
            float4 bdv = *(const float4*)&bds[d];
            float4 r;
            r.x = softplus_(bdv.x + dt0*w0.x + dt1*w0.y + dt2*w0.z + dt3*w0.w);
            r.y = softplus_(bdv.y + dt0*w1.x + dt1*w1.y + dt2*w1.z + dt3*w1.w);
            r.z = softplus_(bdv.z + dt0*w2.x + dt1*w2.y + dt2*w2.z + dt3*w2.w);
            r.w = softplus_(bdv.w + dt0*w3.x + dt1*w3.y + dt2*w3.z + dt3*w3.w);
            uint2 pk; pk.x = pack2bf(r.x, r.y); pk.y = pack2bf(r.z, r.w);
            *(uint2*)&delta_bf[g * 128 + d] = pk;
            *(uint2*)&dls[tokloc * PAD + d] = pk;
        }
    }
    __syncthreads();
    // ---- phase 4: chunk P/Q scan (thread = d=tid>>1, n-oct=tid&1; 8 chains) ----
    {
        int d = tid >> 1;
        int nb = (tid & 1) * 8;
        float4 Av0 = *(const float4*)&A_log[d * 16 + nb];
        float4 Av1 = *(const float4*)&A_log[d * 16 + nb + 4];
        float A0 = -__expf(Av0.x), A1 = -__expf(Av0.y),
              A2 = -__expf(Av0.z), A3 = -__expf(Av0.w);
        float A4 = -__expf(Av1.x), A5 = -__expf(Av1.y),
              A6 = -__expf(Av1.z), A7 = -__expf(Av1.w);
        float P0=1.f,P1=1.f,P2=1.f,P3=1.f,P4=1.f,P5=1.f,P6=1.f,P7=1.f;
        float Q0=0.f,Q1=0.f,Q2=0.f,Q3=0.f,Q4=0.f,Q5=0.f,Q6=0.f,Q7=0.f;
        for (int t = 0; t < LC; ++t) {
            float dl = bf2f(dls[t * PAD + d]);
            float uu = bf2f(uls[t * PAD + d]);
            float4 bm0 = *(const float4*)&bls[t * 16 + nb];
            float4 bm1 = *(const float4*)&bls[t * 16 + nb + 4];
            float du = dl * uu;
            float a0 = __expf(dl * A0), a1 = __expf(dl * A1),
                  a2 = __expf(dl * A2), a3 = __expf(dl * A3);
            float a4 = __expf(dl * A4), a5 = __expf(dl * A5),
                  a6 = __expf(dl * A6), a7 = __expf(dl * A7);
            P0 *= a0; P1 *= a1; P2 *= a2; P3 *= a3;
            P4 *= a4; P5 *= a5; P6 *= a6; P7 *= a7;
            Q0 = a0 * Q0 + du * bm0.x; Q1 = a1 * Q1 + du * bm0.y;
            Q2 = a2 * Q2 + du * bm0.z; Q3 = a3 * Q3 + du * bm0.w;
            Q4 = a4 * Q4 + du * bm1.x; Q5 = a5 * Q5 + du * bm1.y;
            Q6 = a6 * Q6 + du * bm1.z; Q7 = a7 * Q7 + du * bm1.w;
        }
        int idx = blockIdx.x * 2048 + d * 16 + nb;   // blockIdx.x == b*NCHUNK+c
        *(float4*)&P[idx]     = (float4){P0, P1, P2, P3};
        *(float4*)&P[idx + 4] = (float4){P4, P5, P6, P7};
        *(float4*)&Q[idx]     = (float4){Q0, Q1, Q2, Q3};
        *(float4*)&Q[idx + 4] = (float4){Q4, Q5, Q6, Q7};
    }
}

// K4b: carry scan across chunks (8x unrolled: batch loads, then chain).
__global__ __launch_bounds__(256) void k4b_carry(
    const float* __restrict__ P, const float* __restrict__ Q, float* __restrict__ Hinit)
{
    int tid = blockIdx.x * 256 + threadIdx.x;  // 16384
    int b = tid >> 11, dn = tid & 2047;
    float carry = 0.f;
    for (int c0 = 0; c0 < NCHUNK; c0 += 8) {
        float p[8], q[8];
        #pragma unroll
        for (int j = 0; j < 8; ++j) {
            int idx = (b * NCHUNK + c0 + j) * 2048 + dn;
            p[j] = P[idx]; q[j] = Q[idx];
        }
        #pragma unroll
        for (int j = 0; j < 8; ++j) {
            int idx = (b * NCHUNK + c0 + j) * 2048 + dn;
            Hinit[idx] = carry;
            carry = p[j] * carry + q[j];
        }
    }
}

// K4c+K5 fused (57.4 KB LDS): full-d chunk replay -> y into yzls (z preloaded,
// read-then-overwrite same thread) -> out-proj MFMA + residual.
__global__ __launch_bounds__(256) void k4c5_fused(
    const unsigned short* __restrict__ delta_bf, const unsigned short* __restrict__ u_cbf,
    const float* __restrict__ Bm, const float* __restrict__ Cm,
    const unsigned short* __restrict__ z_bf, const float* __restrict__ A_log,
    const float* __restrict__ D_param, const float* __restrict__ Hinit,
    const unsigned short* __restrict__ Wout_bf, const float* __restrict__ b_out,
    const float* __restrict__ x, float* __restrict__ out)
{
    __shared__ unsigned short dls[LC * 128];   // bf16 delta, 16 KB
    __shared__ unsigned short uls[LC * 128];   // 16 KB
    __shared__ float bls[LC * 16];             // 4 KB
    __shared__ float cls[LC * 16];             // 4 KB
    __shared__ unsigned short yzls[LC * PAD];  // 17.4 KB: z preload -> y
    int bid = blockIdx.x;                      // 512 = b*NCHUNK + c
    int tid = threadIdx.x, lane = tid & 63;
    int g0 = bid * 64;
    for (int i = tid; i < LC * 16; i += 256) {
        int row = i >> 4, q = i & 15;
        *(float4*)&dls[row * 128 + q * 8] =
            *(const float4*)&delta_bf[(g0 + row) * 128 + q * 8];
        *(float4*)&uls[row * 128 + q * 8] =
            *(const float4*)&u_cbf[(g0 + row) * 128 + q * 8];
        *(float4*)&yzls[row * PAD + q * 8] =
            *(const float4*)&z_bf[(g0 + row) * 128 + q * 8];
    }
    for (int i = tid; i < LC * 4; i += 256) {
        int row = i >> 2, q = i & 3;
        *(float4*)&bls[row * 16 + q * 4] = *(const float4*)&Bm[(g0 + row) * 16 + q * 4];
        *(float4*)&cls[row * 16 + q * 4] = *(const float4*)&Cm[(g0 + row) * 16 + q * 4];
    }
    int d = tid >> 1;
    int nb = (tid & 1) * 8;
    float4 Av0 = *(const float4*)&A_log[d * 16 + nb];
    float4 Av1 = *(const float4*)&A_log[d * 16 + nb + 4];
    float A0 = -__expf(Av0.x), A1 = -__expf(Av0.y), A2 = -__expf(Av0.z), A3 = -__expf(Av0.w);
    float A4 = -__expf(Av1.x), A5 = -__expf(Av1.y), A6 = -__expf(Av1.z), A7 = -__expf(Av1.w);
    int hbase = bid * 2048 + d * 16 + nb;
    float4 h0 = *(const float4*)&Hinit[hbase];
    float4 h1 = *(const float4*)&Hinit[hbase + 4];
    float Dp = D_param[d];
    __syncthreads();
    for (int t = 0; t < LC; ++t) {
        float dl = bf2f(dls[t * 128 + d]);
        float uu = bf2f(uls[t * 128 + d]);
        float4 bm0 = *(const float4*)&bls[t * 16 + nb];
        float4 bm1 = *(const float4*)&bls[t * 16 + nb + 4];
        float4 cm0 = *(const float4*)&cls[t * 16 + nb];
        float4 cm1 = *(const float4*)&cls[t * 16 + nb + 4];
        float du = dl * uu;
        float a0 = __expf(dl * A0), a1 = __expf(dl * A1),
              a2 = __expf(dl * A2), a3 = __expf(dl * A3);
        float a4 = __expf(dl * A4), a5 = __expf(dl * A5),
              a6 = __expf(dl * A6), a7 = __expf(dl * A7);
        h0.x = a0 * h0.x + du * bm0.x; h0.y = a1 * h0.y + du * bm0.y;
        h0.z = a2 * h0.z + du * bm0.z; h0.w = a3 * h0.w + du * bm0.w;
        h1.x = a4 * h1.x + du * bm1.x; h1.y = a5 * h1.y + du * bm1.y;
        h1.z = a6 * h1.z + du * bm1.z; h1.w = a7 * h1.w + du * bm1.w;
        float yv = h0.x * cm0.x + h0.y * cm0.y + h0.z * cm0.z + h0.w * cm0.w
                 + h1.x * cm1.x + h1.y * cm1.y + h1.z * cm1.z + h1.w * cm1.w;
        yv += __shfl_xor(yv, 1, 64);
        if ((tid & 1) == 0) {
            float y = yv + Dp * uu;
            y *= bf2f(yzls[t * PAD + d]);      // z (preloaded)
            yzls[t * PAD + d] = f2bf(y);       // overwrite with y (same thread)
        }
    }
    __syncthreads();
    // out-proj: M=64 tokens (16/wave), N=64, K=128; out = x + y@W_out^T + b_out
    int wave = tid >> 6;
    int quad = lane >> 4, l16 = lane & 15;
    f32x4 oacc[4];
    #pragma unroll
    for (int nt = 0; nt < 4; ++nt) oacc[nt] = (f32x4){0.f, 0.f, 0.f, 0.f};
    #pragma unroll
    for (int cs = 0; cs < 4; ++cs) {
        int kbase = cs * 32 + quad * 8;
        bf16x8 a = *(const bf16x8*)&yzls[(wave * 16 + l16) * PAD + kbase];
        #pragma unroll
        for (int nt = 0; nt < 4; ++nt) {
            bf16x8 bb = *(const bf16x8*)&Wout_bf[(nt * 16 + l16) * 128 + kbase];
            oacc[nt] = __builtin_amdgcn_mfma_f32_16x16x32_bf16(a, bb, oacc[nt], 0, 0, 0);
        }
    }
    #pragma unroll
    for (int nt = 0; nt < 4; ++nt) {
        int m = nt * 16 + l16;
        float bo = b_out[m];
        #pragma unroll
        for (int r = 0; r < 4; ++r) {
            int t = g0 + wave * 16 + quad * 4 + r;
            out[t * 64 + m] = oacc[nt][r] + bo + x[t * 64 + m];
        }
    }
}

extern "C" void kernel_launch(void* const* d_in, const int* in_sizes, int n_in,
                              void* d_out, int out_size, void* d_ws, size_t ws_size,
                              hipStream_t stream)
{
    const float* x       = (const float*)d_in[0];
    const float* w_norm  = (const float*)d_in[1];
    const float* W_in    = (const float*)d_in[2];
    const float* b_in    = (const float*)d_in[3];
    const float* W_conv  = (const float*)d_in[4];
    const float* b_conv  = (const float*)d_in[5];
    const float* W_xp    = (const float*)d_in[6];
    const float* b_xp    = (const float*)d_in[7];
    const float* W_dt    = (const float*)d_in[8];
    const float* b_dt    = (const float*)d_in[9];
    const float* W_out   = (const float*)d_in[10];
    const float* b_out   = (const float*)d_in[11];
    const float* A_log   = (const float*)d_in[12];
    const float* D_param = (const float*)d_in[13];
    float* ws = (float*)d_ws;

    unsigned short* u_bf = (unsigned short*)ws;            // dead after k2k3a
    unsigned short* z_bf = (unsigned short*)(ws + 2097152);
    unsigned short* u_cbf= (unsigned short*)(ws + 4194304);
    unsigned short* delta_bf = (unsigned short*)(ws + 6291456);   // 4M bf16 = 8MB
    float* Bm     = ws + 10485760;
    float* Cm     = ws + 11010048;
    float* P      = ws + 11534336;
    float* Q      = ws + 12582912;
    float* Hinit  = ws + 13631488;
    unsigned short* Bp      = (unsigned short*)(ws + 14680064);
    unsigned short* Wxp_bf  = (unsigned short*)(ws + 14712832);
    unsigned short* Wout_bf = (unsigned short*)(ws + 14715904);
    unsigned short* Win_bf  = (unsigned short*)(ws + 14720000);
    float* out    = (float*)d_out;

    pack_all<<<376, 256, 0, stream>>>(W_in, w_norm, W_conv, W_xp, W_out,
                                      Win_bf, Bp, Wxp_bf, Wout_bf);
    k1_fused<<<512, 256, 0, stream>>>(x, Win_bf, b_in, u_bf, z_bf);
    k2k3a_fused<<<512, 256, 0, stream>>>(u_bf, Bp, b_conv, Wxp_bf, b_xp,
                                         W_dt, b_dt, A_log,
                                         u_cbf, delta_bf, Bm, Cm, P, Q);
    k4b_carry<<<64, 256, 0, stream>>>(P, Q, Hinit);
    k4c5_fused<<<512, 256, 0, stream>>>(delta_bf, u_cbf, Bm, Cm, z_bf, A_log,
                                        D_param, Hinit, Wout_bf, b_out, x, out);
}